// Round 16
// baseline (270.528 us; speedup 1.0000x reference)
//
#include <hip/hip_runtime.h>
#include <hip/hip_bf16.h>
#include <stdint.h>

typedef unsigned short u16;
typedef __attribute__((ext_vector_type(8))) short s16x8;
typedef __attribute__((ext_vector_type(4))) float f32x4;

#define B_ 2
#define S_ 2048
#define H_ 2304
#define NH_ 8
#define NKV_ 4
#define HD_ 256

__device__ __forceinline__ float bf2f(u16 u) {
  union { uint32_t i; float f; } x; x.i = ((uint32_t)u) << 16; return x.f;
}
__device__ __forceinline__ u16 f2bf(float f) {
  union { float f; uint32_t i; } x; x.f = f;
  uint32_t u = x.i;
  return (u16)((u + 0x7fffu + ((u >> 16) & 1u)) >> 16);
}

__device__ __forceinline__ void async16(const void* g, void* l) {
  __builtin_amdgcn_global_load_lds((const __attribute__((address_space(1))) uint32_t*)g,
                                   (__attribute__((address_space(3))) uint32_t*)l, 16, 0, 0);
}

__device__ __forceinline__ f32x4 mfma16(s16x8 a, s16x8 b, f32x4 c) {
  return __builtin_amdgcn_mfma_f32_16x16x32_bf16(a, b, c, 0, 0, 0);
}

// ---------------- fp32 -> bf16 elementwise convert ----------------
__global__ void f32_to_bf16(const float* __restrict__ in, u16* __restrict__ out, size_t n) {
  size_t i = ((size_t)blockIdx.x * blockDim.x + threadIdx.x) * 4;
  if (i + 3 < n) {
    float4 v = *(const float4*)(in + i);
    ushort4 o;
    o.x = f2bf(v.x); o.y = f2bf(v.y); o.z = f2bf(v.z); o.w = f2bf(v.w);
    *(ushort4*)(out + i) = o;
  }
}

// ---------------- transpose fp32 in -> bf16 out: in[R][C] -> out[C][R] ----------------
__global__ void transpose_f32_bf16(const float* __restrict__ in, u16* __restrict__ out, int R, int C) {
  __shared__ u16 tile[32][33];
  int c0 = blockIdx.x * 32, r0 = blockIdx.y * 32;
  int x = threadIdx.x, y = threadIdx.y;
#pragma unroll
  for (int j = 0; j < 32; j += 8)
    tile[y + j][x] = f2bf(in[(size_t)(r0 + y + j) * C + c0 + x]);
  __syncthreads();
#pragma unroll
  for (int j = 0; j < 32; j += 8)
    out[(size_t)(c0 + y + j) * R + r0 + x] = tile[x][y + j];
}

// ------- strided-batch bf16 transpose: in[z*zin + r*istride + c] -> out[z*zout + c*R + r] -------
__global__ void transpose_bf16_s(const u16* __restrict__ in, u16* __restrict__ out, int R, int C,
                                 int istride, size_t zin, size_t zout) {
  __shared__ u16 tile[32][33];
  in += (size_t)blockIdx.z * zin;
  out += (size_t)blockIdx.z * zout;
  int c0 = blockIdx.x * 32, r0 = blockIdx.y * 32;
  int x = threadIdx.x, y = threadIdx.y;
#pragma unroll
  for (int j = 0; j < 32; j += 8)
    tile[y + j][x] = in[(size_t)(r0 + y + j) * istride + c0 + x];
  __syncthreads();
#pragma unroll
  for (int j = 0; j < 32; j += 8)
    out[(size_t)(c0 + y + j) * R + r0 + x] = tile[x][y + j];
}

// ================= 256x256 deep-pipelined GEMM (1-phase counted schedule) =================
template <bool F32OUT>
__global__ __launch_bounds__(512) void gemm256(const u16* __restrict__ A, const u16* __restrict__ BT,
                                               void* __restrict__ Cout, int M, int N, int Kd) {
  __shared__ u16 As[2][256 * 64];
  __shared__ u16 Bs[2][256 * 64];
  int tid = threadIdx.x, lane = tid & 63, wave = tid >> 6;
  int nT = gridDim.x * gridDim.y;
  int bid = blockIdx.y * gridDim.x + blockIdx.x;
  int tile = (bid & 7) * (nT >> 3) + (bid >> 3);        // XCD swizzle (nT % 8 == 0)
  int bn = (tile % gridDim.x) * 256;
  int bm = (tile / gridDim.x) * 256;
  int wm = (wave >> 2) * 128, wn = (wave & 3) * 64;
  int fr = lane & 15, fq = lane >> 4;
  f32x4 acc[8][4];
#pragma unroll
  for (int i = 0; i < 8; i++)
#pragma unroll
    for (int j = 0; j < 4; j++) acc[i][j] = (f32x4){0.f, 0.f, 0.f, 0.f};

  int srow = tid >> 3, sslot = tid & 7;
  int scol = (sslot * 8) ^ ((srow & 7) << 3);           // pre-swizzled source col (u16 units)
  const u16* Ab = A + (size_t)(bm + srow) * Kd + scol;
  const u16* Bb = BT + (size_t)(bn + srow) * Kd + scol;

  auto stage = [&](int buf, int k0) {
#pragma unroll
    for (int i = 0; i < 4; i++) {
      async16(Ab + (size_t)i * 64 * Kd + k0, (char*)&As[buf][0] + wave * 1024 + i * 8192);
      async16(Bb + (size_t)i * 64 * Kd + k0, (char*)&Bs[buf][0] + wave * 1024 + i * 8192);
    }
  };

  int NT = Kd >> 6;
  int rsw = (fr & 7) << 3;
  stage(0, 0);
  for (int t = 0; t < NT; ++t) {
    if (t + 1 < NT) {
      stage((t + 1) & 1, (t + 1) << 6);
      asm volatile("s_waitcnt vmcnt(8)" ::: "memory");
    } else {
      asm volatile("s_waitcnt vmcnt(0)" ::: "memory");
    }
    __builtin_amdgcn_sched_barrier(0);
    __builtin_amdgcn_s_barrier();
    __builtin_amdgcn_sched_barrier(0);
    const u16* Ap = &As[t & 1][0];
    const u16* Bp = &Bs[t & 1][0];
    __builtin_amdgcn_s_setprio(1);
    s16x8 bfr[4][2];
#pragma unroll
    for (int j = 0; j < 4; j++)
#pragma unroll
      for (int s = 0; s < 2; s++)
        bfr[j][s] = *(const s16x8*)&Bp[(wn + j * 16 + fr) * 64 + ((s * 32 + fq * 8) ^ rsw)];
#pragma unroll
    for (int i = 0; i < 8; i++) {
      s16x8 a0 = *(const s16x8*)&Ap[(wm + i * 16 + fr) * 64 + ((fq * 8) ^ rsw)];
      s16x8 a1 = *(const s16x8*)&Ap[(wm + i * 16 + fr) * 64 + ((32 + fq * 8) ^ rsw)];
#pragma unroll
      for (int j = 0; j < 4; j++) {
        acc[i][j] = mfma16(a0, bfr[j][0], acc[i][j]);
        acc[i][j] = mfma16(a1, bfr[j][1], acc[i][j]);
      }
    }
    __builtin_amdgcn_s_setprio(0);
    asm volatile("s_waitcnt lgkmcnt(0)" ::: "memory");
    __builtin_amdgcn_sched_barrier(0);
    __builtin_amdgcn_s_barrier();
  }

#pragma unroll
  for (int i = 0; i < 8; i++)
#pragma unroll
    for (int j = 0; j < 4; j++)
#pragma unroll
      for (int r = 0; r < 4; r++) {
        int row = bm + wm + i * 16 + fq * 4 + r;
        int col = bn + wn + j * 16 + fr;
        if (F32OUT) ((float*)Cout)[(size_t)row * N + col] = acc[i][j][r];
        else        ((u16*)Cout)[(size_t)row * N + col] = f2bf(acc[i][j][r]);
      }
}

// ================= 128x128 GEMM, BK=64 (32 MFMA + 16 ds_read per barrier-pair) =================
template <bool F32OUT>
__global__ __launch_bounds__(256) void gemm128(const u16* __restrict__ A, const u16* __restrict__ BT,
                                               void* __restrict__ Cout, int M, int N, int Kd) {
  __shared__ u16 As[2][128 * 64];
  __shared__ u16 Bs[2][128 * 64];
  int tid = threadIdx.x, lane = tid & 63, wave = tid >> 6;
  int nT = gridDim.x * gridDim.y;
  int bid = blockIdx.y * gridDim.x + blockIdx.x;
  int tile = (bid & 7) * (nT >> 3) + (bid >> 3);
  int bn = (tile % gridDim.x) * 128;
  int bm = (tile / gridDim.x) * 128;
  int wm = (wave >> 1) * 64, wn = (wave & 1) * 64;
  int fr = lane & 15, fq = lane >> 4;
  f32x4 acc[4][4];
#pragma unroll
  for (int i = 0; i < 4; i++)
#pragma unroll
    for (int j = 0; j < 4; j++) acc[i][j] = (f32x4){0.f, 0.f, 0.f, 0.f};

  // staging: granule c = tid + i*256 (i<4): row = c>>3 = (tid>>3) + i*32, slot = c&7
  int srow = tid >> 3, sslot = tid & 7;
  int scol = (sslot * 8) ^ ((srow & 7) << 3);           // (row&7) invariant under +32i
  const u16* Ab = A + (size_t)(bm + srow) * Kd + scol;
  const u16* Bb = BT + (size_t)(bn + srow) * Kd + scol;

  auto stage = [&](int buf, int k0) {
#pragma unroll
    for (int i = 0; i < 4; i++) {
      async16(Ab + (size_t)i * 32 * Kd + k0, (char*)&As[buf][0] + (tid + i * 256) * 16);
      async16(Bb + (size_t)i * 32 * Kd + k0, (char*)&Bs[buf][0] + (tid + i * 256) * 16);
    }
  };

  int NT = Kd >> 6;
  int rsw = (fr & 7) << 3;
  stage(0, 0);
  for (int t = 0; t < NT; ++t) {
    if (t + 1 < NT) {
      stage((t + 1) & 1, (t + 1) << 6);
      asm volatile("s_waitcnt vmcnt(8)" ::: "memory");
    } else {
      asm volatile("s_waitcnt vmcnt(0)" ::: "memory");
    }
    __builtin_amdgcn_sched_barrier(0);
    __builtin_amdgcn_s_barrier();
    __builtin_amdgcn_sched_barrier(0);
    const u16* Ap = &As[t & 1][0];
    const u16* Bp = &Bs[t & 1][0];
    __builtin_amdgcn_s_setprio(1);
    s16x8 af[4][2], bv[4][2];
#pragma unroll
    for (int i = 0; i < 4; i++)
#pragma unroll
      for (int s = 0; s < 2; s++) {
        af[i][s] = *(const s16x8*)&Ap[(wm + i * 16 + fr) * 64 + ((s * 32 + fq * 8) ^ rsw)];
        bv[i][s] = *(const s16x8*)&Bp[(wn + i * 16 + fr) * 64 + ((s * 32 + fq * 8) ^ rsw)];
      }
#pragma unroll
    for (int i = 0; i < 4; i++)
#pragma unroll
      for (int j = 0; j < 4; j++) {
        acc[i][j] = mfma16(af[i][0], bv[j][0], acc[i][j]);
        acc[i][j] = mfma16(af[i][1], bv[j][1], acc[i][j]);
      }
    __builtin_amdgcn_s_setprio(0);
    asm volatile("s_waitcnt lgkmcnt(0)" ::: "memory");
    __builtin_amdgcn_sched_barrier(0);
    __builtin_amdgcn_s_barrier();
  }
#pragma unroll
  for (int i = 0; i < 4; i++)
#pragma unroll
    for (int j = 0; j < 4; j++)
#pragma unroll
      for (int r = 0; r < 4; r++) {
        int row = bm + wm + i * 16 + fq * 4 + r;
        int col = bn + wn + j * 16 + fr;
        if (F32OUT) ((float*)Cout)[(size_t)row * N + col] = acc[i][j][r];
        else        ((u16*)Cout)[(size_t)row * N + col] = f2bf(acc[i][j][r]);
      }
}

// ---------------- RoPE sin/cos table: [pos 0..S-1][d 0..127] f32 ----------------
__global__ void rope_table(float* __restrict__ ct, float* __restrict__ st) {
  int t = blockIdx.x * blockDim.x + threadIdx.x;   // t = p*128 + d
  int d = t & 127;
  int p = t >> 7;
  float invf = exp2f(-(float)d * 0.1038102530f); // log2(10000)/128
  float f = (float)p * invf;
  float s, c;
  sincosf(f, &s, &c);
  ct[t] = c;
  st[t] = s;
}

// ---------------- RoPE on K columns of fused QKV (8 pairs per thread) ----------------
__global__ void rope_k(u16* __restrict__ QKV, const int* __restrict__ pos_ids,
                       const float* __restrict__ ct, const float* __restrict__ st) {
  int t = blockIdx.x * blockDim.x + threadIdx.x;   // 4096 rows * 4 heads * 16 dgroups
  int dg = t & 15, h = (t >> 4) & 3, row = t >> 6;
  u16* p1 = QKV + (size_t)row * 4096 + 2048 + h * 256 + dg * 8;
  u16* p2 = p1 + 128;
  int pos = pos_ids[row];
  const float* ctp = ct + pos * 128 + dg * 8;
  const float* stp = st + pos * 128 + dg * 8;
  s16x8 v1 = *(const s16x8*)p1, v2 = *(const s16x8*)p2;
#pragma unroll
  for (int j = 0; j < 8; j++) {
    float c = ctp[j], s = stp[j];
    float a = bf2f((u16)v1[j]);
    float b = bf2f((u16)v2[j]);
    v1[j] = (short)f2bf(a * c - b * s);
    v2[j] = (short)f2bf(b * c + a * s);
  }
  *(s16x8*)p1 = v1;
  *(s16x8*)p2 = v2;
}

// ---------------- flash attention, KEY-SPLIT, 2-barrier race-free pipeline ----------
// grid 1024; id&7 = b*4+g pinned per XCD (KV L2-resident); qt heavy-first.
// Per tile: vmcnt(0) -> BAR-A -> stage V(t), K(t+2) -> QK^T/softmax/Pwrite -> lgkm0
//           -> vmcnt(4) -> BAR-C -> PV -> lgkm0.
// Ledger: V WAR protected by BAR-A (a wave reaches iter t+2 staging only after ALL waves
// passed BAR-A(t+2), which follows their PV(t) lgkm0).  K WAR has 2 barriers in between.
// vmcnt(0)@top retires K(t) staged ~600cy earlier (no stall); vmcnt(4) keeps K(t+2) in flight.
__global__ __launch_bounds__(256) void attn_kernel(const u16* __restrict__ QKV, const u16* __restrict__ VT,
                                                   const int* __restrict__ amask, const int* __restrict__ pos_ids,
                                                   const float* __restrict__ ct, const float* __restrict__ st,
                                                   u16* __restrict__ O0, u16* __restrict__ O1,
                                                   float* __restrict__ L0, float* __restrict__ L1) {
  __shared__ u16 Kl[2][32 * 256];        // K double buffer; granule swz: slot ^= key&7
  __shared__ u16 Vl[256 * 32];           // V single buffer; granule swz: slot ^= (hd>>1)&3
  __shared__ u16 Pl[4][16 * 32];         // per-wave P, XOR-swizzled cols
  __shared__ unsigned char Mb[256];      // bit-packed amask (2048 bits)
  int id = blockIdx.x;
  int bg = id & 7;                        // XCD-pinned (b,g)
  int r_ = id >> 3;
  int qt = 31 - (r_ >> 2);                // heavy first
  int hl = (r_ >> 1) & 1;
  int half = r_ & 1;
  int b = bg >> 2, g = bg & 3;
  int h = g * 2 + hl;
  int tid = threadIdx.x, lane = tid & 63, wave = tid >> 6;
  int fr = lane & 15, fq = lane >> 4;
  int q0 = qt * 64;
  u16* Op = half ? O1 : O0;
  float* Lp = half ? L1 : L0;

  // ---- bit-pack attention mask: thread t packs ints 8t..8t+7 into byte Mb[t] ----
  const int* amp = amask + b * S_;
  {
    int4 a = *(const int4*)(amp + tid * 8);
    int4 c = *(const int4*)(amp + tid * 8 + 4);
    unsigned v = (unsigned)(a.x > 0) | ((unsigned)(a.y > 0) << 1) | ((unsigned)(a.z > 0) << 2) |
                 ((unsigned)(a.w > 0) << 3) | ((unsigned)(c.x > 0) << 4) | ((unsigned)(c.y > 0) << 5) |
                 ((unsigned)(c.z > 0) << 6) | ((unsigned)(c.w > 0) << 7);
    Mb[tid] = (unsigned char)v;
  }

  // ---- load Q rows wave*16+fr, apply RoPE in-register, scale 1/16 ----
  int qrow_g = b * S_ + q0 + wave * 16 + fr;
  s16x8 qr[8];
  const u16* qb = QKV + (size_t)qrow_g * 4096 + h * 256 + fq * 8;
#pragma unroll
  for (int kk = 0; kk < 8; kk++) qr[kk] = *(const s16x8*)(qb + kk * 32);
  int pos = pos_ids[qrow_g];
  const float* ctp = ct + pos * 128 + fq * 8;
  const float* stp = st + pos * 128 + fq * 8;
  s16x8 qf[8];
#pragma unroll
  for (int kk = 0; kk < 4; kk++) {
#pragma unroll
    for (int jj = 0; jj < 8; jj++) {
      float c = ctp[kk * 32 + jj], s = stp[kk * 32 + jj];
      float a = bf2f((u16)qr[kk][jj]);
      float bb = bf2f((u16)qr[kk + 4][jj]);
      qf[kk][jj]     = (short)f2bf((a * c - bb * s) * 0.0625f);
      qf[kk + 4][jj] = (short)f2bf((bb * c + a * s) * 0.0625f);
    }
  }

  f32x4 zero4 = {0.f, 0.f, 0.f, 0.f};
  f32x4 oacc[16];
#pragma unroll
  for (int i = 0; i < 16; i++) oacc[i] = zero4;
  f32x4 lacc = zero4;
  s16x8 onesv;
#pragma unroll
  for (int i = 0; i < 8; i++) onesv[i] = (short)0x3F80;

  const u16* Kbase = QKV + (size_t)b * S_ * 4096 + 2048 + g * 256;
  const u16* Vbase = VT + (size_t)(b * 4 + g) * 256 * S_;

  // ---- staging pointers: 1024 granules each for K,V; 4 K + 4 V per thread ----
  const u16* KsP[4];
  const u16* VsP[4];
  int dst16[4];
#pragma unroll
  for (int i = 0; i < 4; i++) {
    int c = tid + i * 256;
    int key = c >> 5, slot = c & 31;
    KsP[i] = Kbase + (size_t)key * 4096 + ((slot ^ (key & 7)) * 8);
    int hd = c >> 2, vs = c & 3;
    VsP[i] = Vbase + (size_t)hd * 2048 + ((vs ^ ((hd >> 1) & 3)) * 8);
    dst16[i] = c * 16;
  }

  __syncthreads();                                  // Mb visible; all prologue vmem drained

  // prologue: stage K(half)
#pragma unroll
  for (int i = 0; i < 4; i++)
    async16(KsP[i] + (size_t)(half * 32) * 4096, (char*)&Kl[0][0] + dst16[i]);

  int nt = 2 * qt + 2;
  int ksw = fr & 7;
  int vswl = (fr >> 1) & 3;
  int psw = (fr & 3) << 3;
  int kb = 0;
  for (int t = half; t < nt; t += 2) {
    int k0 = t * 32;
    bool more = (t + 2 < nt);
    asm volatile("s_waitcnt vmcnt(0)" ::: "memory");     // retire K(t) (issued ~1 iter ago)
    __builtin_amdgcn_sched_barrier(0);
    __builtin_amdgcn_s_barrier();                        // BAR-A: all waves' K(t) visible;
    __builtin_amdgcn_sched_barrier(0);                   //   also V-WAR fence (see header)

    // stage V(t) then K(t+2): FIFO order V older than K for the vmcnt(4) below
#pragma unroll
    for (int i = 0; i < 4; i++)
      async16(VsP[i] + k0, (char*)&Vl[0] + dst16[i]);
    if (more) {
#pragma unroll
      for (int i = 0; i < 4; i++)
        async16(KsP[i] + (size_t)(k0 + 64) * 4096, (char*)&Kl[kb ^ 1][0] + dst16[i]);
    }

    // ---- QK^T: keys {fr, 16+fr} x 32-wide K tile ----
    const u16* Kp = &Kl[kb][0];
    __builtin_amdgcn_s_setprio(1);
    f32x4 s0 = zero4, s1 = zero4;
#pragma unroll
    for (int kk = 0; kk < 8; kk++) {
      s16x8 b0 = *(const s16x8*)&Kp[fr * 256 + (((kk * 4 + fq) ^ ksw) * 8)];
      s16x8 b1 = *(const s16x8*)&Kp[(16 + fr) * 256 + (((kk * 4 + fq) ^ ksw) * 8)];
      s0 = mfma16(qf[kk], b0, s0);
      s1 = mfma16(qf[kk], b1, s1);
    }
    __builtin_amdgcn_s_setprio(0);

    int am0 = (Mb[(k0 + fr) >> 3] >> ((k0 + fr) & 7)) & 1;
    int am1 = (Mb[(k0 + 16 + fr) >> 3] >> ((k0 + 16 + fr) & 7)) & 1;
    bool needmask = (t >= nt - 2);
#pragma unroll
    for (int r = 0; r < 4; r++) {
      int qrow = fq * 4 + r;
      int qg = q0 + wave * 16 + qrow;
      // p = exp(50*tanh(s/50) - 50) = exp(-100/(exp(0.04*s)+1))  [fixed max 50]
      float e20 = __expf(s0[r] * 0.04f);
      float e21 = __expf(s1[r] * 0.04f);
      float p0 = __expf(__fdividef(-100.f, e20 + 1.f));
      float p1 = __expf(__fdividef(-100.f, e21 + 1.f));
      bool ok0 = am0 && (!needmask || (k0 + fr) <= qg);
      bool ok1 = am1 && (!needmask || (k0 + 16 + fr) <= qg);
      p0 = ok0 ? p0 : 0.f;
      p1 = ok1 ? p1 : 0.f;
      Pl[wave][qrow * 32 + (fr ^ (r << 3))] = f2bf(p0);
      Pl[wave][qrow * 32 + ((16 + fr) ^ (r << 3))] = f2bf(p1);
    }
    asm volatile("s_waitcnt lgkmcnt(0)" ::: "memory");   // own P writes + K reads drained
    __builtin_amdgcn_sched_barrier(0);
    if (more)
      asm volatile("s_waitcnt vmcnt(4)" ::: "memory");   // retire V(t); K(t+2) stays in flight
    else
      asm volatile("s_waitcnt vmcnt(0)" ::: "memory");
    __builtin_amdgcn_sched_barrier(0);
    __builtin_amdgcn_s_barrier();                        // BAR-C: all waves' V(t) visible
    __builtin_amdgcn_sched_barrier(0);

    // ---- PV (per-wave P) ----
    s16x8 pf = *(const s16x8*)&Pl[wave][fr * 32 + ((fq * 8) ^ psw)];
    __builtin_amdgcn_s_setprio(1);
    lacc = mfma16(pf, onesv, lacc);
#pragma unroll
    for (int df = 0; df < 16; df++) {
      s16x8 vv = *(const s16x8*)&Vl[(df * 16 + fr) * 32 + ((fq ^ vswl) * 8)];
      oacc[df] = mfma16(pf, vv, oacc[df]);
    }
    __builtin_amdgcn_s_setprio(0);
    asm volatile("s_waitcnt lgkmcnt(0)" ::: "memory");   // own V reads done (before next BAR-A)
    __builtin_amdgcn_sched_barrier(0);
    kb ^= 1;
  }

  // ---- write unnormalized bf16 partial O and f32 partial l ----
  if (fr == 0) {
#pragma unroll
    for (int r = 0; r < 4; r++)
      Lp[(size_t)(b * S_ + q0 + wave * 16 + fq * 4 + r) * 8 + h] = lacc[r];
  }
#pragma unroll
  for (int df = 0; df < 16; df++) {
#pragma unroll
    for (int r = 0; r < 4; r++) {
      Op[(size_t)(b * S_ + q0 + wave * 16 + fq * 4 + r) * 2048 + h * 256 + df * 16 + fr] =
          f2bf(oacc[df][r]);
    }
  }
}

// ---------------- combine partial halves: AO = (O0+O1)/(l0+l1) ----------------
__global__ void combine_o(const u16* __restrict__ O0, const u16* __restrict__ O1,
                          const float* __restrict__ L0, const float* __restrict__ L1,
                          u16* __restrict__ AO) {
  int idx = blockIdx.x * blockDim.x + threadIdx.x;   // 4096 rows x 256 groups of 8 cols
  int row = idx >> 8;
  int cg = idx & 255;
  int h = cg >> 5;
  float rinv = 1.0f / (L0[row * 8 + h] + L1[row * 8 + h]);
  size_t base = (size_t)row * 2048 + cg * 8;
  s16x8 a = *(const s16x8*)(O0 + base);
  s16x8 b = *(const s16x8*)(O1 + base);
  s16x8 o;
#pragma unroll
  for (int j = 0; j < 8; j++)
    o[j] = (short)f2bf((bf2f((u16)a[j]) + bf2f((u16)b[j])) * rinv);
  *(s16x8*)(AO + base) = o;
}

extern "C" void kernel_launch(void* const* d_in, const int* in_sizes, int n_in,
                              void* d_out, int out_size, void* d_ws, size_t ws_size,
                              hipStream_t stream) {
  const float* X   = (const float*)d_in[0];   // [B,S,H] fp32
  const int* amask = (const int*)d_in[1];
  const int* pos   = (const int*)d_in[2];
  const float* Wq  = (const float*)d_in[3];
  const float* Wk  = (const float*)d_in[4];
  const float* Wv  = (const float*)d_in[5];
  const float* Wo  = (const float*)d_in[6];
  float* out = (float*)d_out;                 // [B,S,H] fp32

  char* ws = (char*)d_ws;
  size_t off = 0;
  auto allocB = [&](size_t bytes) {
    char* p = ws + off;
    off += ((bytes + 255) & ~(size_t)255);
    return p;
  };
  u16* Xb   = (u16*)allocB((size_t)4096 * 2304 * 2);
  u16* WqT  = (u16*)allocB((size_t)2048 * 2304 * 2);   // WqT/WkT/WvT contiguous => fused B^T
  u16* WkT  = (u16*)allocB((size_t)1024 * 2304 * 2);
  u16* WvT  = (u16*)allocB((size_t)1024 * 2304 * 2);
  u16* WoT  = (u16*)allocB((size_t)2304 * 2048 * 2);
  u16* QKV  = (u16*)allocB((size_t)4096 * 4096 * 2);
  u16* VTb  = (u16*)allocB((size_t)4096 * 1024 * 2);
  u16* AO   = (u16*)allocB((size_t)4096 * 2048 * 2);
  float* CT = (float*)allocB((size_t)2048 * 128 * 4);
  float* ST = (float*)allocB((size_t)2048 * 128 * 4);
  float* Lp0 = (float*)allocB((size_t)4096 * 8 * 4);
  float* Lp1 = (float*)allocB((size_t)4096 * 8 * 4);
  // O partials ALIAS the Xb/WqT/WkT/WvT-head region (dead after gemm256)
  u16* Op0 = (u16*)ws;
  u16* Op1 = Op0 + (size_t)4096 * 2048;
  if (off > ws_size) return;

  // RoPE table (independent; early)
  rope_table<<<(2048 * 128) / 256, 256, 0, stream>>>(CT, ST);

  // hidden_states fp32 -> bf16
  {
    size_t n = (size_t)4096 * 2304;
    f32_to_bf16<<<(unsigned)((n / 4 + 255) / 256), 256, 0, stream>>>(X, Xb, n);
  }

  dim3 tb(32, 8);
  transpose_f32_bf16<<<dim3(2048 / 32, 2304 / 32), tb, 0, stream>>>(Wq, WqT, 2304, 2048);
  transpose_f32_bf16<<<dim3(1024 / 32, 2304 / 32), tb, 0, stream>>>(Wk, WkT, 2304, 1024);
  transpose_f32_bf16<<<dim3(1024 / 32, 2304 / 32), tb, 0, stream>>>(Wv, WvT, 2304, 1024);
  transpose_f32_bf16<<<dim3(2304 / 32, 2048 / 32), tb, 0, stream>>>(Wo, WoT, 2048, 2304);

  // fused QKV projection (256² 1-phase counted)  [Xb/WqT/WkT/WvT dead after this]
  gemm256<false><<<dim3(4096 / 256, 4096 / 256), 512, 0, stream>>>(Xb, WqT, QKV, 4096, 4096, 2304);

  // RoPE on K only (Q roped in-register inside attn)
  rope_k<<<(4096 * 4 * 16) / 256, 256, 0, stream>>>(QKV, pos, CT, ST);

  // V (QKV cols 3072..4095) -> VT[b][kv][d][s]
  transpose_bf16_s<<<dim3(1024 / 32, 2048 / 32, 2), tb, 0, stream>>>(
      QKV + 3072, VTb, 2048, 1024, 4096, (size_t)2048 * 4096, (size_t)1024 * 2048);

  // attention: key-split grid 1024, XCD-pinned (b,g), 2-barrier pipeline
  attn_kernel<<<dim3(1024), 256, 0, stream>>>(QKV, VTb, amask, pos, CT, ST, Op0, Op1, Lp0, Lp1);

  // combine halves -> AO bf16
  combine_o<<<4096, 256, 0, stream>>>(Op0, Op1, Lp0, Lp1, AO);

  // output projection -> fp32 d_out (128² BK=64 pipelined)
  gemm128<true><<<dim3(2304 / 128, 4096 / 128), 256, 0, stream>>>(AO, WoT, out, 4096, 2304, 2048);
}

// Round 17
// 261.822 us; speedup vs baseline: 1.0333x; 1.0333x over previous
//
#include <hip/hip_runtime.h>
#include <hip/hip_bf16.h>
#include <stdint.h>

typedef unsigned short u16;
typedef __attribute__((ext_vector_type(8))) short s16x8;
typedef __attribute__((ext_vector_type(4))) float f32x4;

#define B_ 2
#define S_ 2048
#define H_ 2304
#define NH_ 8
#define NKV_ 4
#define HD_ 256

__device__ __forceinline__ float bf2f(u16 u) {
  union { uint32_t i; float f; } x; x.i = ((uint32_t)u) << 16; return x.f;
}
__device__ __forceinline__ u16 f2bf(float f) {
  union { float f; uint32_t i; } x; x.f = f;
  uint32_t u = x.i;
  return (u16)((u + 0x7fffu + ((u >> 16) & 1u)) >> 16);
}

__device__ __forceinline__ void async16(const void* g, void* l) {
  __builtin_amdgcn_global_load_lds((const __attribute__((address_space(1))) uint32_t*)g,
                                   (__attribute__((address_space(3))) uint32_t*)l, 16, 0, 0);
}

__device__ __forceinline__ f32x4 mfma16(s16x8 a, s16x8 b, f32x4 c) {
  return __builtin_amdgcn_mfma_f32_16x16x32_bf16(a, b, c, 0, 0, 0);
}

// ---------------- fp32 -> bf16 elementwise convert ----------------
__global__ void f32_to_bf16(const float* __restrict__ in, u16* __restrict__ out, size_t n) {
  size_t i = ((size_t)blockIdx.x * blockDim.x + threadIdx.x) * 4;
  if (i + 3 < n) {
    float4 v = *(const float4*)(in + i);
    ushort4 o;
    o.x = f2bf(v.x); o.y = f2bf(v.y); o.z = f2bf(v.z); o.w = f2bf(v.w);
    *(ushort4*)(out + i) = o;
  }
}

// ---------------- transpose fp32 in -> bf16 out: in[R][C] -> out[C][R] ----------------
__global__ void transpose_f32_bf16(const float* __restrict__ in, u16* __restrict__ out, int R, int C) {
  __shared__ u16 tile[32][33];
  int c0 = blockIdx.x * 32, r0 = blockIdx.y * 32;
  int x = threadIdx.x, y = threadIdx.y;
#pragma unroll
  for (int j = 0; j < 32; j += 8)
    tile[y + j][x] = f2bf(in[(size_t)(r0 + y + j) * C + c0 + x]);
  __syncthreads();
#pragma unroll
  for (int j = 0; j < 32; j += 8)
    out[(size_t)(c0 + y + j) * R + r0 + x] = tile[x][y + j];
}

// ------- strided-batch bf16 transpose: in[z*zin + r*istride + c] -> out[z*zout + c*R + r] -------
__global__ void transpose_bf16_s(const u16* __restrict__ in, u16* __restrict__ out, int R, int C,
                                 int istride, size_t zin, size_t zout) {
  __shared__ u16 tile[32][33];
  in += (size_t)blockIdx.z * zin;
  out += (size_t)blockIdx.z * zout;
  int c0 = blockIdx.x * 32, r0 = blockIdx.y * 32;
  int x = threadIdx.x, y = threadIdx.y;
#pragma unroll
  for (int j = 0; j < 32; j += 8)
    tile[y + j][x] = in[(size_t)(r0 + y + j) * istride + c0 + x];
  __syncthreads();
#pragma unroll
  for (int j = 0; j < 32; j += 8)
    out[(size_t)(c0 + y + j) * R + r0 + x] = tile[x][y + j];
}

// ================= 256x256 deep-pipelined GEMM (1-phase counted schedule) =================
template <bool F32OUT>
__global__ __launch_bounds__(512) void gemm256(const u16* __restrict__ A, const u16* __restrict__ BT,
                                               void* __restrict__ Cout, int M, int N, int Kd) {
  __shared__ u16 As[2][256 * 64];
  __shared__ u16 Bs[2][256 * 64];
  int tid = threadIdx.x, lane = tid & 63, wave = tid >> 6;
  int nT = gridDim.x * gridDim.y;
  int bid = blockIdx.y * gridDim.x + blockIdx.x;
  int tile = (bid & 7) * (nT >> 3) + (bid >> 3);        // XCD swizzle (nT % 8 == 0)
  int bn = (tile % gridDim.x) * 256;
  int bm = (tile / gridDim.x) * 256;
  int wm = (wave >> 2) * 128, wn = (wave & 3) * 64;
  int fr = lane & 15, fq = lane >> 4;
  f32x4 acc[8][4];
#pragma unroll
  for (int i = 0; i < 8; i++)
#pragma unroll
    for (int j = 0; j < 4; j++) acc[i][j] = (f32x4){0.f, 0.f, 0.f, 0.f};

  int srow = tid >> 3, sslot = tid & 7;
  int scol = (sslot * 8) ^ ((srow & 7) << 3);           // pre-swizzled source col (u16 units)
  const u16* Ab = A + (size_t)(bm + srow) * Kd + scol;
  const u16* Bb = BT + (size_t)(bn + srow) * Kd + scol;

  auto stage = [&](int buf, int k0) {
#pragma unroll
    for (int i = 0; i < 4; i++) {
      async16(Ab + (size_t)i * 64 * Kd + k0, (char*)&As[buf][0] + wave * 1024 + i * 8192);
      async16(Bb + (size_t)i * 64 * Kd + k0, (char*)&Bs[buf][0] + wave * 1024 + i * 8192);
    }
  };

  int NT = Kd >> 6;
  int rsw = (fr & 7) << 3;
  stage(0, 0);
  for (int t = 0; t < NT; ++t) {
    if (t + 1 < NT) {
      stage((t + 1) & 1, (t + 1) << 6);
      asm volatile("s_waitcnt vmcnt(8)" ::: "memory");
    } else {
      asm volatile("s_waitcnt vmcnt(0)" ::: "memory");
    }
    __builtin_amdgcn_sched_barrier(0);
    __builtin_amdgcn_s_barrier();
    __builtin_amdgcn_sched_barrier(0);
    const u16* Ap = &As[t & 1][0];
    const u16* Bp = &Bs[t & 1][0];
    __builtin_amdgcn_s_setprio(1);
    s16x8 bfr[4][2];
#pragma unroll
    for (int j = 0; j < 4; j++)
#pragma unroll
      for (int s = 0; s < 2; s++)
        bfr[j][s] = *(const s16x8*)&Bp[(wn + j * 16 + fr) * 64 + ((s * 32 + fq * 8) ^ rsw)];
#pragma unroll
    for (int i = 0; i < 8; i++) {
      s16x8 a0 = *(const s16x8*)&Ap[(wm + i * 16 + fr) * 64 + ((fq * 8) ^ rsw)];
      s16x8 a1 = *(const s16x8*)&Ap[(wm + i * 16 + fr) * 64 + ((32 + fq * 8) ^ rsw)];
#pragma unroll
      for (int j = 0; j < 4; j++) {
        acc[i][j] = mfma16(a0, bfr[j][0], acc[i][j]);
        acc[i][j] = mfma16(a1, bfr[j][1], acc[i][j]);
      }
    }
    __builtin_amdgcn_s_setprio(0);
    asm volatile("s_waitcnt lgkmcnt(0)" ::: "memory");
    __builtin_amdgcn_sched_barrier(0);
    __builtin_amdgcn_s_barrier();
  }

#pragma unroll
  for (int i = 0; i < 8; i++)
#pragma unroll
    for (int j = 0; j < 4; j++)
#pragma unroll
      for (int r = 0; r < 4; r++) {
        int row = bm + wm + i * 16 + fq * 4 + r;
        int col = bn + wn + j * 16 + fr;
        if (F32OUT) ((float*)Cout)[(size_t)row * N + col] = acc[i][j][r];
        else        ((u16*)Cout)[(size_t)row * N + col] = f2bf(acc[i][j][r]);
      }
}

// ================= 128x128 pipelined GEMM, BK=32 (R15 configuration) =================
template <bool F32OUT>
__global__ __launch_bounds__(256) void gemm128(const u16* __restrict__ A, const u16* __restrict__ BT,
                                               void* __restrict__ Cout, int M, int N, int Kd) {
  __shared__ u16 As[2][128 * 32];
  __shared__ u16 Bs[2][128 * 32];
  int tid = threadIdx.x, lane = tid & 63, wave = tid >> 6;
  int nT = gridDim.x * gridDim.y;
  int bid = blockIdx.y * gridDim.x + blockIdx.x;
  int tile = (bid & 7) * (nT >> 3) + (bid >> 3);
  int bn = (tile % gridDim.x) * 128;
  int bm = (tile / gridDim.x) * 128;
  int wm = (wave >> 1) * 64, wn = (wave & 1) * 64;
  int fr = lane & 15, fq = lane >> 4;
  f32x4 acc[4][4];
#pragma unroll
  for (int i = 0; i < 4; i++)
#pragma unroll
    for (int j = 0; j < 4; j++) acc[i][j] = (f32x4){0.f, 0.f, 0.f, 0.f};

  int srow = tid >> 2, sslot = tid & 3;
  int scol = (sslot * 8) ^ ((srow & 3) << 3);
  const u16* Ab = A + (size_t)(bm + srow) * Kd + scol;
  const u16* Bb = BT + (size_t)(bn + srow) * Kd + scol;

  auto stage = [&](int buf, int k0) {
    async16(Ab + k0, (char*)&As[buf][0] + wave * 1024);
    async16(Ab + (size_t)64 * Kd + k0, (char*)&As[buf][0] + wave * 1024 + 4096);
    async16(Bb + k0, (char*)&Bs[buf][0] + wave * 1024);
    async16(Bb + (size_t)64 * Kd + k0, (char*)&Bs[buf][0] + wave * 1024 + 4096);
  };

  int NT = Kd >> 5;
  int rsw = (fr & 3) << 3;
  stage(0, 0);
  for (int t = 0; t < NT; ++t) {
    if (t + 1 < NT) {
      stage((t + 1) & 1, (t + 1) << 5);
      asm volatile("s_waitcnt vmcnt(4)" ::: "memory");
    } else {
      asm volatile("s_waitcnt vmcnt(0)" ::: "memory");
    }
    __builtin_amdgcn_sched_barrier(0);
    __builtin_amdgcn_s_barrier();
    __builtin_amdgcn_sched_barrier(0);
    const u16* Ap = &As[t & 1][0];
    const u16* Bp = &Bs[t & 1][0];
    __builtin_amdgcn_s_setprio(1);
    s16x8 af[4], bv[4];
#pragma unroll
    for (int i = 0; i < 4; i++) af[i] = *(const s16x8*)&Ap[(wm + i * 16 + fr) * 32 + ((fq * 8) ^ rsw)];
#pragma unroll
    for (int j = 0; j < 4; j++) bv[j] = *(const s16x8*)&Bp[(wn + j * 16 + fr) * 32 + ((fq * 8) ^ rsw)];
#pragma unroll
    for (int i = 0; i < 4; i++)
#pragma unroll
      for (int j = 0; j < 4; j++)
        acc[i][j] = mfma16(af[i], bv[j], acc[i][j]);
    __builtin_amdgcn_s_setprio(0);
    asm volatile("s_waitcnt lgkmcnt(0)" ::: "memory");
    __builtin_amdgcn_sched_barrier(0);
    __builtin_amdgcn_s_barrier();
  }
#pragma unroll
  for (int i = 0; i < 4; i++)
#pragma unroll
    for (int j = 0; j < 4; j++)
#pragma unroll
      for (int r = 0; r < 4; r++) {
        int row = bm + wm + i * 16 + fq * 4 + r;
        int col = bn + wn + j * 16 + fr;
        if (F32OUT) ((float*)Cout)[(size_t)row * N + col] = acc[i][j][r];
        else        ((u16*)Cout)[(size_t)row * N + col] = f2bf(acc[i][j][r]);
      }
}

// ---------------- RoPE sin/cos table: [pos 0..S-1][d 0..127] f32 ----------------
__global__ void rope_table(float* __restrict__ ct, float* __restrict__ st) {
  int t = blockIdx.x * blockDim.x + threadIdx.x;   // t = p*128 + d
  int d = t & 127;
  int p = t >> 7;
  float invf = exp2f(-(float)d * 0.1038102530f); // log2(10000)/128
  float f = (float)p * invf;
  float s, c;
  sincosf(f, &s, &c);
  ct[t] = c;
  st[t] = s;
}

// ---------------- RoPE on K columns of fused QKV (8 pairs per thread) ----------------
__global__ void rope_k(u16* __restrict__ QKV, const int* __restrict__ pos_ids,
                       const float* __restrict__ ct, const float* __restrict__ st) {
  int t = blockIdx.x * blockDim.x + threadIdx.x;   // 4096 rows * 4 heads * 16 dgroups
  int dg = t & 15, h = (t >> 4) & 3, row = t >> 6;
  u16* p1 = QKV + (size_t)row * 4096 + 2048 + h * 256 + dg * 8;
  u16* p2 = p1 + 128;
  int pos = pos_ids[row];
  const float* ctp = ct + pos * 128 + dg * 8;
  const float* stp = st + pos * 128 + dg * 8;
  s16x8 v1 = *(const s16x8*)p1, v2 = *(const s16x8*)p2;
#pragma unroll
  for (int j = 0; j < 8; j++) {
    float c = ctp[j], s = stp[j];
    float a = bf2f((u16)v1[j]);
    float b = bf2f((u16)v2[j]);
    v1[j] = (short)f2bf(a * c - b * s);
    v2[j] = (short)f2bf(b * c + a * s);
  }
  *(s16x8*)p1 = v1;
  *(s16x8*)p2 = v2;
}

// ---------------- flash attention, KEY-SPLIT, 2-barrier race-free pipeline ----------
// grid 1024; id&7 = b*4+g pinned per XCD (KV L2-resident); qt heavy-first.
// Per tile: vmcnt(0) -> BAR-A -> stage V(t), K(t+2) -> QK^T/softmax/Pwrite -> lgkm0
//           -> vmcnt(4) -> BAR-C -> PV -> lgkm0.
// Ledger: V WAR protected by BAR-A (a wave reaches iter t+2 staging only after ALL waves
// passed BAR-A(t+2), which follows their PV(t) lgkm0).  K WAR has 2 barriers in between.
__global__ __launch_bounds__(256) void attn_kernel(const u16* __restrict__ QKV, const u16* __restrict__ VT,
                                                   const int* __restrict__ amask, const int* __restrict__ pos_ids,
                                                   const float* __restrict__ ct, const float* __restrict__ st,
                                                   u16* __restrict__ O0, u16* __restrict__ O1,
                                                   float* __restrict__ L0, float* __restrict__ L1) {
  __shared__ u16 Kl[2][32 * 256];        // K double buffer; granule swz: slot ^= key&7
  __shared__ u16 Vl[256 * 32];           // V single buffer; granule swz: slot ^= (hd>>1)&3
  __shared__ u16 Pl[4][16 * 32];         // per-wave P, XOR-swizzled cols
  __shared__ unsigned char Mb[256];      // bit-packed amask (2048 bits)
  int id = blockIdx.x;
  int bg = id & 7;                        // XCD-pinned (b,g)
  int r_ = id >> 3;
  int qt = 31 - (r_ >> 2);                // heavy first
  int hl = (r_ >> 1) & 1;
  int half = r_ & 1;
  int b = bg >> 2, g = bg & 3;
  int h = g * 2 + hl;
  int tid = threadIdx.x, lane = tid & 63, wave = tid >> 6;
  int fr = lane & 15, fq = lane >> 4;
  int q0 = qt * 64;
  u16* Op = half ? O1 : O0;
  float* Lp = half ? L1 : L0;

  // ---- bit-pack attention mask: thread t packs ints 8t..8t+7 into byte Mb[t] ----
  const int* amp = amask + b * S_;
  {
    int4 a = *(const int4*)(amp + tid * 8);
    int4 c = *(const int4*)(amp + tid * 8 + 4);
    unsigned v = (unsigned)(a.x > 0) | ((unsigned)(a.y > 0) << 1) | ((unsigned)(a.z > 0) << 2) |
                 ((unsigned)(a.w > 0) << 3) | ((unsigned)(c.x > 0) << 4) | ((unsigned)(c.y > 0) << 5) |
                 ((unsigned)(c.z > 0) << 6) | ((unsigned)(c.w > 0) << 7);
    Mb[tid] = (unsigned char)v;
  }

  // ---- load Q rows wave*16+fr, apply RoPE in-register, scale 1/16 ----
  int qrow_g = b * S_ + q0 + wave * 16 + fr;
  s16x8 qr[8];
  const u16* qb = QKV + (size_t)qrow_g * 4096 + h * 256 + fq * 8;
#pragma unroll
  for (int kk = 0; kk < 8; kk++) qr[kk] = *(const s16x8*)(qb + kk * 32);
  int pos = pos_ids[qrow_g];
  const float* ctp = ct + pos * 128 + fq * 8;
  const float* stp = st + pos * 128 + fq * 8;
  s16x8 qf[8];
#pragma unroll
  for (int kk = 0; kk < 4; kk++) {
#pragma unroll
    for (int jj = 0; jj < 8; jj++) {
      float c = ctp[kk * 32 + jj], s = stp[kk * 32 + jj];
      float a = bf2f((u16)qr[kk][jj]);
      float bb = bf2f((u16)qr[kk + 4][jj]);
      qf[kk][jj]     = (short)f2bf((a * c - bb * s) * 0.0625f);
      qf[kk + 4][jj] = (short)f2bf((bb * c + a * s) * 0.0625f);
    }
  }

  f32x4 zero4 = {0.f, 0.f, 0.f, 0.f};
  f32x4 oacc[16];
#pragma unroll
  for (int i = 0; i < 16; i++) oacc[i] = zero4;
  f32x4 lacc = zero4;
  s16x8 onesv;
#pragma unroll
  for (int i = 0; i < 8; i++) onesv[i] = (short)0x3F80;

  const u16* Kbase = QKV + (size_t)b * S_ * 4096 + 2048 + g * 256;
  const u16* Vbase = VT + (size_t)(b * 4 + g) * 256 * S_;

  // ---- staging pointers: 1024 granules each for K,V; 4 K + 4 V per thread ----
  const u16* KsP[4];
  const u16* VsP[4];
  int dst16[4];
#pragma unroll
  for (int i = 0; i < 4; i++) {
    int c = tid + i * 256;
    int key = c >> 5, slot = c & 31;
    KsP[i] = Kbase + (size_t)key * 4096 + ((slot ^ (key & 7)) * 8);
    int hd = c >> 2, vs = c & 3;
    VsP[i] = Vbase + (size_t)hd * 2048 + ((vs ^ ((hd >> 1) & 3)) * 8);
    dst16[i] = c * 16;
  }

  __syncthreads();                                  // Mb visible; all prologue vmem drained

  // prologue: stage K(half)
#pragma unroll
  for (int i = 0; i < 4; i++)
    async16(KsP[i] + (size_t)(half * 32) * 4096, (char*)&Kl[0][0] + dst16[i]);

  int nt = 2 * qt + 2;
  int ksw = fr & 7;
  int vswl = (fr >> 1) & 3;
  int psw = (fr & 3) << 3;
  int kb = 0;
  for (int t = half; t < nt; t += 2) {
    int k0 = t * 32;
    bool more = (t + 2 < nt);
    asm volatile("s_waitcnt vmcnt(0)" ::: "memory");     // retire K(t) (issued ~1 iter ago)
    __builtin_amdgcn_sched_barrier(0);
    __builtin_amdgcn_s_barrier();                        // BAR-A: all waves' K(t) visible;
    __builtin_amdgcn_sched_barrier(0);                   //   also V-WAR fence (see header)

    // stage V(t) then K(t+2): FIFO order V older than K for the vmcnt(4) below
#pragma unroll
    for (int i = 0; i < 4; i++)
      async16(VsP[i] + k0, (char*)&Vl[0] + dst16[i]);
    if (more) {
#pragma unroll
      for (int i = 0; i < 4; i++)
        async16(KsP[i] + (size_t)(k0 + 64) * 4096, (char*)&Kl[kb ^ 1][0] + dst16[i]);
    }

    // ---- QK^T: keys {fr, 16+fr} x 32-wide K tile ----
    const u16* Kp = &Kl[kb][0];
    __builtin_amdgcn_s_setprio(1);
    f32x4 s0 = zero4, s1 = zero4;
#pragma unroll
    for (int kk = 0; kk < 8; kk++) {
      s16x8 b0 = *(const s16x8*)&Kp[fr * 256 + (((kk * 4 + fq) ^ ksw) * 8)];
      s16x8 b1 = *(const s16x8*)&Kp[(16 + fr) * 256 + (((kk * 4 + fq) ^ ksw) * 8)];
      s0 = mfma16(qf[kk], b0, s0);
      s1 = mfma16(qf[kk], b1, s1);
    }
    __builtin_amdgcn_s_setprio(0);

    int am0 = (Mb[(k0 + fr) >> 3] >> ((k0 + fr) & 7)) & 1;
    int am1 = (Mb[(k0 + 16 + fr) >> 3] >> ((k0 + 16 + fr) & 7)) & 1;
    bool needmask = (t >= nt - 2);
#pragma unroll
    for (int r = 0; r < 4; r++) {
      int qrow = fq * 4 + r;
      int qg = q0 + wave * 16 + qrow;
      // p = exp(50*tanh(s/50) - 50) = exp(-100/(exp(0.04*s)+1))  [fixed max 50]
      float e20 = __expf(s0[r] * 0.04f);
      float e21 = __expf(s1[r] * 0.04f);
      float p0 = __expf(__fdividef(-100.f, e20 + 1.f));
      float p1 = __expf(__fdividef(-100.f, e21 + 1.f));
      bool ok0 = am0 && (!needmask || (k0 + fr) <= qg);
      bool ok1 = am1 && (!needmask || (k0 + 16 + fr) <= qg);
      p0 = ok0 ? p0 : 0.f;
      p1 = ok1 ? p1 : 0.f;
      Pl[wave][qrow * 32 + (fr ^ (r << 3))] = f2bf(p0);
      Pl[wave][qrow * 32 + ((16 + fr) ^ (r << 3))] = f2bf(p1);
    }
    asm volatile("s_waitcnt lgkmcnt(0)" ::: "memory");   // own P writes + K reads drained
    __builtin_amdgcn_sched_barrier(0);
    if (more)
      asm volatile("s_waitcnt vmcnt(4)" ::: "memory");   // retire V(t); K(t+2) stays in flight
    else
      asm volatile("s_waitcnt vmcnt(0)" ::: "memory");
    __builtin_amdgcn_sched_barrier(0);
    __builtin_amdgcn_s_barrier();                        // BAR-C: all waves' V(t) visible
    __builtin_amdgcn_sched_barrier(0);

    // ---- PV (per-wave P) ----
    s16x8 pf = *(const s16x8*)&Pl[wave][fr * 32 + ((fq * 8) ^ psw)];
    __builtin_amdgcn_s_setprio(1);
    lacc = mfma16(pf, onesv, lacc);
#pragma unroll
    for (int df = 0; df < 16; df++) {
      s16x8 vv = *(const s16x8*)&Vl[(df * 16 + fr) * 32 + ((fq ^ vswl) * 8)];
      oacc[df] = mfma16(pf, vv, oacc[df]);
    }
    __builtin_amdgcn_s_setprio(0);
    asm volatile("s_waitcnt lgkmcnt(0)" ::: "memory");   // own V reads done (before next BAR-A)
    __builtin_amdgcn_sched_barrier(0);
    kb ^= 1;
  }

  // ---- write unnormalized bf16 partial O and f32 partial l ----
  if (fr == 0) {
#pragma unroll
    for (int r = 0; r < 4; r++)
      Lp[(size_t)(b * S_ + q0 + wave * 16 + fq * 4 + r) * 8 + h] = lacc[r];
  }
#pragma unroll
  for (int df = 0; df < 16; df++) {
#pragma unroll
    for (int r = 0; r < 4; r++) {
      Op[(size_t)(b * S_ + q0 + wave * 16 + fq * 4 + r) * 2048 + h * 256 + df * 16 + fr] =
          f2bf(oacc[df][r]);
    }
  }
}

// ---------------- combine partial halves: AO = (O0+O1)/(l0+l1) ----------------
__global__ void combine_o(const u16* __restrict__ O0, const u16* __restrict__ O1,
                          const float* __restrict__ L0, const float* __restrict__ L1,
                          u16* __restrict__ AO) {
  int idx = blockIdx.x * blockDim.x + threadIdx.x;   // 4096 rows x 256 groups of 8 cols
  int row = idx >> 8;
  int cg = idx & 255;
  int h = cg >> 5;
  float rinv = 1.0f / (L0[row * 8 + h] + L1[row * 8 + h]);
  size_t base = (size_t)row * 2048 + cg * 8;
  s16x8 a = *(const s16x8*)(O0 + base);
  s16x8 b = *(const s16x8*)(O1 + base);
  s16x8 o;
#pragma unroll
  for (int j = 0; j < 8; j++)
    o[j] = (short)f2bf((bf2f((u16)a[j]) + bf2f((u16)b[j])) * rinv);
  *(s16x8*)(AO + base) = o;
}

extern "C" void kernel_launch(void* const* d_in, const int* in_sizes, int n_in,
                              void* d_out, int out_size, void* d_ws, size_t ws_size,
                              hipStream_t stream) {
  const float* X   = (const float*)d_in[0];   // [B,S,H] fp32
  const int* amask = (const int*)d_in[1];
  const int* pos   = (const int*)d_in[2];
  const float* Wq  = (const float*)d_in[3];
  const float* Wk  = (const float*)d_in[4];
  const float* Wv  = (const float*)d_in[5];
  const float* Wo  = (const float*)d_in[6];
  float* out = (float*)d_out;                 // [B,S,H] fp32

  char* ws = (char*)d_ws;
  size_t off = 0;
  auto allocB = [&](size_t bytes) {
    char* p = ws + off;
    off += ((bytes + 255) & ~(size_t)255);
    return p;
  };
  u16* Xb   = (u16*)allocB((size_t)4096 * 2304 * 2);
  u16* WqT  = (u16*)allocB((size_t)2048 * 2304 * 2);   // WqT/WkT/WvT contiguous => fused B^T
  u16* WkT  = (u16*)allocB((size_t)1024 * 2304 * 2);
  u16* WvT  = (u16*)allocB((size_t)1024 * 2304 * 2);
  u16* WoT  = (u16*)allocB((size_t)2304 * 2048 * 2);
  u16* QKV  = (u16*)allocB((size_t)4096 * 4096 * 2);
  u16* VTb  = (u16*)allocB((size_t)4096 * 1024 * 2);
  u16* AO   = (u16*)allocB((size_t)4096 * 2048 * 2);
  float* CT = (float*)allocB((size_t)2048 * 128 * 4);
  float* ST = (float*)allocB((size_t)2048 * 128 * 4);
  float* Lp0 = (float*)allocB((size_t)4096 * 8 * 4);
  float* Lp1 = (float*)allocB((size_t)4096 * 8 * 4);
  // O partials ALIAS the Xb/WqT/WkT/WvT-head region (dead after gemm256)
  u16* Op0 = (u16*)ws;
  u16* Op1 = Op0 + (size_t)4096 * 2048;
  if (off > ws_size) return;

  // RoPE table (independent; early)
  rope_table<<<(2048 * 128) / 256, 256, 0, stream>>>(CT, ST);

  // hidden_states fp32 -> bf16
  {
    size_t n = (size_t)4096 * 2304;
    f32_to_bf16<<<(unsigned)((n / 4 + 255) / 256), 256, 0, stream>>>(X, Xb, n);
  }

  dim3 tb(32, 8);
  transpose_f32_bf16<<<dim3(2048 / 32, 2304 / 32), tb, 0, stream>>>(Wq, WqT, 2304, 2048);
  transpose_f32_bf16<<<dim3(1024 / 32, 2304 / 32), tb, 0, stream>>>(Wk, WkT, 2304, 1024);
  transpose_f32_bf16<<<dim3(1024 / 32, 2304 / 32), tb, 0, stream>>>(Wv, WvT, 2304, 1024);
  transpose_f32_bf16<<<dim3(2304 / 32, 2048 / 32), tb, 0, stream>>>(Wo, WoT, 2048, 2304);

  // fused QKV projection (256² 1-phase counted)  [Xb/WqT/WkT/WvT dead after this]
  gemm256<false><<<dim3(4096 / 256, 4096 / 256), 512, 0, stream>>>(Xb, WqT, QKV, 4096, 4096, 2304);

  // RoPE on K only (Q roped in-register inside attn)
  rope_k<<<(4096 * 4 * 16) / 256, 256, 0, stream>>>(QKV, pos, CT, ST);

  // V (QKV cols 3072..4095) -> VT[b][kv][d][s]
  transpose_bf16_s<<<dim3(1024 / 32, 2048 / 32, 2), tb, 0, stream>>>(
      QKV + 3072, VTb, 2048, 1024, 4096, (size_t)2048 * 4096, (size_t)1024 * 2048);

  // attention: key-split grid 1024, XCD-pinned (b,g), 2-barrier pipeline
  attn_kernel<<<dim3(1024), 256, 0, stream>>>(QKV, VTb, amask, pos, CT, ST, Op0, Op1, Lp0, Lp1);

  // combine halves -> AO bf16
  combine_o<<<4096, 256, 0, stream>>>(Op0, Op1, Lp0, Lp1, AO);

  // output projection -> fp32 d_out (128² BK=32 pipelined)
  gemm128<true><<<dim3(2304 / 128, 4096 / 128), 256, 0, stream>>>(AO, WoT, out, 4096, 2304, 2048);
}

// Round 18
// 248.371 us; speedup vs baseline: 1.0892x; 1.0542x over previous
//
#include <hip/hip_runtime.h>
#include <hip/hip_bf16.h>
#include <stdint.h>

typedef unsigned short u16;
typedef __attribute__((ext_vector_type(8))) short s16x8;
typedef __attribute__((ext_vector_type(4))) float f32x4;

#define B_ 2
#define S_ 2048
#define H_ 2304
#define NH_ 8
#define NKV_ 4
#define HD_ 256

__device__ __forceinline__ float bf2f(u16 u) {
  union { uint32_t i; float f; } x; x.i = ((uint32_t)u) << 16; return x.f;
}
__device__ __forceinline__ u16 f2bf(float f) {
  union { float f; uint32_t i; } x; x.f = f;
  uint32_t u = x.i;
  return (u16)((u + 0x7fffu + ((u >> 16) & 1u)) >> 16);
}

__device__ __forceinline__ void async16(const void* g, void* l) {
  __builtin_amdgcn_global_load_lds((const __attribute__((address_space(1))) uint32_t*)g,
                                   (__attribute__((address_space(3))) uint32_t*)l, 16, 0, 0);
}

__device__ __forceinline__ f32x4 mfma16(s16x8 a, s16x8 b, f32x4 c) {
  return __builtin_amdgcn_mfma_f32_16x16x32_bf16(a, b, c, 0, 0, 0);
}

// ================= fused prep: rope table + X convert + 4 weight transposes =================
// All sections independent (disjoint outputs); branch is block-uniform so __syncthreads is safe.
// Section map (flat blockIdx.x):
//   [0,1024)        rope_table            (2048x128 table)
//   [1024,10240)    f32_to_bf16 of X      (9,437,184 elems, 1024/block)
//   [10240,14848)   Wq^T  (R=2304,C=2048) 64x72 tiles
//   [14848,17152)   Wk^T  (R=2304,C=1024) 32x72 tiles
//   [17152,19456)   Wv^T  (R=2304,C=1024) 32x72 tiles
//   [19456,24064)   Wo^T  (R=2048,C=2304) 72x64 tiles
__global__ __launch_bounds__(256) void prep_kernel(
    const float* __restrict__ X, u16* __restrict__ Xb,
    const float* __restrict__ Wq, u16* __restrict__ WqT,
    const float* __restrict__ Wk, u16* __restrict__ WkT,
    const float* __restrict__ Wv, u16* __restrict__ WvT,
    const float* __restrict__ Wo, u16* __restrict__ WoT,
    float* __restrict__ ct, float* __restrict__ st) {
  __shared__ u16 tile[32][33];
  int bid = blockIdx.x, tid = threadIdx.x;

  auto tposeT = [&](const float* in, u16* out, int R, int C, int bx, int by) {
    int c0 = bx * 32, r0 = by * 32;
    int x = tid & 31, y = tid >> 5;
#pragma unroll
    for (int j = 0; j < 32; j += 8)
      tile[y + j][x] = f2bf(in[(size_t)(r0 + y + j) * C + c0 + x]);
    __syncthreads();
#pragma unroll
    for (int j = 0; j < 32; j += 8)
      out[(size_t)(c0 + y + j) * R + r0 + x] = tile[x][y + j];
  };

  if (bid < 1024) {
    int t = bid * 256 + tid;                       // t = p*128 + d
    int d = t & 127;
    int p = t >> 7;
    float invf = exp2f(-(float)d * 0.1038102530f); // log2(10000)/128
    float f = (float)p * invf;
    float s, c;
    sincosf(f, &s, &c);
    ct[t] = c;
    st[t] = s;
  } else if (bid < 10240) {
    size_t i = ((size_t)(bid - 1024) * 256 + tid) * 4;
    float4 v = *(const float4*)(X + i);
    ushort4 o;
    o.x = f2bf(v.x); o.y = f2bf(v.y); o.z = f2bf(v.z); o.w = f2bf(v.w);
    *(ushort4*)(Xb + i) = o;
  } else if (bid < 14848) {
    int b2 = bid - 10240;
    tposeT(Wq, WqT, 2304, 2048, b2 & 63, b2 >> 6);
  } else if (bid < 17152) {
    int b2 = bid - 14848;
    tposeT(Wk, WkT, 2304, 1024, b2 & 31, b2 >> 5);
  } else if (bid < 19456) {
    int b2 = bid - 17152;
    tposeT(Wv, WvT, 2304, 1024, b2 & 31, b2 >> 5);
  } else {
    int b2 = bid - 19456;
    tposeT(Wo, WoT, 2048, 2304, b2 % 72, b2 / 72);
  }
}

// ------- strided-batch bf16 transpose: in[z*zin + r*istride + c] -> out[z*zout + c*R + r] -------
__global__ void transpose_bf16_s(const u16* __restrict__ in, u16* __restrict__ out, int R, int C,
                                 int istride, size_t zin, size_t zout) {
  __shared__ u16 tile[32][33];
  in += (size_t)blockIdx.z * zin;
  out += (size_t)blockIdx.z * zout;
  int c0 = blockIdx.x * 32, r0 = blockIdx.y * 32;
  int x = threadIdx.x, y = threadIdx.y;
#pragma unroll
  for (int j = 0; j < 32; j += 8)
    tile[y + j][x] = in[(size_t)(r0 + y + j) * istride + c0 + x];
  __syncthreads();
#pragma unroll
  for (int j = 0; j < 32; j += 8)
    out[(size_t)(c0 + y + j) * R + r0 + x] = tile[x][y + j];
}

// ================= 256x256 deep-pipelined GEMM (1-phase counted schedule) =================
template <bool F32OUT>
__global__ __launch_bounds__(512) void gemm256(const u16* __restrict__ A, const u16* __restrict__ BT,
                                               void* __restrict__ Cout, int M, int N, int Kd) {
  __shared__ u16 As[2][256 * 64];
  __shared__ u16 Bs[2][256 * 64];
  int tid = threadIdx.x, lane = tid & 63, wave = tid >> 6;
  int nT = gridDim.x * gridDim.y;
  int bid = blockIdx.y * gridDim.x + blockIdx.x;
  int tile = (bid & 7) * (nT >> 3) + (bid >> 3);        // XCD swizzle (nT % 8 == 0)
  int bn = (tile % gridDim.x) * 256;
  int bm = (tile / gridDim.x) * 256;
  int wm = (wave >> 2) * 128, wn = (wave & 3) * 64;
  int fr = lane & 15, fq = lane >> 4;
  f32x4 acc[8][4];
#pragma unroll
  for (int i = 0; i < 8; i++)
#pragma unroll
    for (int j = 0; j < 4; j++) acc[i][j] = (f32x4){0.f, 0.f, 0.f, 0.f};

  int srow = tid >> 3, sslot = tid & 7;
  int scol = (sslot * 8) ^ ((srow & 7) << 3);           // pre-swizzled source col (u16 units)
  const u16* Ab = A + (size_t)(bm + srow) * Kd + scol;
  const u16* Bb = BT + (size_t)(bn + srow) * Kd + scol;

  auto stage = [&](int buf, int k0) {
#pragma unroll
    for (int i = 0; i < 4; i++) {
      async16(Ab + (size_t)i * 64 * Kd + k0, (char*)&As[buf][0] + wave * 1024 + i * 8192);
      async16(Bb + (size_t)i * 64 * Kd + k0, (char*)&Bs[buf][0] + wave * 1024 + i * 8192);
    }
  };

  int NT = Kd >> 6;
  int rsw = (fr & 7) << 3;
  stage(0, 0);
  for (int t = 0; t < NT; ++t) {
    if (t + 1 < NT) {
      stage((t + 1) & 1, (t + 1) << 6);
      asm volatile("s_waitcnt vmcnt(8)" ::: "memory");
    } else {
      asm volatile("s_waitcnt vmcnt(0)" ::: "memory");
    }
    __builtin_amdgcn_sched_barrier(0);
    __builtin_amdgcn_s_barrier();
    __builtin_amdgcn_sched_barrier(0);
    const u16* Ap = &As[t & 1][0];
    const u16* Bp = &Bs[t & 1][0];
    __builtin_amdgcn_s_setprio(1);
    s16x8 bfr[4][2];
#pragma unroll
    for (int j = 0; j < 4; j++)
#pragma unroll
      for (int s = 0; s < 2; s++)
        bfr[j][s] = *(const s16x8*)&Bp[(wn + j * 16 + fr) * 64 + ((s * 32 + fq * 8) ^ rsw)];
#pragma unroll
    for (int i = 0; i < 8; i++) {
      s16x8 a0 = *(const s16x8*)&Ap[(wm + i * 16 + fr) * 64 + ((fq * 8) ^ rsw)];
      s16x8 a1 = *(const s16x8*)&Ap[(wm + i * 16 + fr) * 64 + ((32 + fq * 8) ^ rsw)];
#pragma unroll
      for (int j = 0; j < 4; j++) {
        acc[i][j] = mfma16(a0, bfr[j][0], acc[i][j]);
        acc[i][j] = mfma16(a1, bfr[j][1], acc[i][j]);
      }
    }
    __builtin_amdgcn_s_setprio(0);
    asm volatile("s_waitcnt lgkmcnt(0)" ::: "memory");
    __builtin_amdgcn_sched_barrier(0);
    __builtin_amdgcn_s_barrier();
  }

#pragma unroll
  for (int i = 0; i < 8; i++)
#pragma unroll
    for (int j = 0; j < 4; j++)
#pragma unroll
      for (int r = 0; r < 4; r++) {
        int row = bm + wm + i * 16 + fq * 4 + r;
        int col = bn + wn + j * 16 + fr;
        if (F32OUT) ((float*)Cout)[(size_t)row * N + col] = acc[i][j][r];
        else        ((u16*)Cout)[(size_t)row * N + col] = f2bf(acc[i][j][r]);
      }
}

// ================= 128x128 pipelined GEMM, BK=32 =================
template <bool F32OUT>
__global__ __launch_bounds__(256) void gemm128(const u16* __restrict__ A, const u16* __restrict__ BT,
                                               void* __restrict__ Cout, int M, int N, int Kd) {
  __shared__ u16 As[2][128 * 32];
  __shared__ u16 Bs[2][128 * 32];
  int tid = threadIdx.x, lane = tid & 63, wave = tid >> 6;
  int nT = gridDim.x * gridDim.y;
  int bid = blockIdx.y * gridDim.x + blockIdx.x;
  int tile = (bid & 7) * (nT >> 3) + (bid >> 3);
  int bn = (tile % gridDim.x) * 128;
  int bm = (tile / gridDim.x) * 128;
  int wm = (wave >> 1) * 64, wn = (wave & 1) * 64;
  int fr = lane & 15, fq = lane >> 4;
  f32x4 acc[4][4];
#pragma unroll
  for (int i = 0; i < 4; i++)
#pragma unroll
    for (int j = 0; j < 4; j++) acc[i][j] = (f32x4){0.f, 0.f, 0.f, 0.f};

  int srow = tid >> 2, sslot = tid & 3;
  int scol = (sslot * 8) ^ ((srow & 3) << 3);
  const u16* Ab = A + (size_t)(bm + srow) * Kd + scol;
  const u16* Bb = BT + (size_t)(bn + srow) * Kd + scol;

  auto stage = [&](int buf, int k0) {
    async16(Ab + k0, (char*)&As[buf][0] + wave * 1024);
    async16(Ab + (size_t)64 * Kd + k0, (char*)&As[buf][0] + wave * 1024 + 4096);
    async16(Bb + k0, (char*)&Bs[buf][0] + wave * 1024);
    async16(Bb + (size_t)64 * Kd + k0, (char*)&Bs[buf][0] + wave * 1024 + 4096);
  };

  int NT = Kd >> 5;
  int rsw = (fr & 3) << 3;
  stage(0, 0);
  for (int t = 0; t < NT; ++t) {
    if (t + 1 < NT) {
      stage((t + 1) & 1, (t + 1) << 5);
      asm volatile("s_waitcnt vmcnt(4)" ::: "memory");
    } else {
      asm volatile("s_waitcnt vmcnt(0)" ::: "memory");
    }
    __builtin_amdgcn_sched_barrier(0);
    __builtin_amdgcn_s_barrier();
    __builtin_amdgcn_sched_barrier(0);
    const u16* Ap = &As[t & 1][0];
    const u16* Bp = &Bs[t & 1][0];
    __builtin_amdgcn_s_setprio(1);
    s16x8 af[4], bv[4];
#pragma unroll
    for (int i = 0; i < 4; i++) af[i] = *(const s16x8*)&Ap[(wm + i * 16 + fr) * 32 + ((fq * 8) ^ rsw)];
#pragma unroll
    for (int j = 0; j < 4; j++) bv[j] = *(const s16x8*)&Bp[(wn + j * 16 + fr) * 32 + ((fq * 8) ^ rsw)];
#pragma unroll
    for (int i = 0; i < 4; i++)
#pragma unroll
      for (int j = 0; j < 4; j++)
        acc[i][j] = mfma16(af[i], bv[j], acc[i][j]);
    __builtin_amdgcn_s_setprio(0);
    asm volatile("s_waitcnt lgkmcnt(0)" ::: "memory");
    __builtin_amdgcn_sched_barrier(0);
    __builtin_amdgcn_s_barrier();
  }
#pragma unroll
  for (int i = 0; i < 4; i++)
#pragma unroll
    for (int j = 0; j < 4; j++)
#pragma unroll
      for (int r = 0; r < 4; r++) {
        int row = bm + wm + i * 16 + fq * 4 + r;
        int col = bn + wn + j * 16 + fr;
        if (F32OUT) ((float*)Cout)[(size_t)row * N + col] = acc[i][j][r];
        else        ((u16*)Cout)[(size_t)row * N + col] = f2bf(acc[i][j][r]);
      }
}

// ---------------- RoPE on K columns of fused QKV (8 pairs per thread) ----------------
__global__ void rope_k(u16* __restrict__ QKV, const int* __restrict__ pos_ids,
                       const float* __restrict__ ct, const float* __restrict__ st) {
  int t = blockIdx.x * blockDim.x + threadIdx.x;   // 4096 rows * 4 heads * 16 dgroups
  int dg = t & 15, h = (t >> 4) & 3, row = t >> 6;
  u16* p1 = QKV + (size_t)row * 4096 + 2048 + h * 256 + dg * 8;
  u16* p2 = p1 + 128;
  int pos = pos_ids[row];
  const float* ctp = ct + pos * 128 + dg * 8;
  const float* stp = st + pos * 128 + dg * 8;
  s16x8 v1 = *(const s16x8*)p1, v2 = *(const s16x8*)p2;
#pragma unroll
  for (int j = 0; j < 8; j++) {
    float c = ctp[j], s = stp[j];
    float a = bf2f((u16)v1[j]);
    float b = bf2f((u16)v2[j]);
    v1[j] = (short)f2bf(a * c - b * s);
    v2[j] = (short)f2bf(b * c + a * s);
  }
  *(s16x8*)p1 = v1;
  *(s16x8*)p2 = v2;
}

// ---------------- flash attention, KEY-SPLIT, 2-barrier race-free pipeline ----------
// grid 1024; id&7 = b*4+g pinned per XCD (KV L2-resident); qt heavy-first.
// Per tile: vmcnt(0) -> BAR-A -> stage V(t), K(t+2) -> QK^T/softmax/Pwrite -> lgkm0
//           -> vmcnt(4) -> BAR-C -> PV -> lgkm0.
__global__ __launch_bounds__(256) void attn_kernel(const u16* __restrict__ QKV, const u16* __restrict__ VT,
                                                   const int* __restrict__ amask, const int* __restrict__ pos_ids,
                                                   const float* __restrict__ ct, const float* __restrict__ st,
                                                   u16* __restrict__ O0, u16* __restrict__ O1,
                                                   float* __restrict__ L0, float* __restrict__ L1) {
  __shared__ u16 Kl[2][32 * 256];        // K double buffer; granule swz: slot ^= key&7
  __shared__ u16 Vl[256 * 32];           // V single buffer; granule swz: slot ^= (hd>>1)&3
  __shared__ u16 Pl[4][16 * 32];         // per-wave P, XOR-swizzled cols
  __shared__ unsigned char Mb[256];      // bit-packed amask (2048 bits)
  int id = blockIdx.x;
  int bg = id & 7;                        // XCD-pinned (b,g)
  int r_ = id >> 3;
  int qt = 31 - (r_ >> 2);                // heavy first
  int hl = (r_ >> 1) & 1;
  int half = r_ & 1;
  int b = bg >> 2, g = bg & 3;
  int h = g * 2 + hl;
  int tid = threadIdx.x, lane = tid & 63, wave = tid >> 6;
  int fr = lane & 15, fq = lane >> 4;
  int q0 = qt * 64;
  u16* Op = half ? O1 : O0;
  float* Lp = half ? L1 : L0;

  // ---- bit-pack attention mask: thread t packs ints 8t..8t+7 into byte Mb[t] ----
  const int* amp = amask + b * S_;
  {
    int4 a = *(const int4*)(amp + tid * 8);
    int4 c = *(const int4*)(amp + tid * 8 + 4);
    unsigned v = (unsigned)(a.x > 0) | ((unsigned)(a.y > 0) << 1) | ((unsigned)(a.z > 0) << 2) |
                 ((unsigned)(a.w > 0) << 3) | ((unsigned)(c.x > 0) << 4) | ((unsigned)(c.y > 0) << 5) |
                 ((unsigned)(c.z > 0) << 6) | ((unsigned)(c.w > 0) << 7);
    Mb[tid] = (unsigned char)v;
  }

  // ---- load Q rows wave*16+fr, apply RoPE in-register, scale 1/16 ----
  int qrow_g = b * S_ + q0 + wave * 16 + fr;
  s16x8 qr[8];
  const u16* qb = QKV + (size_t)qrow_g * 4096 + h * 256 + fq * 8;
#pragma unroll
  for (int kk = 0; kk < 8; kk++) qr[kk] = *(const s16x8*)(qb + kk * 32);
  int pos = pos_ids[qrow_g];
  const float* ctp = ct + pos * 128 + fq * 8;
  const float* stp = st + pos * 128 + fq * 8;
  s16x8 qf[8];
#pragma unroll
  for (int kk = 0; kk < 4; kk++) {
#pragma unroll
    for (int jj = 0; jj < 8; jj++) {
      float c = ctp[kk * 32 + jj], s = stp[kk * 32 + jj];
      float a = bf2f((u16)qr[kk][jj]);
      float bb = bf2f((u16)qr[kk + 4][jj]);
      qf[kk][jj]     = (short)f2bf((a * c - bb * s) * 0.0625f);
      qf[kk + 4][jj] = (short)f2bf((bb * c + a * s) * 0.0625f);
    }
  }

  f32x4 zero4 = {0.f, 0.f, 0.f, 0.f};
  f32x4 oacc[16];
#pragma unroll
  for (int i = 0; i < 16; i++) oacc[i] = zero4;
  f32x4 lacc = zero4;
  s16x8 onesv;
#pragma unroll
  for (int i = 0; i < 8; i++) onesv[i] = (short)0x3F80;

  const u16* Kbase = QKV + (size_t)b * S_ * 4096 + 2048 + g * 256;
  const u16* Vbase = VT + (size_t)(b * 4 + g) * 256 * S_;

  // ---- staging pointers: 1024 granules each for K,V; 4 K + 4 V per thread ----
  const u16* KsP[4];
  const u16* VsP[4];
  int dst16[4];
#pragma unroll
  for (int i = 0; i < 4; i++) {
    int c = tid + i * 256;
    int key = c >> 5, slot = c & 31;
    KsP[i] = Kbase + (size_t)key * 4096 + ((slot ^ (key & 7)) * 8);
    int hd = c >> 2, vs = c & 3;
    VsP[i] = Vbase + (size_t)hd * 2048 + ((vs ^ ((hd >> 1) & 3)) * 8);
    dst16[i] = c * 16;
  }

  __syncthreads();                                  // Mb visible; all prologue vmem drained

  // prologue: stage K(half)
#pragma unroll
  for (int i = 0; i < 4; i++)
    async16(KsP[i] + (size_t)(half * 32) * 4096, (char*)&Kl[0][0] + dst16[i]);

  int nt = 2 * qt + 2;
  int ksw = fr & 7;
  int vswl = (fr >> 1) & 3;
  int psw = (fr & 3) << 3;
  int kb = 0;
  for (int t = half; t < nt; t += 2) {
    int k0 = t * 32;
    bool more = (t + 2 < nt);
    asm volatile("s_waitcnt vmcnt(0)" ::: "memory");     // retire K(t) (issued ~1 iter ago)
    __builtin_amdgcn_sched_barrier(0);
    __builtin_amdgcn_s_barrier();                        // BAR-A: all waves' K(t) visible;
    __builtin_amdgcn_sched_barrier(0);                   //   also V-WAR fence

    // stage V(t) then K(t+2): FIFO order V older than K for the vmcnt(4) below
#pragma unroll
    for (int i = 0; i < 4; i++)
      async16(VsP[i] + k0, (char*)&Vl[0] + dst16[i]);
    if (more) {
#pragma unroll
      for (int i = 0; i < 4; i++)
        async16(KsP[i] + (size_t)(k0 + 64) * 4096, (char*)&Kl[kb ^ 1][0] + dst16[i]);
    }

    // ---- QK^T: keys {fr, 16+fr} x 32-wide K tile ----
    const u16* Kp = &Kl[kb][0];
    __builtin_amdgcn_s_setprio(1);
    f32x4 s0 = zero4, s1 = zero4;
#pragma unroll
    for (int kk = 0; kk < 8; kk++) {
      s16x8 b0 = *(const s16x8*)&Kp[fr * 256 + (((kk * 4 + fq) ^ ksw) * 8)];
      s16x8 b1 = *(const s16x8*)&Kp[(16 + fr) * 256 + (((kk * 4 + fq) ^ ksw) * 8)];
      s0 = mfma16(qf[kk], b0, s0);
      s1 = mfma16(qf[kk], b1, s1);
    }
    __builtin_amdgcn_s_setprio(0);

    int am0 = (Mb[(k0 + fr) >> 3] >> ((k0 + fr) & 7)) & 1;
    int am1 = (Mb[(k0 + 16 + fr) >> 3] >> ((k0 + 16 + fr) & 7)) & 1;
    bool needmask = (t >= nt - 2);
#pragma unroll
    for (int r = 0; r < 4; r++) {
      int qrow = fq * 4 + r;
      int qg = q0 + wave * 16 + qrow;
      // p = exp(50*tanh(s/50) - 50) = exp(-100/(exp(0.04*s)+1))  [fixed max 50]
      float e20 = __expf(s0[r] * 0.04f);
      float e21 = __expf(s1[r] * 0.04f);
      float p0 = __expf(__fdividef(-100.f, e20 + 1.f));
      float p1 = __expf(__fdividef(-100.f, e21 + 1.f));
      bool ok0 = am0 && (!needmask || (k0 + fr) <= qg);
      bool ok1 = am1 && (!needmask || (k0 + 16 + fr) <= qg);
      p0 = ok0 ? p0 : 0.f;
      p1 = ok1 ? p1 : 0.f;
      Pl[wave][qrow * 32 + (fr ^ (r << 3))] = f2bf(p0);
      Pl[wave][qrow * 32 + ((16 + fr) ^ (r << 3))] = f2bf(p1);
    }
    asm volatile("s_waitcnt lgkmcnt(0)" ::: "memory");   // own P writes + K reads drained
    __builtin_amdgcn_sched_barrier(0);
    if (more)
      asm volatile("s_waitcnt vmcnt(4)" ::: "memory");   // retire V(t); K(t+2) stays in flight
    else
      asm volatile("s_waitcnt vmcnt(0)" ::: "memory");
    __builtin_amdgcn_sched_barrier(0);
    __builtin_amdgcn_s_barrier();                        // BAR-C: all waves' V(t) visible
    __builtin_amdgcn_sched_barrier(0);

    // ---- PV (per-wave P) ----
    s16x8 pf = *(const s16x8*)&Pl[wave][fr * 32 + ((fq * 8) ^ psw)];
    __builtin_amdgcn_s_setprio(1);
    lacc = mfma16(pf, onesv, lacc);
#pragma unroll
    for (int df = 0; df < 16; df++) {
      s16x8 vv = *(const s16x8*)&Vl[(df * 16 + fr) * 32 + ((fq ^ vswl) * 8)];
      oacc[df] = mfma16(pf, vv, oacc[df]);
    }
    __builtin_amdgcn_s_setprio(0);
    asm volatile("s_waitcnt lgkmcnt(0)" ::: "memory");   // own V reads done (before next BAR-A)
    __builtin_amdgcn_sched_barrier(0);
    kb ^= 1;
  }

  // ---- write unnormalized bf16 partial O and f32 partial l ----
  if (fr == 0) {
#pragma unroll
    for (int r = 0; r < 4; r++)
      Lp[(size_t)(b * S_ + q0 + wave * 16 + fq * 4 + r) * 8 + h] = lacc[r];
  }
#pragma unroll
  for (int df = 0; df < 16; df++) {
#pragma unroll
    for (int r = 0; r < 4; r++) {
      Op[(size_t)(b * S_ + q0 + wave * 16 + fq * 4 + r) * 2048 + h * 256 + df * 16 + fr] =
          f2bf(oacc[df][r]);
    }
  }
}

// ---------------- combine partial halves: AO = (O0+O1)/(l0+l1) ----------------
__global__ void combine_o(const u16* __restrict__ O0, const u16* __restrict__ O1,
                          const float* __restrict__ L0, const float* __restrict__ L1,
                          u16* __restrict__ AO) {
  int idx = blockIdx.x * blockDim.x + threadIdx.x;   // 4096 rows x 256 groups of 8 cols
  int row = idx >> 8;
  int cg = idx & 255;
  int h = cg >> 5;
  float rinv = 1.0f / (L0[row * 8 + h] + L1[row * 8 + h]);
  size_t base = (size_t)row * 2048 + cg * 8;
  s16x8 a = *(const s16x8*)(O0 + base);
  s16x8 b = *(const s16x8*)(O1 + base);
  s16x8 o;
#pragma unroll
  for (int j = 0; j < 8; j++)
    o[j] = (short)f2bf((bf2f((u16)a[j]) + bf2f((u16)b[j])) * rinv);
  *(s16x8*)(AO + base) = o;
}

extern "C" void kernel_launch(void* const* d_in, const int* in_sizes, int n_in,
                              void* d_out, int out_size, void* d_ws, size_t ws_size,
                              hipStream_t stream) {
  const float* X   = (const float*)d_in[0];   // [B,S,H] fp32
  const int* amask = (const int*)d_in[1];
  const int* pos   = (const int*)d_in[2];
  const float* Wq  = (const float*)d_in[3];
  const float* Wk  = (const float*)d_in[4];
  const float* Wv  = (const float*)d_in[5];
  const float* Wo  = (const float*)d_in[6];
  float* out = (float*)d_out;                 // [B,S,H] fp32

  char* ws = (char*)d_ws;
  size_t off = 0;
  auto allocB = [&](size_t bytes) {
    char* p = ws + off;
    off += ((bytes + 255) & ~(size_t)255);
    return p;
  };
  u16* Xb   = (u16*)allocB((size_t)4096 * 2304 * 2);
  u16* WqT  = (u16*)allocB((size_t)2048 * 2304 * 2);   // WqT/WkT/WvT contiguous => fused B^T
  u16* WkT  = (u16*)allocB((size_t)1024 * 2304 * 2);
  u16* WvT  = (u16*)allocB((size_t)1024 * 2304 * 2);
  u16* WoT  = (u16*)allocB((size_t)2304 * 2048 * 2);
  u16* QKV  = (u16*)allocB((size_t)4096 * 4096 * 2);
  u16* VTb  = (u16*)allocB((size_t)4096 * 1024 * 2);
  u16* AO   = (u16*)allocB((size_t)4096 * 2048 * 2);
  float* CT = (float*)allocB((size_t)2048 * 128 * 4);
  float* ST = (float*)allocB((size_t)2048 * 128 * 4);
  float* Lp0 = (float*)allocB((size_t)4096 * 8 * 4);
  float* Lp1 = (float*)allocB((size_t)4096 * 8 * 4);
  // O partials ALIAS the Xb/WqT/WkT/WvT-head region (dead after gemm256)
  u16* Op0 = (u16*)ws;
  u16* Op1 = Op0 + (size_t)4096 * 2048;
  if (off > ws_size) return;

  // fused prep: rope table + X convert + 4 weight transposes (one launch)
  prep_kernel<<<24064, 256, 0, stream>>>(X, Xb, Wq, WqT, Wk, WkT, Wv, WvT, Wo, WoT, CT, ST);

  // fused QKV projection (256² 1-phase counted)  [Xb/WqT/WkT/WvT dead after this]
  gemm256<false><<<dim3(4096 / 256, 4096 / 256), 512, 0, stream>>>(Xb, WqT, QKV, 4096, 4096, 2304);

  // RoPE on K only (Q roped in-register inside attn)
  rope_k<<<(4096 * 4 * 16) / 256, 256, 0, stream>>>(QKV, pos, CT, ST);

  // V (QKV cols 3072..4095) -> VT[b][kv][d][s]
  transpose_bf16_s<<<dim3(1024 / 32, 2048 / 32, 2), dim3(32, 8), 0, stream>>>(
      QKV + 3072, VTb, 2048, 1024, 4096, (size_t)2048 * 4096, (size_t)1024 * 2048);

  // attention: key-split grid 1024, XCD-pinned (b,g), 2-barrier pipeline
  attn_kernel<<<dim3(1024), 256, 0, stream>>>(QKV, VTb, amask, pos, CT, ST, Op0, Op1, Lp0, Lp1);

  // combine halves -> AO bf16
  combine_o<<<4096, 256, 0, stream>>>(Op0, Op1, Lp0, Lp1, AO);

  // output projection -> fp32 d_out (128² BK=32 pipelined)
  gemm128<true><<<dim3(2304 / 128, 4096 / 128), 256, 0, stream>>>(AO, WoT, out, 4096, 2304, 2048);
}

// Round 21
// 246.593 us; speedup vs baseline: 1.0971x; 1.0072x over previous
//
#include <hip/hip_runtime.h>
#include <hip/hip_bf16.h>
#include <stdint.h>

typedef unsigned short u16;
typedef __attribute__((ext_vector_type(8))) short s16x8;
typedef __attribute__((ext_vector_type(4))) float f32x4;

#define B_ 2
#define S_ 2048
#define H_ 2304
#define NH_ 8
#define NKV_ 4
#define HD_ 256

__device__ __forceinline__ float bf2f(u16 u) {
  union { uint32_t i; float f; } x; x.i = ((uint32_t)u) << 16; return x.f;
}
__device__ __forceinline__ u16 f2bf(float f) {
  union { float f; uint32_t i; } x; x.f = f;
  uint32_t u = x.i;
  return (u16)((u + 0x7fffu + ((u >> 16) & 1u)) >> 16);
}

__device__ __forceinline__ void async16(const void* g, void* l) {
  __builtin_amdgcn_global_load_lds((const __attribute__((address_space(1))) uint32_t*)g,
                                   (__attribute__((address_space(3))) uint32_t*)l, 16, 0, 0);
}

__device__ __forceinline__ f32x4 mfma16(s16x8 a, s16x8 b, f32x4 c) {
  return __builtin_amdgcn_mfma_f32_16x16x32_bf16(a, b, c, 0, 0, 0);
}

// ================= fused prep: rope table + X convert + 4 weight transposes =================
// All sections independent (disjoint outputs); branch is block-uniform so __syncthreads is safe.
__global__ __launch_bounds__(256) void prep_kernel(
    const float* __restrict__ X, u16* __restrict__ Xb,
    const float* __restrict__ Wq, u16* __restrict__ WqT,
    const float* __restrict__ Wk, u16* __restrict__ WkT,
    const float* __restrict__ Wv, u16* __restrict__ WvT,
    const float* __restrict__ Wo, u16* __restrict__ WoT,
    float* __restrict__ ct, float* __restrict__ st) {
  __shared__ u16 tile[32][33];
  int bid = blockIdx.x, tid = threadIdx.x;

  auto tposeT = [&](const float* in, u16* out, int R, int C, int bx, int by) {
    int c0 = bx * 32, r0 = by * 32;
    int x = tid & 31, y = tid >> 5;
#pragma unroll
    for (int j = 0; j < 32; j += 8)
      tile[y + j][x] = f2bf(in[(size_t)(r0 + y + j) * C + c0 + x]);
    __syncthreads();
#pragma unroll
    for (int j = 0; j < 32; j += 8)
      out[(size_t)(c0 + y + j) * R + r0 + x] = tile[x][y + j];
  };

  if (bid < 1024) {
    int t = bid * 256 + tid;                       // t = p*128 + d
    int d = t & 127;
    int p = t >> 7;
    float invf = exp2f(-(float)d * 0.1038102530f); // log2(10000)/128
    float f = (float)p * invf;
    float s, c;
    sincosf(f, &s, &c);
    ct[t] = c;
    st[t] = s;
  } else if (bid < 10240) {
    size_t i = ((size_t)(bid - 1024) * 256 + tid) * 4;
    float4 v = *(const float4*)(X + i);
    ushort4 o;
    o.x = f2bf(v.x); o.y = f2bf(v.y); o.z = f2bf(v.z); o.w = f2bf(v.w);
    *(ushort4*)(Xb + i) = o;
  } else if (bid < 14848) {
    int b2 = bid - 10240;
    tposeT(Wq, WqT, 2304, 2048, b2 & 63, b2 >> 6);
  } else if (bid < 17152) {
    int b2 = bid - 14848;
    tposeT(Wk, WkT, 2304, 1024, b2 & 31, b2 >> 5);
  } else if (bid < 19456) {
    int b2 = bid - 17152;
    tposeT(Wv, WvT, 2304, 1024, b2 & 31, b2 >> 5);
  } else {
    int b2 = bid - 19456;
    tposeT(Wo, WoT, 2048, 2304, b2 % 72, b2 / 72);
  }
}

// ================= fused mid: rope_k + V-transpose (independent sections) =================
// [0,1024):      rope_k  (4096 rows x 4 kv-heads x 16 dgroups, 256 thr/block)
// [1024,5120):   V-transpose: QKV cols 3072.. -> VT[b][kv][d][s]
//                b2 in [0,4096): bx = b2&31, by = (b2>>5)&63, z = b2>>11 in {0,1}.
__global__ __launch_bounds__(256) void mid_kernel(u16* __restrict__ QKV, u16* __restrict__ VTb,
                                                  const int* __restrict__ pos_ids,
                                                  const float* __restrict__ ct,
                                                  const float* __restrict__ st) {
  __shared__ u16 tile[32][33];
  int bid = blockIdx.x, tid = threadIdx.x;
  if (bid < 1024) {
    int t = bid * 256 + tid;
    int dg = t & 15, h = (t >> 4) & 3, row = t >> 6;
    u16* p1 = QKV + (size_t)row * 4096 + 2048 + h * 256 + dg * 8;
    u16* p2 = p1 + 128;
    int pos = pos_ids[row];
    const float* ctp = ct + pos * 128 + dg * 8;
    const float* stp = st + pos * 128 + dg * 8;
    s16x8 v1 = *(const s16x8*)p1, v2 = *(const s16x8*)p2;
#pragma unroll
    for (int j = 0; j < 8; j++) {
      float c = ctp[j], s = stp[j];
      float a = bf2f((u16)v1[j]);
      float b = bf2f((u16)v2[j]);
      v1[j] = (short)f2bf(a * c - b * s);
      v2[j] = (short)f2bf(b * c + a * s);
    }
    *(s16x8*)p1 = v1;
    *(s16x8*)p2 = v2;
  } else {
    int b2 = bid - 1024;                       // [0,4096)
    int bx = b2 & 31;                          // c0 tile (V col within 1024)
    int by = (b2 >> 5) & 63;                   // r0 tile (seq row within 2048)
    int z = b2 >> 11;                          // batch {0,1}
    const u16* in = QKV + 3072 + (size_t)z * 2048 * 4096;
    u16* out = VTb + (size_t)z * 1024 * 2048;
    int c0 = bx * 32, r0 = by * 32;
    int x = tid & 31, y = tid >> 5;
#pragma unroll
    for (int j = 0; j < 32; j += 8)
      tile[y + j][x] = in[(size_t)(r0 + y + j) * 4096 + c0 + x];
    __syncthreads();
#pragma unroll
    for (int j = 0; j < 32; j += 8)
      out[(size_t)(c0 + y + j) * 2048 + r0 + x] = tile[x][y + j];
  }
}

// ================= 256x256 deep-pipelined GEMM (1-phase counted schedule) =================
template <bool F32OUT>
__global__ __launch_bounds__(512) void gemm256(const u16* __restrict__ A, const u16* __restrict__ BT,
                                               void* __restrict__ Cout, int M, int N, int Kd) {
  __shared__ u16 As[2][256 * 64];
  __shared__ u16 Bs[2][256 * 64];
  int tid = threadIdx.x, lane = tid & 63, wave = tid >> 6;
  int nT = gridDim.x * gridDim.y;
  int bid = blockIdx.y * gridDim.x + blockIdx.x;
  int tile = (bid & 7) * (nT >> 3) + (bid >> 3);        // XCD swizzle (nT % 8 == 0)
  int bn = (tile % gridDim.x) * 256;
  int bm = (tile / gridDim.x) * 256;
  int wm = (wave >> 2) * 128, wn = (wave & 3) * 64;
  int fr = lane & 15, fq = lane >> 4;
  f32x4 acc[8][4];
#pragma unroll
  for (int i = 0; i < 8; i++)
#pragma unroll
    for (int j = 0; j < 4; j++) acc[i][j] = (f32x4){0.f, 0.f, 0.f, 0.f};

  int srow = tid >> 3, sslot = tid & 7;
  int scol = (sslot * 8) ^ ((srow & 7) << 3);           // pre-swizzled source col (u16 units)
  const u16* Ab = A + (size_t)(bm + srow) * Kd + scol;
  const u16* Bb = BT + (size_t)(bn + srow) * Kd + scol;

  auto stage = [&](int buf, int k0) {
#pragma unroll
    for (int i = 0; i < 4; i++) {
      async16(Ab + (size_t)i * 64 * Kd + k0, (char*)&As[buf][0] + wave * 1024 + i * 8192);
      async16(Bb + (size_t)i * 64 * Kd + k0, (char*)&Bs[buf][0] + wave * 1024 + i * 8192);
    }
  };

  int NT = Kd >> 6;
  int rsw = (fr & 7) << 3;
  stage(0, 0);
  for (int t = 0; t < NT; ++t) {
    if (t + 1 < NT) {
      stage((t + 1) & 1, (t + 1) << 6);
      asm volatile("s_waitcnt vmcnt(8)" ::: "memory");
    } else {
      asm volatile("s_waitcnt vmcnt(0)" ::: "memory");
    }
    __builtin_amdgcn_sched_barrier(0);
    __builtin_amdgcn_s_barrier();
    __builtin_amdgcn_sched_barrier(0);
    const u16* Ap = &As[t & 1][0];
    const u16* Bp = &Bs[t & 1][0];
    __builtin_amdgcn_s_setprio(1);
    s16x8 bfr[4][2];
#pragma unroll
    for (int j = 0; j < 4; j++)
#pragma unroll
      for (int s = 0; s < 2; s++)
        bfr[j][s] = *(const s16x8*)&Bp[(wn + j * 16 + fr) * 64 + ((s * 32 + fq * 8) ^ rsw)];
#pragma unroll
    for (int i = 0; i < 8; i++) {
      s16x8 a0 = *(const s16x8*)&Ap[(wm + i * 16 + fr) * 64 + ((fq * 8) ^ rsw)];
      s16x8 a1 = *(const s16x8*)&Ap[(wm + i * 16 + fr) * 64 + ((32 + fq * 8) ^ rsw)];
#pragma unroll
      for (int j = 0; j < 4; j++) {
        acc[i][j] = mfma16(a0, bfr[j][0], acc[i][j]);
        acc[i][j] = mfma16(a1, bfr[j][1], acc[i][j]);
      }
    }
    __builtin_amdgcn_s_setprio(0);
    asm volatile("s_waitcnt lgkmcnt(0)" ::: "memory");
    __builtin_amdgcn_sched_barrier(0);
    __builtin_amdgcn_s_barrier();
  }

#pragma unroll
  for (int i = 0; i < 8; i++)
#pragma unroll
    for (int j = 0; j < 4; j++)
#pragma unroll
      for (int r = 0; r < 4; r++) {
        int row = bm + wm + i * 16 + fq * 4 + r;
        int col = bn + wn + j * 16 + fr;
        if (F32OUT) ((float*)Cout)[(size_t)row * N + col] = acc[i][j][r];
        else        ((u16*)Cout)[(size_t)row * N + col] = f2bf(acc[i][j][r]);
      }
}

// ================= 128x128 pipelined GEMM, BK=32 =================
template <bool F32OUT>
__global__ __launch_bounds__(256) void gemm128(const u16* __restrict__ A, const u16* __restrict__ BT,
                                               void* __restrict__ Cout, int M, int N, int Kd) {
  __shared__ u16 As[2][128 * 32];
  __shared__ u16 Bs[2][128 * 32];
  int tid = threadIdx.x, lane = tid & 63, wave = tid >> 6;
  int nT = gridDim.x * gridDim.y;
  int bid = blockIdx.y * gridDim.x + blockIdx.x;
  int tile = (bid & 7) * (nT >> 3) + (bid >> 3);
  int bn = (tile % gridDim.x) * 128;
  int bm = (tile / gridDim.x) * 128;
  int wm = (wave >> 1) * 64, wn = (wave & 1) * 64;
  int fr = lane & 15, fq = lane >> 4;
  f32x4 acc[4][4];
#pragma unroll
  for (int i = 0; i < 4; i++)
#pragma unroll
    for (int j = 0; j < 4; j++) acc[i][j] = (f32x4){0.f, 0.f, 0.f, 0.f};

  int srow = tid >> 2, sslot = tid & 3;
  int scol = (sslot * 8) ^ ((srow & 3) << 3);
  const u16* Ab = A + (size_t)(bm + srow) * Kd + scol;
  const u16* Bb = BT + (size_t)(bn + srow) * Kd + scol;

  auto stage = [&](int buf, int k0) {
    async16(Ab + k0, (char*)&As[buf][0] + wave * 1024);
    async16(Ab + (size_t)64 * Kd + k0, (char*)&As[buf][0] + wave * 1024 + 4096);
    async16(Bb + k0, (char*)&Bs[buf][0] + wave * 1024);
    async16(Bb + (size_t)64 * Kd + k0, (char*)&Bs[buf][0] + wave * 1024 + 4096);
  };

  int NT = Kd >> 5;
  int rsw = (fr & 3) << 3;
  stage(0, 0);
  for (int t = 0; t < NT; ++t) {
    if (t + 1 < NT) {
      stage((t + 1) & 1, (t + 1) << 5);
      asm volatile("s_waitcnt vmcnt(4)" ::: "memory");
    } else {
      asm volatile("s_waitcnt vmcnt(0)" ::: "memory");
    }
    __builtin_amdgcn_sched_barrier(0);
    __builtin_amdgcn_s_barrier();
    __builtin_amdgcn_sched_barrier(0);
    const u16* Ap = &As[t & 1][0];
    const u16* Bp = &Bs[t & 1][0];
    __builtin_amdgcn_s_setprio(1);
    s16x8 af[4], bv[4];
#pragma unroll
    for (int i = 0; i < 4; i++) af[i] = *(const s16x8*)&Ap[(wm + i * 16 + fr) * 32 + ((fq * 8) ^ rsw)];
#pragma unroll
    for (int j = 0; j < 4; j++) bv[j] = *(const s16x8*)&Bp[(wn + j * 16 + fr) * 32 + ((fq * 8) ^ rsw)];
#pragma unroll
    for (int i = 0; i < 4; i++)
#pragma unroll
      for (int j = 0; j < 4; j++)
        acc[i][j] = mfma16(af[i], bv[j], acc[i][j]);
    __builtin_amdgcn_s_setprio(0);
    asm volatile("s_waitcnt lgkmcnt(0)" ::: "memory");
    __builtin_amdgcn_sched_barrier(0);
    __builtin_amdgcn_s_barrier();
  }
#pragma unroll
  for (int i = 0; i < 4; i++)
#pragma unroll
    for (int j = 0; j < 4; j++)
#pragma unroll
      for (int r = 0; r < 4; r++) {
        int row = bm + wm + i * 16 + fq * 4 + r;
        int col = bn + wn + j * 16 + fr;
        if (F32OUT) ((float*)Cout)[(size_t)row * N + col] = acc[i][j][r];
        else        ((u16*)Cout)[(size_t)row * N + col] = f2bf(acc[i][j][r]);
      }
}

// ---------------- flash attention, KEY-SPLIT, 2-barrier race-free pipeline ----------
// grid 1024; id&7 = b*4+g pinned per XCD (KV L2-resident); qt heavy-first.
// Per tile: vmcnt(0) -> BAR-A -> stage V(t), K(t+2) -> QK^T/softmax/Pwrite -> lgkm0
//           -> vmcnt(4) -> BAR-C -> PV -> lgkm0.
__global__ __launch_bounds__(256) void attn_kernel(const u16* __restrict__ QKV, const u16* __restrict__ VT,
                                                   const int* __restrict__ amask, const int* __restrict__ pos_ids,
                                                   const float* __restrict__ ct, const float* __restrict__ st,
                                                   u16* __restrict__ O0, u16* __restrict__ O1,
                                                   float* __restrict__ L0, float* __restrict__ L1) {
  __shared__ u16 Kl[2][32 * 256];        // K double buffer; granule swz: slot ^= key&7
  __shared__ u16 Vl[256 * 32];           // V single buffer; granule swz: slot ^= (hd>>1)&3
  __shared__ u16 Pl[4][16 * 32];         // per-wave P, XOR-swizzled cols
  __shared__ unsigned char Mb[256];      // bit-packed amask (2048 bits)
  int id = blockIdx.x;
  int bg = id & 7;                        // XCD-pinned (b,g)
  int r_ = id >> 3;
  int qt = 31 - (r_ >> 2);                // heavy first
  int hl = (r_ >> 1) & 1;
  int half = r_ & 1;
  int b = bg >> 2, g = bg & 3;
  int h = g * 2 + hl;
  int tid = threadIdx.x, lane = tid & 63, wave = tid >> 6;
  int fr = lane & 15, fq = lane >> 4;
  int q0 = qt * 64;
  u16* Op = half ? O1 : O0;
  float* Lp = half ? L1 : L0;

  // ---- bit-pack attention mask: thread t packs ints 8t..8t+7 into byte Mb[t] ----
  const int* amp = amask + b * S_;
  {
    int4 a = *(const int4*)(amp + tid * 8);
    int4 c = *(const int4*)(amp + tid * 8 + 4);
    unsigned v = (unsigned)(a.x > 0) | ((unsigned)(a.y > 0) << 1) | ((unsigned)(a.z > 0) << 2) |
                 ((unsigned)(a.w > 0) << 3) | ((unsigned)(c.x > 0) << 4) | ((unsigned)(c.y > 0) << 5) |
                 ((unsigned)(c.z > 0) << 6) | ((unsigned)(c.w > 0) << 7);
    Mb[tid] = (unsigned char)v;
  }

  // ---- load Q rows wave*16+fr, apply RoPE in-register, scale 1/16 ----
  int qrow_g = b * S_ + q0 + wave * 16 + fr;
  s16x8 qr[8];
  const u16* qb = QKV + (size_t)qrow_g * 4096 + h * 256 + fq * 8;
#pragma unroll
  for (int kk = 0; kk < 8; kk++) qr[kk] = *(const s16x8*)(qb + kk * 32);
  int pos = pos_ids[qrow_g];
  const float* ctp = ct + pos * 128 + fq * 8;
  const float* stp = st + pos * 128 + fq * 8;
  s16x8 qf[8];
#pragma unroll
  for (int kk = 0; kk < 4; kk++) {
#pragma unroll
    for (int jj = 0; jj < 8; jj++) {
      float c = ctp[kk * 32 + jj], s = stp[kk * 32 + jj];
      float a = bf2f((u16)qr[kk][jj]);
      float bb = bf2f((u16)qr[kk + 4][jj]);
      qf[kk][jj]     = (short)f2bf((a * c - bb * s) * 0.0625f);
      qf[kk + 4][jj] = (short)f2bf((bb * c + a * s) * 0.0625f);
    }
  }

  f32x4 zero4 = {0.f, 0.f, 0.f, 0.f};
  f32x4 oacc[16];
#pragma unroll
  for (int i = 0; i < 16; i++) oacc[i] = zero4;
  f32x4 lacc = zero4;
  s16x8 onesv;
#pragma unroll
  for (int i = 0; i < 8; i++) onesv[i] = (short)0x3F80;

  const u16* Kbase = QKV + (size_t)b * S_ * 4096 + 2048 + g * 256;
  const u16* Vbase = VT + (size_t)(b * 4 + g) * 256 * S_;

  // ---- staging pointers: 1024 granules each for K,V; 4 K + 4 V per thread ----
  const u16* KsP[4];
  const u16* VsP[4];
  int dst16[4];
#pragma unroll
  for (int i = 0; i < 4; i++) {
    int c = tid + i * 256;
    int key = c >> 5, slot = c & 31;
    KsP[i] = Kbase + (size_t)key * 4096 + ((slot ^ (key & 7)) * 8);
    int hd = c >> 2, vs = c & 3;
    VsP[i] = Vbase + (size_t)hd * 2048 + ((vs ^ ((hd >> 1) & 3)) * 8);
    dst16[i] = c * 16;
  }

  __syncthreads();                                  // Mb visible; all prologue vmem drained

  // prologue: stage K(half)
#pragma unroll
  for (int i = 0; i < 4; i++)
    async16(KsP[i] + (size_t)(half * 32) * 4096, (char*)&Kl[0][0] + dst16[i]);

  int nt = 2 * qt + 2;
  int ksw = fr & 7;
  int vswl = (fr >> 1) & 3;
  int psw = (fr & 3) << 3;
  int kb = 0;
  for (int t = half; t < nt; t += 2) {
    int k0 = t * 32;
    bool more = (t + 2 < nt);
    asm volatile("s_waitcnt vmcnt(0)" ::: "memory");     // retire K(t) (issued ~1 iter ago)
    __builtin_amdgcn_sched_barrier(0);
    __builtin_amdgcn_s_barrier();                        // BAR-A: all waves' K(t) visible;
    __builtin_amdgcn_sched_barrier(0);                   //   also V-WAR fence

    // stage V(t) then K(t+2): FIFO order V older than K for the vmcnt(4) below
#pragma unroll
    for (int i = 0; i < 4; i++)
      async16(VsP[i] + k0, (char*)&Vl[0] + dst16[i]);
    if (more) {
#pragma unroll
      for (int i = 0; i < 4; i++)
        async16(KsP[i] + (size_t)(k0 + 64) * 4096, (char*)&Kl[kb ^ 1][0] + dst16[i]);
    }

    // ---- QK^T: keys {fr, 16+fr} x 32-wide K tile ----
    const u16* Kp = &Kl[kb][0];
    __builtin_amdgcn_s_setprio(1);
    f32x4 s0 = zero4, s1 = zero4;
#pragma unroll
    for (int kk = 0; kk < 8; kk++) {
      s16x8 b0 = *(const s16x8*)&Kp[fr * 256 + (((kk * 4 + fq) ^ ksw) * 8)];
      s16x8 b1 = *(const s16x8*)&Kp[(16 + fr) * 256 + (((kk * 4 + fq) ^ ksw) * 8)];
      s0 = mfma16(qf[kk], b0, s0);
      s1 = mfma16(qf[kk], b1, s1);
    }
    __builtin_amdgcn_s_setprio(0);

    int am0 = (Mb[(k0 + fr) >> 3] >> ((k0 + fr) & 7)) & 1;
    int am1 = (Mb[(k0 + 16 + fr) >> 3] >> ((k0 + 16 + fr) & 7)) & 1;
    bool needmask = (t >= nt - 2);
#pragma unroll
    for (int r = 0; r < 4; r++) {
      int qrow = fq * 4 + r;
      int qg = q0 + wave * 16 + qrow;
      // p = exp(50*tanh(s/50) - 50) = exp(-100/(exp(0.04*s)+1))  [fixed max 50]
      float e20 = __expf(s0[r] * 0.04f);
      float e21 = __expf(s1[r] * 0.04f);
      float p0 = __expf(__fdividef(-100.f, e20 + 1.f));
      float p1 = __expf(__fdividef(-100.f, e21 + 1.f));
      bool ok0 = am0 && (!needmask || (k0 + fr) <= qg);
      bool ok1 = am1 && (!needmask || (k0 + 16 + fr) <= qg);
      p0 = ok0 ? p0 : 0.f;
      p1 = ok1 ? p1 : 0.f;
      Pl[wave][qrow * 32 + (fr ^ (r << 3))] = f2bf(p0);
      Pl[wave][qrow * 32 + ((16 + fr) ^ (r << 3))] = f2bf(p1);
    }
    asm volatile("s_waitcnt lgkmcnt(0)" ::: "memory");   // own P writes + K reads drained
    __builtin_amdgcn_sched_barrier(0);
    if (more)
      asm volatile("s_waitcnt vmcnt(4)" ::: "memory");   // retire V(t); K(t+2) stays in flight
    else
      asm volatile("s_waitcnt vmcnt(0)" ::: "memory");
    __builtin_amdgcn_sched_barrier(0);
    __builtin_amdgcn_s_barrier();                        // BAR-C: all waves' V(t) visible
    __builtin_amdgcn_sched_barrier(0);

    // ---- PV (per-wave P) ----
    s16x8 pf = *(const s16x8*)&Pl[wave][fr * 32 + ((fq * 8) ^ psw)];
    __builtin_amdgcn_s_setprio(1);
    lacc = mfma16(pf, onesv, lacc);
#pragma unroll
    for (int df = 0; df < 16; df++) {
      s16x8 vv = *(const s16x8*)&Vl[(df * 16 + fr) * 32 + ((fq ^ vswl) * 8)];
      oacc[df] = mfma16(pf, vv, oacc[df]);
    }
    __builtin_amdgcn_s_setprio(0);
    asm volatile("s_waitcnt lgkmcnt(0)" ::: "memory");   // own V reads done (before next BAR-A)
    __builtin_amdgcn_sched_barrier(0);
    kb ^= 1;
  }

  // ---- write unnormalized bf16 partial O and f32 partial l ----
  if (fr == 0) {
#pragma unroll
    for (int r = 0; r < 4; r++)
      Lp[(size_t)(b * S_ + q0 + wave * 16 + fq * 4 + r) * 8 + h] = lacc[r];
  }
#pragma unroll
  for (int df = 0; df < 16; df++) {
#pragma unroll
    for (int r = 0; r < 4; r++) {
      Op[(size_t)(b * S_ + q0 + wave * 16 + fq * 4 + r) * 2048 + h * 256 + df * 16 + fr] =
          f2bf(oacc[df][r]);
    }
  }
}

// ---------------- combine partial halves: AO = (O0+O1)/(l0+l1) ----------------
__global__ void combine_o(const u16* __restrict__ O0, const u16* __restrict__ O1,
                          const float* __restrict__ L0, const float* __restrict__ L1,
                          u16* __restrict__ AO) {
  int idx = blockIdx.x * blockDim.x + threadIdx.x;   // 4096 rows x 256 groups of 8 cols
  int row = idx >> 8;
  int cg = idx & 255;
  int h = cg >> 5;
  float rinv = 1.0f / (L0[row * 8 + h] + L1[row * 8 + h]);
  size_t base = (size_t)row * 2048 + cg * 8;
  s16x8 a = *(const s16x8*)(O0 + base);
  s16x8 b = *(const s16x8*)(O1 + base);
  s16x8 o;
#pragma unroll
  for (int j = 0; j < 8; j++)
    o[j] = (short)f2bf((bf2f((u16)a[j]) + bf2f((u16)b[j])) * rinv);
  *(s16x8*)(AO + base) = o;
}

extern "C" void kernel_launch(void* const* d_in, const int* in_sizes, int n_in,
                              void* d_out, int out_size, void* d_ws, size_t ws_size,
                              hipStream_t stream) {
  const float* X   = (const float*)d_in[0];   // [B,S,H] fp32
  const int* amask = (const int*)d_in[1];
  const int* pos   = (const int*)d_in[2];
  const float* Wq  = (const float*)d_in[3];
  const float* Wk  = (const float*)d_in[4];
  const float* Wv  = (const float*)d_in[5];
  const float* Wo  = (const float*)d_in[6];
  float* out = (float*)d_out;                 // [B,S,H] fp32

  char* ws = (char*)d_ws;
  size_t off = 0;
  auto allocB = [&](size_t bytes) {
    char* p = ws + off;
    off += ((bytes + 255) & ~(size_t)255);
    return p;
  };
  u16* Xb   = (u16*)allocB((size_t)4096 * 2304 * 2);
  u16* WqT  = (u16*)allocB((size_t)2048 * 2304 * 2);   // WqT/WkT/WvT contiguous => fused B^T
  u16* WkT  = (u16*)allocB((size_t)1024 * 2304 * 2);
  u16* WvT  = (u16*)allocB((size_t)1024 * 2304 * 2);
  u16* WoT  = (u16*)allocB((size_t)2304 * 2048 * 2);
  u16* QKV  = (u16*)allocB((size_t)4096 * 4096 * 2);
  u16* VTb  = (u16*)allocB((size_t)4096 * 1024 * 2);
  u16* AO   = (u16*)allocB((size_t)4096 * 2048 * 2);
  float* CT = (float*)allocB((size_t)2048 * 128 * 4);
  float* ST = (float*)allocB((size_t)2048 * 128 * 4);
  float* Lp0 = (float*)allocB((size_t)4096 * 8 * 4);
  float* Lp1 = (float*)allocB((size_t)4096 * 8 * 4);
  // O partials ALIAS the Xb/WqT/WkT/WvT-head region (dead after gemm256)
  u16* Op0 = (u16*)ws;
  u16* Op1 = Op0 + (size_t)4096 * 2048;
  if (off > ws_size) return;

  // fused prep: rope table + X convert + 4 weight transposes (one launch)
  prep_kernel<<<24064, 256, 0, stream>>>(X, Xb, Wq, WqT, Wk, WkT, Wv, WvT, Wo, WoT, CT, ST);

  // fused QKV projection (256² 1-phase counted)  [Xb/WqT/WkT/WvT dead after this]
  gemm256<false><<<dim3(4096 / 256, 4096 / 256), 512, 0, stream>>>(Xb, WqT, QKV, 4096, 4096, 2304);

  // fused mid: rope_k + V-transpose (one launch; 1024 + 4096 blocks)
  mid_kernel<<<5120, 256, 0, stream>>>(QKV, VTb, pos, CT, ST);

  // attention: key-split grid 1024, XCD-pinned (b,g), 2-barrier pipeline
  attn_kernel<<<dim3(1024), 256, 0, stream>>>(QKV, VTb, amask, pos, CT, ST, Op0, Op1, Lp0, Lp1);

  // combine halves -> AO bf16
  combine_o<<<4096, 256, 0, stream>>>(Op0, Op1, Lp0, Lp1, AO);

  // output projection -> fp32 d_out (128² BK=32 pipelined)
  gemm128<true><<<dim3(2304 / 128, 4096 / 128), 256, 0, stream>>>(AO, WoT, out, 4096, 2304, 2048);
}

// Round 22
// 241.900 us; speedup vs baseline: 1.1183x; 1.0194x over previous
//
#include <hip/hip_runtime.h>
#include <hip/hip_bf16.h>
#include <stdint.h>

typedef unsigned short u16;
typedef __attribute__((ext_vector_type(8))) short s16x8;
typedef __attribute__((ext_vector_type(4))) float f32x4;

#define B_ 2
#define S_ 2048
#define H_ 2304
#define NH_ 8
#define NKV_ 4
#define HD_ 256

__device__ __forceinline__ float bf2f(u16 u) {
  union { uint32_t i; float f; } x; x.i = ((uint32_t)u) << 16; return x.f;
}
__device__ __forceinline__ u16 f2bf(float f) {
  union { float f; uint32_t i; } x; x.f = f;
  uint32_t u = x.i;
  return (u16)((u + 0x7fffu + ((u >> 16) & 1u)) >> 16);
}
__device__ __forceinline__ u16 f2bft(float f) {          // truncating (for P: bias cancels in O/l)
  union { float f; uint32_t i; } x; x.f = f;
  return (u16)(x.i >> 16);
}

__device__ __forceinline__ void async16(const void* g, void* l) {
  __builtin_amdgcn_global_load_lds((const __attribute__((address_space(1))) uint32_t*)g,
                                   (__attribute__((address_space(3))) uint32_t*)l, 16, 0, 0);
}

__device__ __forceinline__ f32x4 mfma16(s16x8 a, s16x8 b, f32x4 c) {
  return __builtin_amdgcn_mfma_f32_16x16x32_bf16(a, b, c, 0, 0, 0);
}

// ================= fused prep: rope table + X convert + 4 weight transposes =================
// All sections independent (disjoint outputs); branch is block-uniform so __syncthreads is safe.
__global__ __launch_bounds__(256) void prep_kernel(
    const float* __restrict__ X, u16* __restrict__ Xb,
    const float* __restrict__ Wq, u16* __restrict__ WqT,
    const float* __restrict__ Wk, u16* __restrict__ WkT,
    const float* __restrict__ Wv, u16* __restrict__ WvT,
    const float* __restrict__ Wo, u16* __restrict__ WoT,
    float* __restrict__ ct, float* __restrict__ st) {
  __shared__ u16 tile[32][33];
  int bid = blockIdx.x, tid = threadIdx.x;

  auto tposeT = [&](const float* in, u16* out, int R, int C, int bx, int by) {
    int c0 = bx * 32, r0 = by * 32;
    int x = tid & 31, y = tid >> 5;
#pragma unroll
    for (int j = 0; j < 32; j += 8)
      tile[y + j][x] = f2bf(in[(size_t)(r0 + y + j) * C + c0 + x]);
    __syncthreads();
#pragma unroll
    for (int j = 0; j < 32; j += 8)
      out[(size_t)(c0 + y + j) * R + r0 + x] = tile[x][y + j];
  };

  if (bid < 1024) {
    int t = bid * 256 + tid;                       // t = p*128 + d
    int d = t & 127;
    int p = t >> 7;
    float invf = exp2f(-(float)d * 0.1038102530f); // log2(10000)/128
    float f = (float)p * invf;
    float s, c;
    sincosf(f, &s, &c);
    ct[t] = c;
    st[t] = s;
  } else if (bid < 10240) {
    size_t i = ((size_t)(bid - 1024) * 256 + tid) * 4;
    float4 v = *(const float4*)(X + i);
    ushort4 o;
    o.x = f2bf(v.x); o.y = f2bf(v.y); o.z = f2bf(v.z); o.w = f2bf(v.w);
    *(ushort4*)(Xb + i) = o;
  } else if (bid < 14848) {
    int b2 = bid - 10240;
    tposeT(Wq, WqT, 2304, 2048, b2 & 63, b2 >> 6);
  } else if (bid < 17152) {
    int b2 = bid - 14848;
    tposeT(Wk, WkT, 2304, 1024, b2 & 31, b2 >> 5);
  } else if (bid < 19456) {
    int b2 = bid - 17152;
    tposeT(Wv, WvT, 2304, 1024, b2 & 31, b2 >> 5);
  } else {
    int b2 = bid - 19456;
    tposeT(Wo, WoT, 2048, 2304, b2 % 72, b2 / 72);
  }
}

// ================= fused mid: rope_k + V-transpose (independent sections) =================
// [0,1024):      rope_k  (4096 rows x 4 kv-heads x 16 dgroups, 256 thr/block)
// [1024,5120):   V-transpose: QKV cols 3072.. -> VT[b][kv][d][s]
//                b2 in [0,4096): bx = b2&31, by = (b2>>5)&63, z = b2>>11 in {0,1}.
__global__ __launch_bounds__(256) void mid_kernel(u16* __restrict__ QKV, u16* __restrict__ VTb,
                                                  const int* __restrict__ pos_ids,
                                                  const float* __restrict__ ct,
                                                  const float* __restrict__ st) {
  __shared__ u16 tile[32][33];
  int bid = blockIdx.x, tid = threadIdx.x;
  if (bid < 1024) {
    int t = bid * 256 + tid;
    int dg = t & 15, h = (t >> 4) & 3, row = t >> 6;
    u16* p1 = QKV + (size_t)row * 4096 + 2048 + h * 256 + dg * 8;
    u16* p2 = p1 + 128;
    int pos = pos_ids[row];
    const float* ctp = ct + pos * 128 + dg * 8;
    const float* stp = st + pos * 128 + dg * 8;
    s16x8 v1 = *(const s16x8*)p1, v2 = *(const s16x8*)p2;
#pragma unroll
    for (int j = 0; j < 8; j++) {
      float c = ctp[j], s = stp[j];
      float a = bf2f((u16)v1[j]);
      float b = bf2f((u16)v2[j]);
      v1[j] = (short)f2bf(a * c - b * s);
      v2[j] = (short)f2bf(b * c + a * s);
    }
    *(s16x8*)p1 = v1;
    *(s16x8*)p2 = v2;
  } else {
    int b2 = bid - 1024;                       // [0,4096)
    int bx = b2 & 31;                          // c0 tile (V col within 1024)
    int by = (b2 >> 5) & 63;                   // r0 tile (seq row within 2048)
    int z = b2 >> 11;                          // batch {0,1}
    const u16* in = QKV + 3072 + (size_t)z * 2048 * 4096;
    u16* out = VTb + (size_t)z * 1024 * 2048;
    int c0 = bx * 32, r0 = by * 32;
    int x = tid & 31, y = tid >> 5;
#pragma unroll
    for (int j = 0; j < 32; j += 8)
      tile[y + j][x] = in[(size_t)(r0 + y + j) * 4096 + c0 + x];
    __syncthreads();
#pragma unroll
    for (int j = 0; j < 32; j += 8)
      out[(size_t)(c0 + y + j) * 2048 + r0 + x] = tile[x][y + j];
  }
}

// ================= 256x256 deep-pipelined GEMM (1-phase counted schedule) =================
template <bool F32OUT>
__global__ __launch_bounds__(512) void gemm256(const u16* __restrict__ A, const u16* __restrict__ BT,
                                               void* __restrict__ Cout, int M, int N, int Kd) {
  __shared__ u16 As[2][256 * 64];
  __shared__ u16 Bs[2][256 * 64];
  int tid = threadIdx.x, lane = tid & 63, wave = tid >> 6;
  int nT = gridDim.x * gridDim.y;
  int bid = blockIdx.y * gridDim.x + blockIdx.x;
  int tile = (bid & 7) * (nT >> 3) + (bid >> 3);        // XCD swizzle (nT % 8 == 0)
  int bn = (tile % gridDim.x) * 256;
  int bm = (tile / gridDim.x) * 256;
  int wm = (wave >> 2) * 128, wn = (wave & 3) * 64;
  int fr = lane & 15, fq = lane >> 4;
  f32x4 acc[8][4];
#pragma unroll
  for (int i = 0; i < 8; i++)
#pragma unroll
    for (int j = 0; j < 4; j++) acc[i][j] = (f32x4){0.f, 0.f, 0.f, 0.f};

  int srow = tid >> 3, sslot = tid & 7;
  int scol = (sslot * 8) ^ ((srow & 7) << 3);           // pre-swizzled source col (u16 units)
  const u16* Ab = A + (size_t)(bm + srow) * Kd + scol;
  const u16* Bb = BT + (size_t)(bn + srow) * Kd + scol;

  auto stage = [&](int buf, int k0) {
#pragma unroll
    for (int i = 0; i < 4; i++) {
      async16(Ab + (size_t)i * 64 * Kd + k0, (char*)&As[buf][0] + wave * 1024 + i * 8192);
      async16(Bb + (size_t)i * 64 * Kd + k0, (char*)&Bs[buf][0] + wave * 1024 + i * 8192);
    }
  };

  int NT = Kd >> 6;
  int rsw = (fr & 7) << 3;
  stage(0, 0);
  for (int t = 0; t < NT; ++t) {
    if (t + 1 < NT) {
      stage((t + 1) & 1, (t + 1) << 6);
      asm volatile("s_waitcnt vmcnt(8)" ::: "memory");
    } else {
      asm volatile("s_waitcnt vmcnt(0)" ::: "memory");
    }
    __builtin_amdgcn_sched_barrier(0);
    __builtin_amdgcn_s_barrier();
    __builtin_amdgcn_sched_barrier(0);
    const u16* Ap = &As[t & 1][0];
    const u16* Bp = &Bs[t & 1][0];
    __builtin_amdgcn_s_setprio(1);
    s16x8 bfr[4][2];
#pragma unroll
    for (int j = 0; j < 4; j++)
#pragma unroll
      for (int s = 0; s < 2; s++)
        bfr[j][s] = *(const s16x8*)&Bp[(wn + j * 16 + fr) * 64 + ((s * 32 + fq * 8) ^ rsw)];
#pragma unroll
    for (int i = 0; i < 8; i++) {
      s16x8 a0 = *(const s16x8*)&Ap[(wm + i * 16 + fr) * 64 + ((fq * 8) ^ rsw)];
      s16x8 a1 = *(const s16x8*)&Ap[(wm + i * 16 + fr) * 64 + ((32 + fq * 8) ^ rsw)];
#pragma unroll
      for (int j = 0; j < 4; j++) {
        acc[i][j] = mfma16(a0, bfr[j][0], acc[i][j]);
        acc[i][j] = mfma16(a1, bfr[j][1], acc[i][j]);
      }
    }
    __builtin_amdgcn_s_setprio(0);
    asm volatile("s_waitcnt lgkmcnt(0)" ::: "memory");
    __builtin_amdgcn_sched_barrier(0);
    __builtin_amdgcn_s_barrier();
  }

#pragma unroll
  for (int i = 0; i < 8; i++)
#pragma unroll
    for (int j = 0; j < 4; j++)
#pragma unroll
      for (int r = 0; r < 4; r++) {
        int row = bm + wm + i * 16 + fq * 4 + r;
        int col = bn + wn + j * 16 + fr;
        if (F32OUT) ((float*)Cout)[(size_t)row * N + col] = acc[i][j][r];
        else        ((u16*)Cout)[(size_t)row * N + col] = f2bf(acc[i][j][r]);
      }
}

// ================= 128x128 pipelined GEMM, BK=32 =================
template <bool F32OUT>
__global__ __launch_bounds__(256) void gemm128(const u16* __restrict__ A, const u16* __restrict__ BT,
                                               void* __restrict__ Cout, int M, int N, int Kd) {
  __shared__ u16 As[2][128 * 32];
  __shared__ u16 Bs[2][128 * 32];
  int tid = threadIdx.x, lane = tid & 63, wave = tid >> 6;
  int nT = gridDim.x * gridDim.y;
  int bid = blockIdx.y * gridDim.x + blockIdx.x;
  int tile = (bid & 7) * (nT >> 3) + (bid >> 3);
  int bn = (tile % gridDim.x) * 128;
  int bm = (tile / gridDim.x) * 128;
  int wm = (wave >> 1) * 64, wn = (wave & 1) * 64;
  int fr = lane & 15, fq = lane >> 4;
  f32x4 acc[4][4];
#pragma unroll
  for (int i = 0; i < 4; i++)
#pragma unroll
    for (int j = 0; j < 4; j++) acc[i][j] = (f32x4){0.f, 0.f, 0.f, 0.f};

  int srow = tid >> 2, sslot = tid & 3;
  int scol = (sslot * 8) ^ ((srow & 3) << 3);
  const u16* Ab = A + (size_t)(bm + srow) * Kd + scol;
  const u16* Bb = BT + (size_t)(bn + srow) * Kd + scol;

  auto stage = [&](int buf, int k0) {
    async16(Ab + k0, (char*)&As[buf][0] + wave * 1024);
    async16(Ab + (size_t)64 * Kd + k0, (char*)&As[buf][0] + wave * 1024 + 4096);
    async16(Bb + k0, (char*)&Bs[buf][0] + wave * 1024);
    async16(Bb + (size_t)64 * Kd + k0, (char*)&Bs[buf][0] + wave * 1024 + 4096);
  };

  int NT = Kd >> 5;
  int rsw = (fr & 3) << 3;
  stage(0, 0);
  for (int t = 0; t < NT; ++t) {
    if (t + 1 < NT) {
      stage((t + 1) & 1, (t + 1) << 5);
      asm volatile("s_waitcnt vmcnt(4)" ::: "memory");
    } else {
      asm volatile("s_waitcnt vmcnt(0)" ::: "memory");
    }
    __builtin_amdgcn_sched_barrier(0);
    __builtin_amdgcn_s_barrier();
    __builtin_amdgcn_sched_barrier(0);
    const u16* Ap = &As[t & 1][0];
    const u16* Bp = &Bs[t & 1][0];
    __builtin_amdgcn_s_setprio(1);
    s16x8 af[4], bv[4];
#pragma unroll
    for (int i = 0; i < 4; i++) af[i] = *(const s16x8*)&Ap[(wm + i * 16 + fr) * 32 + ((fq * 8) ^ rsw)];
#pragma unroll
    for (int j = 0; j < 4; j++) bv[j] = *(const s16x8*)&Bp[(wn + j * 16 + fr) * 32 + ((fq * 8) ^ rsw)];
#pragma unroll
    for (int i = 0; i < 4; i++)
#pragma unroll
      for (int j = 0; j < 4; j++)
        acc[i][j] = mfma16(af[i], bv[j], acc[i][j]);
    __builtin_amdgcn_s_setprio(0);
    asm volatile("s_waitcnt lgkmcnt(0)" ::: "memory");
    __builtin_amdgcn_sched_barrier(0);
    __builtin_amdgcn_s_barrier();
  }
#pragma unroll
  for (int i = 0; i < 4; i++)
#pragma unroll
    for (int j = 0; j < 4; j++)
#pragma unroll
      for (int r = 0; r < 4; r++) {
        int row = bm + wm + i * 16 + fq * 4 + r;
        int col = bn + wn + j * 16 + fr;
        if (F32OUT) ((float*)Cout)[(size_t)row * N + col] = acc[i][j][r];
        else        ((u16*)Cout)[(size_t)row * N + col] = f2bf(acc[i][j][r]);
      }
}

// ---------------- flash attention, KEY-SPLIT, 2-barrier race-free pipeline ----------
// grid 1024; id&7 = b*4+g pinned per XCD (KV L2-resident); qt heavy-first.
// Per tile: vmcnt(0) -> BAR-A -> stage V(t), K(t+2) -> QK^T/softmax/Pwrite -> lgkm0
//           -> vmcnt(4) -> BAR-C -> PV -> lgkm0.
__global__ __launch_bounds__(256) void attn_kernel(const u16* __restrict__ QKV, const u16* __restrict__ VT,
                                                   const int* __restrict__ amask, const int* __restrict__ pos_ids,
                                                   const float* __restrict__ ct, const float* __restrict__ st,
                                                   u16* __restrict__ O0, u16* __restrict__ O1,
                                                   float* __restrict__ L0, float* __restrict__ L1) {
  __shared__ u16 Kl[2][32 * 256];        // K double buffer; granule swz: slot ^= key&7
  __shared__ u16 Vl[256 * 32];           // V single buffer; granule swz: slot ^= (hd>>1)&3
  __shared__ u16 Pl[4][16 * 32];         // per-wave P, XOR-swizzled cols
  __shared__ unsigned char Mb[256];      // bit-packed amask (2048 bits)
  int id = blockIdx.x;
  int bg = id & 7;                        // XCD-pinned (b,g)
  int r_ = id >> 3;
  int qt = 31 - (r_ >> 2);                // heavy first
  int hl = (r_ >> 1) & 1;
  int half = r_ & 1;
  int b = bg >> 2, g = bg & 3;
  int h = g * 2 + hl;
  int tid = threadIdx.x, lane = tid & 63, wave = tid >> 6;
  int fr = lane & 15, fq = lane >> 4;
  int q0 = qt * 64;
  u16* Op = half ? O1 : O0;
  float* Lp = half ? L1 : L0;

  // ---- bit-pack attention mask: thread t packs ints 8t..8t+7 into byte Mb[t] ----
  const int* amp = amask + b * S_;
  {
    int4 a = *(const int4*)(amp + tid * 8);
    int4 c = *(const int4*)(amp + tid * 8 + 4);
    unsigned v = (unsigned)(a.x > 0) | ((unsigned)(a.y > 0) << 1) | ((unsigned)(a.z > 0) << 2) |
                 ((unsigned)(a.w > 0) << 3) | ((unsigned)(c.x > 0) << 4) | ((unsigned)(c.y > 0) << 5) |
                 ((unsigned)(c.z > 0) << 6) | ((unsigned)(c.w > 0) << 7);
    Mb[tid] = (unsigned char)v;
  }

  // ---- load Q rows wave*16+fr, apply RoPE in-register, scale 1/16 ----
  int qrow_g = b * S_ + q0 + wave * 16 + fr;
  s16x8 qr[8];
  const u16* qb = QKV + (size_t)qrow_g * 4096 + h * 256 + fq * 8;
#pragma unroll
  for (int kk = 0; kk < 8; kk++) qr[kk] = *(const s16x8*)(qb + kk * 32);
  int pos = pos_ids[qrow_g];
  const float* ctp = ct + pos * 128 + fq * 8;
  const float* stp = st + pos * 128 + fq * 8;
  s16x8 qf[8];
#pragma unroll
  for (int kk = 0; kk < 4; kk++) {
#pragma unroll
    for (int jj = 0; jj < 8; jj++) {
      float c = ctp[kk * 32 + jj], s = stp[kk * 32 + jj];
      float a = bf2f((u16)qr[kk][jj]);
      float bb = bf2f((u16)qr[kk + 4][jj]);
      qf[kk][jj]     = (short)f2bf((a * c - bb * s) * 0.0625f);
      qf[kk + 4][jj] = (short)f2bf((bb * c + a * s) * 0.0625f);
    }
  }

  f32x4 zero4 = {0.f, 0.f, 0.f, 0.f};
  f32x4 oacc[16];
#pragma unroll
  for (int i = 0; i < 16; i++) oacc[i] = zero4;
  f32x4 lacc = zero4;
  s16x8 onesv;
#pragma unroll
  for (int i = 0; i < 8; i++) onesv[i] = (short)0x3F80;

  const u16* Kbase = QKV + (size_t)b * S_ * 4096 + 2048 + g * 256;
  const u16* Vbase = VT + (size_t)(b * 4 + g) * 256 * S_;

  // ---- staging pointers: 1024 granules each for K,V; 4 K + 4 V per thread ----
  const u16* KsP[4];
  const u16* VsP[4];
  int dst16[4];
#pragma unroll
  for (int i = 0; i < 4; i++) {
    int c = tid + i * 256;
    int key = c >> 5, slot = c & 31;
    KsP[i] = Kbase + (size_t)key * 4096 + ((slot ^ (key & 7)) * 8);
    int hd = c >> 2, vs = c & 3;
    VsP[i] = Vbase + (size_t)hd * 2048 + ((vs ^ ((hd >> 1) & 3)) * 8);
    dst16[i] = c * 16;
  }

  __syncthreads();                                  // Mb visible; all prologue vmem drained

  // prologue: stage K(half)
#pragma unroll
  for (int i = 0; i < 4; i++)
    async16(KsP[i] + (size_t)(half * 32) * 4096, (char*)&Kl[0][0] + dst16[i]);

  int nt = 2 * qt + 2;
  int ksw = fr & 7;
  int vswl = (fr >> 1) & 3;
  int psw = (fr & 3) << 3;
  int kb = 0;
  for (int t = half; t < nt; t += 2) {
    int k0 = t * 32;
    bool more = (t + 2 < nt);
    asm volatile("s_waitcnt vmcnt(0)" ::: "memory");     // retire K(t) (issued ~1 iter ago)
    __builtin_amdgcn_sched_barrier(0);
    __builtin_amdgcn_s_barrier();                        // BAR-A: all waves' K(t) visible;
    __builtin_amdgcn_sched_barrier(0);                   //   also V-WAR fence

    // stage V(t) then K(t+2): FIFO order V older than K for the vmcnt(4) below
#pragma unroll
    for (int i = 0; i < 4; i++)
      async16(VsP[i] + k0, (char*)&Vl[0] + dst16[i]);
    if (more) {
#pragma unroll
      for (int i = 0; i < 4; i++)
        async16(KsP[i] + (size_t)(k0 + 64) * 4096, (char*)&Kl[kb ^ 1][0] + dst16[i]);
    }

    // ---- QK^T: keys {fr, 16+fr} x 32-wide K tile ----
    const u16* Kp = &Kl[kb][0];
    __builtin_amdgcn_s_setprio(1);
    f32x4 s0 = zero4, s1 = zero4;
#pragma unroll
    for (int kk = 0; kk < 8; kk++) {
      s16x8 b0 = *(const s16x8*)&Kp[fr * 256 + (((kk * 4 + fq) ^ ksw) * 8)];
      s16x8 b1 = *(const s16x8*)&Kp[(16 + fr) * 256 + (((kk * 4 + fq) ^ ksw) * 8)];
      s0 = mfma16(qf[kk], b0, s0);
      s1 = mfma16(qf[kk], b1, s1);
    }
    __builtin_amdgcn_s_setprio(0);

    int am0 = (Mb[(k0 + fr) >> 3] >> ((k0 + fr) & 7)) & 1;
    int am1 = (Mb[(k0 + 16 + fr) >> 3] >> ((k0 + 16 + fr) & 7)) & 1;
    bool needmask = (t >= nt - 2);                       // wave-uniform
    float pv0[4], pv1[4];
#pragma unroll
    for (int r = 0; r < 4; r++) {
      // p = exp(50*tanh(s/50) - 50) = exp(-100/(exp(0.04*s)+1))  [fixed max 50]
      float e20 = __expf(s0[r] * 0.04f);
      float e21 = __expf(s1[r] * 0.04f);
      pv0[r] = __expf(__fdividef(-100.f, e20 + 1.f));
      pv1[r] = __expf(__fdividef(-100.f, e21 + 1.f));
    }
    if (needmask) {                                      // uniform branch: causal only on last iter
#pragma unroll
      for (int r = 0; r < 4; r++) {
        int qg = q0 + wave * 16 + fq * 4 + r;
        if (!((k0 + fr) <= qg)) pv0[r] = 0.f;
        if (!((k0 + 16 + fr) <= qg)) pv1[r] = 0.f;
      }
    }
#pragma unroll
    for (int r = 0; r < 4; r++) {
      int qrow = fq * 4 + r;
      float p0 = am0 ? pv0[r] : 0.f;
      float p1 = am1 ? pv1[r] : 0.f;
      Pl[wave][qrow * 32 + (fr ^ (r << 3))] = f2bft(p0);
      Pl[wave][qrow * 32 + ((16 + fr) ^ (r << 3))] = f2bft(p1);
    }
    asm volatile("s_waitcnt lgkmcnt(0)" ::: "memory");   // own P writes + K reads drained
    __builtin_amdgcn_sched_barrier(0);
    if (more)
      asm volatile("s_waitcnt vmcnt(4)" ::: "memory");   // retire V(t); K(t+2) stays in flight
    else
      asm volatile("s_waitcnt vmcnt(0)" ::: "memory");
    __builtin_amdgcn_sched_barrier(0);
    __builtin_amdgcn_s_barrier();                        // BAR-C: all waves' V(t) visible
    __builtin_amdgcn_sched_barrier(0);

    // ---- PV (per-wave P) ----
    s16x8 pf = *(const s16x8*)&Pl[wave][fr * 32 + ((fq * 8) ^ psw)];
    __builtin_amdgcn_s_setprio(1);
    lacc = mfma16(pf, onesv, lacc);
#pragma unroll
    for (int df = 0; df < 16; df++) {
      s16x8 vv = *(const s16x8*)&Vl[(df * 16 + fr) * 32 + ((fq ^ vswl) * 8)];
      oacc[df] = mfma16(pf, vv, oacc[df]);
    }
    __builtin_amdgcn_s_setprio(0);
    asm volatile("s_waitcnt lgkmcnt(0)" ::: "memory");   // own V reads done (before next BAR-A)
    __builtin_amdgcn_sched_barrier(0);
    kb ^= 1;
  }

  // ---- write unnormalized bf16 partial O and f32 partial l ----
  if (fr == 0) {
#pragma unroll
    for (int r = 0; r < 4; r++)
      Lp[(size_t)(b * S_ + q0 + wave * 16 + fq * 4 + r) * 8 + h] = lacc[r];
  }
#pragma unroll
  for (int df = 0; df < 16; df++) {
#pragma unroll
    for (int r = 0; r < 4; r++) {
      Op[(size_t)(b * S_ + q0 + wave * 16 + fq * 4 + r) * 2048 + h * 256 + df * 16 + fr] =
          f2bf(oacc[df][r]);
    }
  }
}

// ---------------- combine partial halves: AO = (O0+O1)/(l0+l1) ----------------
__global__ void combine_o(const u16* __restrict__ O0, const u16* __restrict__ O1,
                          const float* __restrict__ L0, const float* __restrict__ L1,
                          u16* __restrict__ AO) {
  int idx = blockIdx.x * blockDim.x + threadIdx.x;   // 4096 rows x 256 groups of 8 cols
  int row = idx >> 8;
  int cg = idx & 255;
  int h = cg >> 5;
  float rinv = 1.0f / (L0[row * 8 + h] + L1[row * 8 + h]);
  size_t base = (size_t)row * 2048 + cg * 8;
  s16x8 a = *(const s16x8*)(O0 + base);
  s16x8 b = *(const s16x8*)(O1 + base);
  s16x8 o;
#pragma unroll
  for (int j = 0; j < 8; j++)
    o[j] = (short)f2bf((bf2f((u16)a[j]) + bf2f((u16)b[j])) * rinv);
  *(s16x8*)(AO + base) = o;
}

extern "C" void kernel_launch(void* const* d_in, const int* in_sizes, int n_in,
                              void* d_out, int out_size, void* d_ws, size_t ws_size,
                              hipStream_t stream) {
  const float* X   = (const float*)d_in[0];   // [B,S,H] fp32
  const int* amask = (const int*)d_in[1];
  const int* pos   = (const int*)d_in[2];
  const float* Wq  = (const float*)d_in[3];
  const float* Wk  = (const float*)d_in[4];
  const float* Wv  = (const float*)d_in[5];
  const float* Wo  = (const float*)d_in[6];
  float* out = (float*)d_out;                 // [B,S,H] fp32

  char* ws = (char*)d_ws;
  size_t off = 0;
  auto allocB = [&](size_t bytes) {
    char* p = ws + off;
    off += ((bytes + 255) & ~(size_t)255);
    return p;
  };
  u16* Xb   = (u16*)allocB((size_t)4096 * 2304 * 2);
  u16* WqT  = (u16*)allocB((size_t)2048 * 2304 * 2);   // WqT/WkT/WvT contiguous => fused B^T
  u16* WkT  = (u16*)allocB((size_t)1024 * 2304 * 2);
  u16* WvT  = (u16*)allocB((size_t)1024 * 2304 * 2);
  u16* WoT  = (u16*)allocB((size_t)2304 * 2048 * 2);
  u16* QKV  = (u16*)allocB((size_t)4096 * 4096 * 2);
  u16* VTb  = (u16*)allocB((size_t)4096 * 1024 * 2);
  u16* AO   = (u16*)allocB((size_t)4096 * 2048 * 2);
  float* CT = (float*)allocB((size_t)2048 * 128 * 4);
  float* ST = (float*)allocB((size_t)2048 * 128 * 4);
  float* Lp0 = (float*)allocB((size_t)4096 * 8 * 4);
  float* Lp1 = (float*)allocB((size_t)4096 * 8 * 4);
  // O partials ALIAS the Xb/WqT/WkT/WvT-head region (dead after gemm256)
  u16* Op0 = (u16*)ws;
  u16* Op1 = Op0 + (size_t)4096 * 2048;
  if (off > ws_size) return;

  // fused prep: rope table + X convert + 4 weight transposes (one launch)
  prep_kernel<<<24064, 256, 0, stream>>>(X, Xb, Wq, WqT, Wk, WkT, Wv, WvT, Wo, WoT, CT, ST);

  // fused QKV projection (256² 1-phase counted)  [Xb/WqT/WkT/WvT dead after this]
  gemm256<false><<<dim3(4096 / 256, 4096 / 256), 512, 0, stream>>>(Xb, WqT, QKV, 4096, 4096, 2304);

  // fused mid: rope_k + V-transpose (one launch; 1024 + 4096 blocks)
  mid_kernel<<<5120, 256, 0, stream>>>(QKV, VTb, pos, CT, ST);

  // attention: key-split grid 1024, XCD-pinned (b,g), 2-barrier pipeline
  attn_kernel<<<dim3(1024), 256, 0, stream>>>(QKV, VTb, amask, pos, CT, ST, Op0, Op1, Lp0, Lp1);

  // combine halves -> AO bf16
  combine_o<<<4096, 256, 0, stream>>>(Op0, Op1, Lp0, Lp1, AO);

  // output projection -> fp32 d_out (128² BK=32 pipelined)
  gemm128<true><<<dim3(2304 / 128, 4096 / 128), 256, 0, stream>>>(AO, WoT, out, 4096, 2304, 2048);
}

// Round 23
// 240.821 us; speedup vs baseline: 1.1234x; 1.0045x over previous
//
#include <hip/hip_runtime.h>
#include <hip/hip_bf16.h>
#include <stdint.h>

typedef unsigned short u16;
typedef __attribute__((ext_vector_type(8))) short s16x8;
typedef __attribute__((ext_vector_type(4))) float f32x4;

#define B_ 2
#define S_ 2048
#define H_ 2304
#define NH_ 8
#define NKV_ 4
#define HD_ 256

__device__ __forceinline__ float bf2f(u16 u) {
  union { uint32_t i; float f; } x; x.i = ((uint32_t)u) << 16; return x.f;
}
__device__ __forceinline__ u16 f2bf(float f) {
  union { float f; uint32_t i; } x; x.f = f;
  uint32_t u = x.i;
  return (u16)((u + 0x7fffu + ((u >> 16) & 1u)) >> 16);
}
__device__ __forceinline__ u16 f2bft(float f) {          // truncating (for P: bias cancels in O/l)
  union { float f; uint32_t i; } x; x.f = f;
  return (u16)(x.i >> 16);
}

__device__ __forceinline__ void async16(const void* g, void* l) {
  __builtin_amdgcn_global_load_lds((const __attribute__((address_space(1))) uint32_t*)g,
                                   (__attribute__((address_space(3))) uint32_t*)l, 16, 0, 0);
}

__device__ __forceinline__ f32x4 mfma16(s16x8 a, s16x8 b, f32x4 c) {
  return __builtin_amdgcn_mfma_f32_16x16x32_bf16(a, b, c, 0, 0, 0);
}

// ================= fused prep: rope table + X convert + 4 weight transposes =================
__global__ __launch_bounds__(256) void prep_kernel(
    const float* __restrict__ X, u16* __restrict__ Xb,
    const float* __restrict__ Wq, u16* __restrict__ WqT,
    const float* __restrict__ Wk, u16* __restrict__ WkT,
    const float* __restrict__ Wv, u16* __restrict__ WvT,
    const float* __restrict__ Wo, u16* __restrict__ WoT,
    float* __restrict__ ct, float* __restrict__ st) {
  __shared__ u16 tile[32][33];
  int bid = blockIdx.x, tid = threadIdx.x;

  auto tposeT = [&](const float* in, u16* out, int R, int C, int bx, int by) {
    int c0 = bx * 32, r0 = by * 32;
    int x = tid & 31, y = tid >> 5;
#pragma unroll
    for (int j = 0; j < 32; j += 8)
      tile[y + j][x] = f2bf(in[(size_t)(r0 + y + j) * C + c0 + x]);
    __syncthreads();
#pragma unroll
    for (int j = 0; j < 32; j += 8)
      out[(size_t)(c0 + y + j) * R + r0 + x] = tile[x][y + j];
  };

  if (bid < 1024) {
    int t = bid * 256 + tid;                       // t = p*128 + d
    int d = t & 127;
    int p = t >> 7;
    float invf = exp2f(-(float)d * 0.1038102530f); // log2(10000)/128
    float f = (float)p * invf;
    float s, c;
    sincosf(f, &s, &c);
    ct[t] = c;
    st[t] = s;
  } else if (bid < 10240) {
    size_t i = ((size_t)(bid - 1024) * 256 + tid) * 4;
    float4 v = *(const float4*)(X + i);
    ushort4 o;
    o.x = f2bf(v.x); o.y = f2bf(v.y); o.z = f2bf(v.z); o.w = f2bf(v.w);
    *(ushort4*)(Xb + i) = o;
  } else if (bid < 14848) {
    int b2 = bid - 10240;
    tposeT(Wq, WqT, 2304, 2048, b2 & 63, b2 >> 6);
  } else if (bid < 17152) {
    int b2 = bid - 14848;
    tposeT(Wk, WkT, 2304, 1024, b2 & 31, b2 >> 5);
  } else if (bid < 19456) {
    int b2 = bid - 17152;
    tposeT(Wv, WvT, 2304, 1024, b2 & 31, b2 >> 5);
  } else {
    int b2 = bid - 19456;
    tposeT(Wo, WoT, 2048, 2304, b2 % 72, b2 / 72);
  }
}

// ================= fused mid: rope_k + V-transpose =================
__global__ __launch_bounds__(256) void mid_kernel(u16* __restrict__ QKV, u16* __restrict__ VTb,
                                                  const int* __restrict__ pos_ids,
                                                  const float* __restrict__ ct,
                                                  const float* __restrict__ st) {
  __shared__ u16 tile[32][33];
  int bid = blockIdx.x, tid = threadIdx.x;
  if (bid < 1024) {
    int t = bid * 256 + tid;
    int dg = t & 15, h = (t >> 4) & 3, row = t >> 6;
    u16* p1 = QKV + (size_t)row * 4096 + 2048 + h * 256 + dg * 8;
    u16* p2 = p1 + 128;
    int pos = pos_ids[row];
    const float* ctp = ct + pos * 128 + dg * 8;
    const float* stp = st + pos * 128 + dg * 8;
    s16x8 v1 = *(const s16x8*)p1, v2 = *(const s16x8*)p2;
#pragma unroll
    for (int j = 0; j < 8; j++) {
      float c = ctp[j], s = stp[j];
      float a = bf2f((u16)v1[j]);
      float b = bf2f((u16)v2[j]);
      v1[j] = (short)f2bf(a * c - b * s);
      v2[j] = (short)f2bf(b * c + a * s);
    }
    *(s16x8*)p1 = v1;
    *(s16x8*)p2 = v2;
  } else {
    int b2 = bid - 1024;                       // [0,4096)
    int bx = b2 & 31;
    int by = (b2 >> 5) & 63;
    int z = b2 >> 11;
    const u16* in = QKV + 3072 + (size_t)z * 2048 * 4096;
    u16* out = VTb + (size_t)z * 1024 * 2048;
    int c0 = bx * 32, r0 = by * 32;
    int x = tid & 31, y = tid >> 5;
#pragma unroll
    for (int j = 0; j < 32; j += 8)
      tile[y + j][x] = in[(size_t)(r0 + y + j) * 4096 + c0 + x];
    __syncthreads();
#pragma unroll
    for (int j = 0; j < 32; j += 8)
      out[(size_t)(c0 + y + j) * 2048 + r0 + x] = tile[x][y + j];
  }
}

// ================= 256x256 GEMM, 4-phase interleave + DISTRIBUTED staging =================
// Per K-tile: vmcnt(0) -> BAR (tile t visible; WAR for buf t+1) -> 4 phases:
//   {ds_read A-quadrant (+B in ph0); phases 0-1 issue 4 staging loads for tile t+1;
//    lgkm0 -> setprio(1) -> 16 MFMA -> setprio(0) -> BAR}.
// Ledger: vmcnt(0)@top retires only tile-t loads (t+1's not yet issued); youngest load
// was issued ~2.5 phases earlier. 5 barriers/tile.
template <bool F32OUT>
__global__ __launch_bounds__(512) void gemm256(const u16* __restrict__ A, const u16* __restrict__ BT,
                                               void* __restrict__ Cout, int M, int N, int Kd) {
  __shared__ u16 As[2][256 * 64];
  __shared__ u16 Bs[2][256 * 64];
  int tid = threadIdx.x, lane = tid & 63, wave = tid >> 6;
  int nT = gridDim.x * gridDim.y;
  int bid = blockIdx.y * gridDim.x + blockIdx.x;
  int tile = (bid & 7) * (nT >> 3) + (bid >> 3);        // XCD swizzle (nT % 8 == 0)
  int bn = (tile % gridDim.x) * 256;
  int bm = (tile / gridDim.x) * 256;
  int wm = (wave >> 2) * 128, wn = (wave & 3) * 64;
  int fr = lane & 15, fq = lane >> 4;
  f32x4 acc[8][4];
#pragma unroll
  for (int i = 0; i < 8; i++)
#pragma unroll
    for (int j = 0; j < 4; j++) acc[i][j] = (f32x4){0.f, 0.f, 0.f, 0.f};

  int srow = tid >> 3, sslot = tid & 7;
  int scol = (sslot * 8) ^ ((srow & 7) << 3);           // pre-swizzled source col (u16 units)
  const u16* Ab = A + (size_t)(bm + srow) * Kd + scol;
  const u16* Bb = BT + (size_t)(bn + srow) * Kd + scol;

  // staging slot i: i<4 -> A row-block i; i>=4 -> B row-block i-4
  auto stage1 = [&](int buf, int k0, int i) {
    if (i < 4)
      async16(Ab + (size_t)i * 64 * Kd + k0, (char*)&As[buf][0] + wave * 1024 + i * 8192);
    else
      async16(Bb + (size_t)(i - 4) * 64 * Kd + k0, (char*)&Bs[buf][0] + wave * 1024 + (i - 4) * 8192);
  };

  int NT = Kd >> 6;
  int rsw = (fr & 7) << 3;
#pragma unroll
  for (int i = 0; i < 8; i++) stage1(0, 0, i);          // prologue: tile 0

  for (int t = 0; t < NT; ++t) {
    asm volatile("s_waitcnt vmcnt(0)" ::: "memory");    // retire tile-t loads (issued iter t-1)
    __builtin_amdgcn_sched_barrier(0);
    __builtin_amdgcn_s_barrier();                       // tile t visible; WAR for buf[(t+1)&1]
    __builtin_amdgcn_sched_barrier(0);
    const u16* Ap = &As[t & 1][0];
    const u16* Bp = &Bs[t & 1][0];
    bool more = (t + 1 < NT);
    int nb = (t + 1) & 1;
    int nk = (t + 1) << 6;
    s16x8 bfr[4][2];
#pragma unroll
    for (int q = 0; q < 4; q++) {
      if (q == 0) {
#pragma unroll
        for (int j = 0; j < 4; j++)
#pragma unroll
          for (int s = 0; s < 2; s++)
            bfr[j][s] = *(const s16x8*)&Bp[(wn + j * 16 + fr) * 64 + ((s * 32 + fq * 8) ^ rsw)];
      }
      s16x8 aq[2][2];
#pragma unroll
      for (int rf = 0; rf < 2; rf++)
#pragma unroll
        for (int s = 0; s < 2; s++)
          aq[rf][s] = *(const s16x8*)&Ap[(wm + q * 32 + rf * 16 + fr) * 64 + ((s * 32 + fq * 8) ^ rsw)];
      if (more && q < 2) {                              // front-loaded: 4 loads in ph0, 4 in ph1
#pragma unroll
        for (int i = 0; i < 4; i++) stage1(nb, nk, q * 4 + i);
      }
      asm volatile("s_waitcnt lgkmcnt(0)" ::: "memory");
      __builtin_amdgcn_sched_barrier(0);
      __builtin_amdgcn_s_setprio(1);
#pragma unroll
      for (int rf = 0; rf < 2; rf++)
#pragma unroll
        for (int j = 0; j < 4; j++) {
          acc[q * 2 + rf][j] = mfma16(aq[rf][0], bfr[j][0], acc[q * 2 + rf][j]);
          acc[q * 2 + rf][j] = mfma16(aq[rf][1], bfr[j][1], acc[q * 2 + rf][j]);
        }
      __builtin_amdgcn_s_setprio(0);
      __builtin_amdgcn_sched_barrier(0);
      __builtin_amdgcn_s_barrier();                     // phase close
      __builtin_amdgcn_sched_barrier(0);
    }
  }

#pragma unroll
  for (int i = 0; i < 8; i++)
#pragma unroll
    for (int j = 0; j < 4; j++)
#pragma unroll
      for (int r = 0; r < 4; r++) {
        int row = bm + wm + i * 16 + fq * 4 + r;
        int col = bn + wn + j * 16 + fr;
        if (F32OUT) ((float*)Cout)[(size_t)row * N + col] = acc[i][j][r];
        else        ((u16*)Cout)[(size_t)row * N + col] = f2bf(acc[i][j][r]);
      }
}

// ================= 128x128 pipelined GEMM, BK=32 =================
template <bool F32OUT>
__global__ __launch_bounds__(256) void gemm128(const u16* __restrict__ A, const u16* __restrict__ BT,
                                               void* __restrict__ Cout, int M, int N, int Kd) {
  __shared__ u16 As[2][128 * 32];
  __shared__ u16 Bs[2][128 * 32];
  int tid = threadIdx.x, lane = tid & 63, wave = tid >> 6;
  int nT = gridDim.x * gridDim.y;
  int bid = blockIdx.y * gridDim.x + blockIdx.x;
  int tile = (bid & 7) * (nT >> 3) + (bid >> 3);
  int bn = (tile % gridDim.x) * 128;
  int bm = (tile / gridDim.x) * 128;
  int wm = (wave >> 1) * 64, wn = (wave & 1) * 64;
  int fr = lane & 15, fq = lane >> 4;
  f32x4 acc[4][4];
#pragma unroll
  for (int i = 0; i < 4; i++)
#pragma unroll
    for (int j = 0; j < 4; j++) acc[i][j] = (f32x4){0.f, 0.f, 0.f, 0.f};

  int srow = tid >> 2, sslot = tid & 3;
  int scol = (sslot * 8) ^ ((srow & 3) << 3);
  const u16* Ab = A + (size_t)(bm + srow) * Kd + scol;
  const u16* Bb = BT + (size_t)(bn + srow) * Kd + scol;

  auto stage = [&](int buf, int k0) {
    async16(Ab + k0, (char*)&As[buf][0] + wave * 1024);
    async16(Ab + (size_t)64 * Kd + k0, (char*)&As[buf][0] + wave * 1024 + 4096);
    async16(Bb + k0, (char*)&Bs[buf][0] + wave * 1024);
    async16(Bb + (size_t)64 * Kd + k0, (char*)&Bs[buf][0] + wave * 1024 + 4096);
  };

  int NT = Kd >> 5;
  int rsw = (fr & 3) << 3;
  stage(0, 0);
  for (int t = 0; t < NT; ++t) {
    if (t + 1 < NT) {
      stage((t + 1) & 1, (t + 1) << 5);
      asm volatile("s_waitcnt vmcnt(4)" ::: "memory");
    } else {
      asm volatile("s_waitcnt vmcnt(0)" ::: "memory");
    }
    __builtin_amdgcn_sched_barrier(0);
    __builtin_amdgcn_s_barrier();
    __builtin_amdgcn_sched_barrier(0);
    const u16* Ap = &As[t & 1][0];
    const u16* Bp = &Bs[t & 1][0];
    __builtin_amdgcn_s_setprio(1);
    s16x8 af[4], bv[4];
#pragma unroll
    for (int i = 0; i < 4; i++) af[i] = *(const s16x8*)&Ap[(wm + i * 16 + fr) * 32 + ((fq * 8) ^ rsw)];
#pragma unroll
    for (int j = 0; j < 4; j++) bv[j] = *(const s16x8*)&Bp[(wn + j * 16 + fr) * 32 + ((fq * 8) ^ rsw)];
#pragma unroll
    for (int i = 0; i < 4; i++)
#pragma unroll
      for (int j = 0; j < 4; j++)
        acc[i][j] = mfma16(af[i], bv[j], acc[i][j]);
    __builtin_amdgcn_s_setprio(0);
    asm volatile("s_waitcnt lgkmcnt(0)" ::: "memory");
    __builtin_amdgcn_sched_barrier(0);
    __builtin_amdgcn_s_barrier();
  }
#pragma unroll
  for (int i = 0; i < 4; i++)
#pragma unroll
    for (int j = 0; j < 4; j++)
#pragma unroll
      for (int r = 0; r < 4; r++) {
        int row = bm + wm + i * 16 + fq * 4 + r;
        int col = bn + wn + j * 16 + fr;
        if (F32OUT) ((float*)Cout)[(size_t)row * N + col] = acc[i][j][r];
        else        ((u16*)Cout)[(size_t)row * N + col] = f2bf(acc[i][j][r]);
      }
}

// ---------------- flash attention, KEY-SPLIT, 2-barrier race-free pipeline ----------
__global__ __launch_bounds__(256) void attn_kernel(const u16* __restrict__ QKV, const u16* __restrict__ VT,
                                                   const int* __restrict__ amask, const int* __restrict__ pos_ids,
                                                   const float* __restrict__ ct, const float* __restrict__ st,
                                                   u16* __restrict__ O0, u16* __restrict__ O1,
                                                   float* __restrict__ L0, float* __restrict__ L1) {
  __shared__ u16 Kl[2][32 * 256];        // K double buffer; granule swz: slot ^= key&7
  __shared__ u16 Vl[256 * 32];           // V single buffer; granule swz: slot ^= (hd>>1)&3
  __shared__ u16 Pl[4][16 * 32];         // per-wave P, XOR-swizzled cols
  __shared__ unsigned char Mb[256];      // bit-packed amask (2048 bits)
  int id = blockIdx.x;
  int bg = id & 7;                        // XCD-pinned (b,g)
  int r_ = id >> 3;
  int qt = 31 - (r_ >> 2);                // heavy first
  int hl = (r_ >> 1) & 1;
  int half = r_ & 1;
  int b = bg >> 2, g = bg & 3;
  int h = g * 2 + hl;
  int tid = threadIdx.x, lane = tid & 63, wave = tid >> 6;
  int fr = lane & 15, fq = lane >> 4;
  int q0 = qt * 64;
  u16* Op = half ? O1 : O0;
  float* Lp = half ? L1 : L0;

  // ---- bit-pack attention mask ----
  const int* amp = amask + b * S_;
  {
    int4 a = *(const int4*)(amp + tid * 8);
    int4 c = *(const int4*)(amp + tid * 8 + 4);
    unsigned v = (unsigned)(a.x > 0) | ((unsigned)(a.y > 0) << 1) | ((unsigned)(a.z > 0) << 2) |
                 ((unsigned)(a.w > 0) << 3) | ((unsigned)(c.x > 0) << 4) | ((unsigned)(c.y > 0) << 5) |
                 ((unsigned)(c.z > 0) << 6) | ((unsigned)(c.w > 0) << 7);
    Mb[tid] = (unsigned char)v;
  }

  // ---- load Q rows wave*16+fr, apply RoPE in-register, scale 1/16 ----
  int qrow_g = b * S_ + q0 + wave * 16 + fr;
  s16x8 qr[8];
  const u16* qb = QKV + (size_t)qrow_g * 4096 + h * 256 + fq * 8;
#pragma unroll
  for (int kk = 0; kk < 8; kk++) qr[kk] = *(const s16x8*)(qb + kk * 32);
  int pos = pos_ids[qrow_g];
  const float* ctp = ct + pos * 128 + fq * 8;
  const float* stp = st + pos * 128 + fq * 8;
  s16x8 qf[8];
#pragma unroll
  for (int kk = 0; kk < 4; kk++) {
#pragma unroll
    for (int jj = 0; jj < 8; jj++) {
      float c = ctp[kk * 32 + jj], s = stp[kk * 32 + jj];
      float a = bf2f((u16)qr[kk][jj]);
      float bb = bf2f((u16)qr[kk + 4][jj]);
      qf[kk][jj]     = (short)f2bf((a * c - bb * s) * 0.0625f);
      qf[kk + 4][jj] = (short)f2bf((bb * c + a * s) * 0.0625f);
    }
  }

  f32x4 zero4 = {0.f, 0.f, 0.f, 0.f};
  f32x4 oacc[16];
#pragma unroll
  for (int i = 0; i < 16; i++) oacc[i] = zero4;
  f32x4 lacc = zero4;
  s16x8 onesv;
#pragma unroll
  for (int i = 0; i < 8; i++) onesv[i] = (short)0x3F80;

  const u16* Kbase = QKV + (size_t)b * S_ * 4096 + 2048 + g * 256;
  const u16* Vbase = VT + (size_t)(b * 4 + g) * 256 * S_;

  const u16* KsP[4];
  const u16* VsP[4];
  int dst16[4];
#pragma unroll
  for (int i = 0; i < 4; i++) {
    int c = tid + i * 256;
    int key = c >> 5, slot = c & 31;
    KsP[i] = Kbase + (size_t)key * 4096 + ((slot ^ (key & 7)) * 8);
    int hd = c >> 2, vs = c & 3;
    VsP[i] = Vbase + (size_t)hd * 2048 + ((vs ^ ((hd >> 1) & 3)) * 8);
    dst16[i] = c * 16;
  }

  __syncthreads();                                  // Mb visible; all prologue vmem drained

  // prologue: stage K(half)
#pragma unroll
  for (int i = 0; i < 4; i++)
    async16(KsP[i] + (size_t)(half * 32) * 4096, (char*)&Kl[0][0] + dst16[i]);

  int nt = 2 * qt + 2;
  int ksw = fr & 7;
  int vswl = (fr >> 1) & 3;
  int psw = (fr & 3) << 3;
  int kb = 0;
  for (int t = half; t < nt; t += 2) {
    int k0 = t * 32;
    bool more = (t + 2 < nt);
    asm volatile("s_waitcnt vmcnt(0)" ::: "memory");     // retire K(t)
    __builtin_amdgcn_sched_barrier(0);
    __builtin_amdgcn_s_barrier();                        // BAR-A
    __builtin_amdgcn_sched_barrier(0);

#pragma unroll
    for (int i = 0; i < 4; i++)
      async16(VsP[i] + k0, (char*)&Vl[0] + dst16[i]);
    if (more) {
#pragma unroll
      for (int i = 0; i < 4; i++)
        async16(KsP[i] + (size_t)(k0 + 64) * 4096, (char*)&Kl[kb ^ 1][0] + dst16[i]);
    }

    const u16* Kp = &Kl[kb][0];
    __builtin_amdgcn_s_setprio(1);
    f32x4 s0 = zero4, s1 = zero4;
#pragma unroll
    for (int kk = 0; kk < 8; kk++) {
      s16x8 b0 = *(const s16x8*)&Kp[fr * 256 + (((kk * 4 + fq) ^ ksw) * 8)];
      s16x8 b1 = *(const s16x8*)&Kp[(16 + fr) * 256 + (((kk * 4 + fq) ^ ksw) * 8)];
      s0 = mfma16(qf[kk], b0, s0);
      s1 = mfma16(qf[kk], b1, s1);
    }
    __builtin_amdgcn_s_setprio(0);

    int am0 = (Mb[(k0 + fr) >> 3] >> ((k0 + fr) & 7)) & 1;
    int am1 = (Mb[(k0 + 16 + fr) >> 3] >> ((k0 + 16 + fr) & 7)) & 1;
    bool needmask = (t >= nt - 2);                       // wave-uniform
    float pv0[4], pv1[4];
#pragma unroll
    for (int r = 0; r < 4; r++) {
      float e20 = __expf(s0[r] * 0.04f);
      float e21 = __expf(s1[r] * 0.04f);
      pv0[r] = __expf(__fdividef(-100.f, e20 + 1.f));
      pv1[r] = __expf(__fdividef(-100.f, e21 + 1.f));
    }
    if (needmask) {
#pragma unroll
      for (int r = 0; r < 4; r++) {
        int qg = q0 + wave * 16 + fq * 4 + r;
        if (!((k0 + fr) <= qg)) pv0[r] = 0.f;
        if (!((k0 + 16 + fr) <= qg)) pv1[r] = 0.f;
      }
    }
#pragma unroll
    for (int r = 0; r < 4; r++) {
      int qrow = fq * 4 + r;
      float p0 = am0 ? pv0[r] : 0.f;
      float p1 = am1 ? pv1[r] : 0.f;
      Pl[wave][qrow * 32 + (fr ^ (r << 3))] = f2bft(p0);
      Pl[wave][qrow * 32 + ((16 + fr) ^ (r << 3))] = f2bft(p1);
    }
    asm volatile("s_waitcnt lgkmcnt(0)" ::: "memory");
    __builtin_amdgcn_sched_barrier(0);
    if (more)
      asm volatile("s_waitcnt vmcnt(4)" ::: "memory");
    else
      asm volatile("s_waitcnt vmcnt(0)" ::: "memory");
    __builtin_amdgcn_sched_barrier(0);
    __builtin_amdgcn_s_barrier();                        // BAR-C
    __builtin_amdgcn_sched_barrier(0);

    s16x8 pf = *(const s16x8*)&Pl[wave][fr * 32 + ((fq * 8) ^ psw)];
    __builtin_amdgcn_s_setprio(1);
    lacc = mfma16(pf, onesv, lacc);
#pragma unroll
    for (int df = 0; df < 16; df++) {
      s16x8 vv = *(const s16x8*)&Vl[(df * 16 + fr) * 32 + ((fq ^ vswl) * 8)];
      oacc[df] = mfma16(pf, vv, oacc[df]);
    }
    __builtin_amdgcn_s_setprio(0);
    asm volatile("s_waitcnt lgkmcnt(0)" ::: "memory");
    __builtin_amdgcn_sched_barrier(0);
    kb ^= 1;
  }

  if (fr == 0) {
#pragma unroll
    for (int r = 0; r < 4; r++)
      Lp[(size_t)(b * S_ + q0 + wave * 16 + fq * 4 + r) * 8 + h] = lacc[r];
  }
#pragma unroll
  for (int df = 0; df < 16; df++) {
#pragma unroll
    for (int r = 0; r < 4; r++) {
      Op[(size_t)(b * S_ + q0 + wave * 16 + fq * 4 + r) * 2048 + h * 256 + df * 16 + fr] =
          f2bf(oacc[df][r]);
    }
  }
}

// ---------------- combine partial halves: AO = (O0+O1)/(l0+l1) ----------------
__global__ void combine_o(const u16* __restrict__ O0, const u16* __restrict__ O1,
                          const float* __restrict__ L0, const float* __restrict__ L1,
                          u16* __restrict__ AO) {
  int idx = blockIdx.x * blockDim.x + threadIdx.x;
  int row = idx >> 8;
  int cg = idx & 255;
  int h = cg >> 5;
  float rinv = 1.0f / (L0[row * 8 + h] + L1[row * 8 + h]);
  size_t base = (size_t)row * 2048 + cg * 8;
  s16x8 a = *(const s16x8*)(O0 + base);
  s16x8 b = *(const s16x8*)(O1 + base);
  s16x8 o;
#pragma unroll
  for (int j = 0; j < 8; j++)
    o[j] = (short)f2bf((bf2f((u16)a[j]) + bf2f((u16)b[j])) * rinv);
  *(s16x8*)(AO + base) = o;
}

extern "C" void kernel_launch(void* const* d_in, const int* in_sizes, int n_in,
                              void* d_out, int out_size, void* d_ws, size_t ws_size,
                              hipStream_t stream) {
  const float* X   = (const float*)d_in[0];   // [B,S,H] fp32
  const int* amask = (const int*)d_in[1];
  const int* pos   = (const int*)d_in[2];
  const float* Wq  = (const float*)d_in[3];
  const float* Wk  = (const float*)d_in[4];
  const float* Wv  = (const float*)d_in[5];
  const float* Wo  = (const float*)d_in[6];
  float* out = (float*)d_out;                 // [B,S,H] fp32

  char* ws = (char*)d_ws;
  size_t off = 0;
  auto allocB = [&](size_t bytes) {
    char* p = ws + off;
    off += ((bytes + 255) & ~(size_t)255);
    return p;
  };
  u16* Xb   = (u16*)allocB((size_t)4096 * 2304 * 2);
  u16* WqT  = (u16*)allocB((size_t)2048 * 2304 * 2);   // WqT/WkT/WvT contiguous => fused B^T
  u16* WkT  = (u16*)allocB((size_t)1024 * 2304 * 2);
  u16* WvT  = (u16*)allocB((size_t)1024 * 2304 * 2);
  u16* WoT  = (u16*)allocB((size_t)2304 * 2048 * 2);
  u16* QKV  = (u16*)allocB((size_t)4096 * 4096 * 2);
  u16* VTb  = (u16*)allocB((size_t)4096 * 1024 * 2);
  u16* AO   = (u16*)allocB((size_t)4096 * 2048 * 2);
  float* CT = (float*)allocB((size_t)2048 * 128 * 4);
  float* ST = (float*)allocB((size_t)2048 * 128 * 4);
  float* Lp0 = (float*)allocB((size_t)4096 * 8 * 4);
  float* Lp1 = (float*)allocB((size_t)4096 * 8 * 4);
  // O partials ALIAS the Xb/WqT/WkT/WvT-head region (dead after gemm256)
  u16* Op0 = (u16*)ws;
  u16* Op1 = Op0 + (size_t)4096 * 2048;
  if (off > ws_size) return;

  // fused prep: rope table + X convert + 4 weight transposes (one launch)
  prep_kernel<<<24064, 256, 0, stream>>>(X, Xb, Wq, WqT, Wk, WkT, Wv, WvT, Wo, WoT, CT, ST);

  // fused QKV projection (256² 4-phase interleave + distributed staging)
  gemm256<false><<<dim3(4096 / 256, 4096 / 256), 512, 0, stream>>>(Xb, WqT, QKV, 4096, 4096, 2304);

  // fused mid: rope_k + V-transpose (one launch; 1024 + 4096 blocks)
  mid_kernel<<<5120, 256, 0, stream>>>(QKV, VTb, pos, CT, ST);

  // attention: key-split grid 1024, XCD-pinned (b,g), 2-barrier pipeline
  attn_kernel<<<dim3(1024), 256, 0, stream>>>(QKV, VTb, amask, pos, CT, ST, Op0, Op1, Lp0, Lp1);

  // combine halves -> AO bf16
  combine_o<<<4096, 256, 0, stream>>>(Op0, Op1, Lp0, Lp1, AO);

  // output projection -> fp32 d_out (128² BK=32 pipelined)
  gemm128<true><<<dim3(2304 / 128, 4096 / 128), 256, 0, stream>>>(AO, WoT, out, 4096, 2304, 2048);
}

// Round 24
// 239.288 us; speedup vs baseline: 1.1306x; 1.0064x over previous
//
#include <hip/hip_runtime.h>
#include <hip/hip_bf16.h>
#include <stdint.h>

typedef unsigned short u16;
typedef __attribute__((ext_vector_type(8))) short s16x8;
typedef __attribute__((ext_vector_type(4))) float f32x4;

#define B_ 2
#define S_ 2048
#define H_ 2304
#define NH_ 8
#define NKV_ 4
#define HD_ 256

__device__ __forceinline__ float bf2f(u16 u) {
  union { uint32_t i; float f; } x; x.i = ((uint32_t)u) << 16; return x.f;
}
__device__ __forceinline__ u16 f2bf(float f) {
  union { float f; uint32_t i; } x; x.f = f;
  uint32_t u = x.i;
  return (u16)((u + 0x7fffu + ((u >> 16) & 1u)) >> 16);
}
__device__ __forceinline__ u16 f2bft(float f) {          // truncating (for P: bias cancels in O/l)
  union { float f; uint32_t i; } x; x.f = f;
  return (u16)(x.i >> 16);
}

__device__ __forceinline__ void async16(const void* g, void* l) {
  __builtin_amdgcn_global_load_lds((const __attribute__((address_space(1))) uint32_t*)g,
                                   (__attribute__((address_space(3))) uint32_t*)l, 16, 0, 0);
}

__device__ __forceinline__ f32x4 mfma16(s16x8 a, s16x8 b, f32x4 c) {
  return __builtin_amdgcn_mfma_f32_16x16x32_bf16(a, b, c, 0, 0, 0);
}

// ================= fused prep: rope table + X convert + 4 weight transposes =================
__global__ __launch_bounds__(256) void prep_kernel(
    const float* __restrict__ X, u16* __restrict__ Xb,
    const float* __restrict__ Wq, u16* __restrict__ WqT,
    const float* __restrict__ Wk, u16* __restrict__ WkT,
    const float* __restrict__ Wv, u16* __restrict__ WvT,
    const float* __restrict__ Wo, u16* __restrict__ WoT,
    float* __restrict__ ct, float* __restrict__ st) {
  __shared__ u16 tile[32][33];
  int bid = blockIdx.x, tid = threadIdx.x;

  auto tposeT = [&](const float* in, u16* out, int R, int C, int bx, int by) {
    int c0 = bx * 32, r0 = by * 32;
    int x = tid & 31, y = tid >> 5;
#pragma unroll
    for (int j = 0; j < 32; j += 8)
      tile[y + j][x] = f2bf(in[(size_t)(r0 + y + j) * C + c0 + x]);
    __syncthreads();
#pragma unroll
    for (int j = 0; j < 32; j += 8)
      out[(size_t)(c0 + y + j) * R + r0 + x] = tile[x][y + j];
  };

  if (bid < 1024) {
    int t = bid * 256 + tid;                       // t = p*128 + d
    int d = t & 127;
    int p = t >> 7;
    float invf = exp2f(-(float)d * 0.1038102530f); // log2(10000)/128
    float f = (float)p * invf;
    float s, c;
    sincosf(f, &s, &c);
    ct[t] = c;
    st[t] = s;
  } else if (bid < 10240) {
    size_t i = ((size_t)(bid - 1024) * 256 + tid) * 4;
    float4 v = *(const float4*)(X + i);
    ushort4 o;
    o.x = f2bf(v.x); o.y = f2bf(v.y); o.z = f2bf(v.z); o.w = f2bf(v.w);
    *(ushort4*)(Xb + i) = o;
  } else if (bid < 14848) {
    int b2 = bid - 10240;
    tposeT(Wq, WqT, 2304, 2048, b2 & 63, b2 >> 6);
  } else if (bid < 17152) {
    int b2 = bid - 14848;
    tposeT(Wk, WkT, 2304, 1024, b2 & 31, b2 >> 5);
  } else if (bid < 19456) {
    int b2 = bid - 17152;
    tposeT(Wv, WvT, 2304, 1024, b2 & 31, b2 >> 5);
  } else {
    int b2 = bid - 19456;
    tposeT(Wo, WoT, 2048, 2304, b2 % 72, b2 / 72);
  }
}

// ================= fused mid: rope_k + V-transpose =================
__global__ __launch_bounds__(256) void mid_kernel(u16* __restrict__ QKV, u16* __restrict__ VTb,
                                                  const int* __restrict__ pos_ids,
                                                  const float* __restrict__ ct,
                                                  const float* __restrict__ st) {
  __shared__ u16 tile[32][33];
  int bid = blockIdx.x, tid = threadIdx.x;
  if (bid < 1024) {
    int t = bid * 256 + tid;
    int dg = t & 15, h = (t >> 4) & 3, row = t >> 6;
    u16* p1 = QKV + (size_t)row * 4096 + 2048 + h * 256 + dg * 8;
    u16* p2 = p1 + 128;
    int pos = pos_ids[row];
    const float* ctp = ct + pos * 128 + dg * 8;
    const float* stp = st + pos * 128 + dg * 8;
    s16x8 v1 = *(const s16x8*)p1, v2 = *(const s16x8*)p2;
#pragma unroll
    for (int j = 0; j < 8; j++) {
      float c = ctp[j], s = stp[j];
      float a = bf2f((u16)v1[j]);
      float b = bf2f((u16)v2[j]);
      v1[j] = (short)f2bf(a * c - b * s);
      v2[j] = (short)f2bf(b * c + a * s);
    }
    *(s16x8*)p1 = v1;
    *(s16x8*)p2 = v2;
  } else {
    int b2 = bid - 1024;                       // [0,4096)
    int bx = b2 & 31;
    int by = (b2 >> 5) & 63;
    int z = b2 >> 11;
    const u16* in = QKV + 3072 + (size_t)z * 2048 * 4096;
    u16* out = VTb + (size_t)z * 1024 * 2048;
    int c0 = bx * 32, r0 = by * 32;
    int x = tid & 31, y = tid >> 5;
#pragma unroll
    for (int j = 0; j < 32; j += 8)
      tile[y + j][x] = in[(size_t)(r0 + y + j) * 4096 + c0 + x];
    __syncthreads();
#pragma unroll
    for (int j = 0; j < 32; j += 8)
      out[(size_t)(c0 + y + j) * 2048 + r0 + x] = tile[x][y + j];
  }
}

// ======== 256x256 GEMM, 4-phase interleave + distributed staging, 1 barrier/tile ========
// Within a tile, phases only READ buf[t&1] (no cross-wave LDS hazard); staging writes go
// to the other buffer, WAR-protected by the TOP barrier (last readers of buf[(t+1)&1]
// finished their ds_reads -- lgkm0 precedes every MFMA cluster -- before reaching it).
// Phase-close barriers are redundant; sched_barrier(0) pins the static interleave.
template <bool F32OUT>
__global__ __launch_bounds__(512) void gemm256(const u16* __restrict__ A, const u16* __restrict__ BT,
                                               void* __restrict__ Cout, int M, int N, int Kd) {
  __shared__ u16 As[2][256 * 64];
  __shared__ u16 Bs[2][256 * 64];
  int tid = threadIdx.x, lane = tid & 63, wave = tid >> 6;
  int nT = gridDim.x * gridDim.y;
  int bid = blockIdx.y * gridDim.x + blockIdx.x;
  int tile = (bid & 7) * (nT >> 3) + (bid >> 3);        // XCD swizzle (nT % 8 == 0)
  int bn = (tile % gridDim.x) * 256;
  int bm = (tile / gridDim.x) * 256;
  int wm = (wave >> 2) * 128, wn = (wave & 3) * 64;
  int fr = lane & 15, fq = lane >> 4;
  f32x4 acc[8][4];
#pragma unroll
  for (int i = 0; i < 8; i++)
#pragma unroll
    for (int j = 0; j < 4; j++) acc[i][j] = (f32x4){0.f, 0.f, 0.f, 0.f};

  int srow = tid >> 3, sslot = tid & 7;
  int scol = (sslot * 8) ^ ((srow & 7) << 3);           // pre-swizzled source col (u16 units)
  const u16* Ab = A + (size_t)(bm + srow) * Kd + scol;
  const u16* Bb = BT + (size_t)(bn + srow) * Kd + scol;

  // staging slot i: i<4 -> A row-block i; i>=4 -> B row-block i-4
  auto stage1 = [&](int buf, int k0, int i) {
    if (i < 4)
      async16(Ab + (size_t)i * 64 * Kd + k0, (char*)&As[buf][0] + wave * 1024 + i * 8192);
    else
      async16(Bb + (size_t)(i - 4) * 64 * Kd + k0, (char*)&Bs[buf][0] + wave * 1024 + (i - 4) * 8192);
  };

  int NT = Kd >> 6;
  int rsw = (fr & 7) << 3;
#pragma unroll
  for (int i = 0; i < 8; i++) stage1(0, 0, i);          // prologue: tile 0

  for (int t = 0; t < NT; ++t) {
    asm volatile("s_waitcnt vmcnt(0)" ::: "memory");    // retire tile-t loads (issued iter t-1)
    __builtin_amdgcn_sched_barrier(0);
    __builtin_amdgcn_s_barrier();                       // tile t visible; WAR for buf[(t+1)&1]
    __builtin_amdgcn_sched_barrier(0);
    const u16* Ap = &As[t & 1][0];
    const u16* Bp = &Bs[t & 1][0];
    bool more = (t + 1 < NT);
    int nb = (t + 1) & 1;
    int nk = (t + 1) << 6;
    s16x8 bfr[4][2];
#pragma unroll
    for (int q = 0; q < 4; q++) {
      if (q == 0) {
#pragma unroll
        for (int j = 0; j < 4; j++)
#pragma unroll
          for (int s = 0; s < 2; s++)
            bfr[j][s] = *(const s16x8*)&Bp[(wn + j * 16 + fr) * 64 + ((s * 32 + fq * 8) ^ rsw)];
      }
      s16x8 aq[2][2];
#pragma unroll
      for (int rf = 0; rf < 2; rf++)
#pragma unroll
        for (int s = 0; s < 2; s++)
          aq[rf][s] = *(const s16x8*)&Ap[(wm + q * 32 + rf * 16 + fr) * 64 + ((s * 32 + fq * 8) ^ rsw)];
      if (more && q < 2) {                              // front-loaded: 4 loads in ph0, 4 in ph1
#pragma unroll
        for (int i = 0; i < 4; i++) stage1(nb, nk, q * 4 + i);
      }
      asm volatile("s_waitcnt lgkmcnt(0)" ::: "memory");
      __builtin_amdgcn_sched_barrier(0);
      __builtin_amdgcn_s_setprio(1);
#pragma unroll
      for (int rf = 0; rf < 2; rf++)
#pragma unroll
        for (int j = 0; j < 4; j++) {
          acc[q * 2 + rf][j] = mfma16(aq[rf][0], bfr[j][0], acc[q * 2 + rf][j]);
          acc[q * 2 + rf][j] = mfma16(aq[rf][1], bfr[j][1], acc[q * 2 + rf][j]);
        }
      __builtin_amdgcn_s_setprio(0);
      __builtin_amdgcn_sched_barrier(0);                // pin interleave only (no s_barrier)
    }
  }

#pragma unroll
  for (int i = 0; i < 8; i++)
#pragma unroll
    for (int j = 0; j < 4; j++)
#pragma unroll
      for (int r = 0; r < 4; r++) {
        int row = bm + wm + i * 16 + fq * 4 + r;
        int col = bn + wn + j * 16 + fr;
        if (F32OUT) ((float*)Cout)[(size_t)row * N + col] = acc[i][j][r];
        else        ((u16*)Cout)[(size_t)row * N + col] = f2bf(acc[i][j][r]);
      }
}

// ================= 128x128 pipelined GEMM, BK=32 =================
template <bool F32OUT>
__global__ __launch_bounds__(256) void gemm128(const u16* __restrict__ A, const u16* __restrict__ BT,
                                               void* __restrict__ Cout, int M, int N, int Kd) {
  __shared__ u16 As[2][128 * 32];
  __shared__ u16 Bs[2][128 * 32];
  int tid = threadIdx.x, lane = tid & 63, wave = tid >> 6;
  int nT = gridDim.x * gridDim.y;
  int bid = blockIdx.y * gridDim.x + blockIdx.x;
  int tile = (bid & 7) * (nT >> 3) + (bid >> 3);
  int bn = (tile % gridDim.x) * 128;
  int bm = (tile / gridDim.x) * 128;
  int wm = (wave >> 1) * 64, wn = (wave & 1) * 64;
  int fr = lane & 15, fq = lane >> 4;
  f32x4 acc[4][4];
#pragma unroll
  for (int i = 0; i < 4; i++)
#pragma unroll
    for (int j = 0; j < 4; j++) acc[i][j] = (f32x4){0.f, 0.f, 0.f, 0.f};

  int srow = tid >> 2, sslot = tid & 3;
  int scol = (sslot * 8) ^ ((srow & 3) << 3);
  const u16* Ab = A + (size_t)(bm + srow) * Kd + scol;
  const u16* Bb = BT + (size_t)(bn + srow) * Kd + scol;

  auto stage = [&](int buf, int k0) {
    async16(Ab + k0, (char*)&As[buf][0] + wave * 1024);
    async16(Ab + (size_t)64 * Kd + k0, (char*)&As[buf][0] + wave * 1024 + 4096);
    async16(Bb + k0, (char*)&Bs[buf][0] + wave * 1024);
    async16(Bb + (size_t)64 * Kd + k0, (char*)&Bs[buf][0] + wave * 1024 + 4096);
  };

  int NT = Kd >> 5;
  int rsw = (fr & 3) << 3;
  stage(0, 0);
  for (int t = 0; t < NT; ++t) {
    if (t + 1 < NT) {
      stage((t + 1) & 1, (t + 1) << 5);
      asm volatile("s_waitcnt vmcnt(4)" ::: "memory");
    } else {
      asm volatile("s_waitcnt vmcnt(0)" ::: "memory");
    }
    __builtin_amdgcn_sched_barrier(0);
    __builtin_amdgcn_s_barrier();
    __builtin_amdgcn_sched_barrier(0);
    const u16* Ap = &As[t & 1][0];
    const u16* Bp = &Bs[t & 1][0];
    __builtin_amdgcn_s_setprio(1);
    s16x8 af[4], bv[4];
#pragma unroll
    for (int i = 0; i < 4; i++) af[i] = *(const s16x8*)&Ap[(wm + i * 16 + fr) * 32 + ((fq * 8) ^ rsw)];
#pragma unroll
    for (int j = 0; j < 4; j++) bv[j] = *(const s16x8*)&Bp[(wn + j * 16 + fr) * 32 + ((fq * 8) ^ rsw)];
#pragma unroll
    for (int i = 0; i < 4; i++)
#pragma unroll
      for (int j = 0; j < 4; j++)
        acc[i][j] = mfma16(af[i], bv[j], acc[i][j]);
    __builtin_amdgcn_s_setprio(0);
    asm volatile("s_waitcnt lgkmcnt(0)" ::: "memory");
    __builtin_amdgcn_sched_barrier(0);
    __builtin_amdgcn_s_barrier();
  }
#pragma unroll
  for (int i = 0; i < 4; i++)
#pragma unroll
    for (int j = 0; j < 4; j++)
#pragma unroll
      for (int r = 0; r < 4; r++) {
        int row = bm + wm + i * 16 + fq * 4 + r;
        int col = bn + wn + j * 16 + fr;
        if (F32OUT) ((float*)Cout)[(size_t)row * N + col] = acc[i][j][r];
        else        ((u16*)Cout)[(size_t)row * N + col] = f2bf(acc[i][j][r]);
      }
}

// ---------------- flash attention, KEY-SPLIT, 2-barrier race-free pipeline ----------
__global__ __launch_bounds__(256) void attn_kernel(const u16* __restrict__ QKV, const u16* __restrict__ VT,
                                                   const int* __restrict__ amask, const int* __restrict__ pos_ids,
                                                   const float* __restrict__ ct, const float* __restrict__ st,
                                                   u16* __restrict__ O0, u16* __restrict__ O1,
                                                   float* __restrict__ L0, float* __restrict__ L1) {
  __shared__ u16 Kl[2][32 * 256];        // K double buffer; granule swz: slot ^= key&7
  __shared__ u16 Vl[256 * 32];           // V single buffer; granule swz: slot ^= (hd>>1)&3
  __shared__ u16 Pl[4][16 * 32];         // per-wave P, XOR-swizzled cols
  __shared__ unsigned char Mb[256];      // bit-packed amask (2048 bits)
  int id = blockIdx.x;
  int bg = id & 7;                        // XCD-pinned (b,g)
  int r_ = id >> 3;
  int qt = 31 - (r_ >> 2);                // heavy first
  int hl = (r_ >> 1) & 1;
  int half = r_ & 1;
  int b = bg >> 2, g = bg & 3;
  int h = g * 2 + hl;
  int tid = threadIdx.x, lane = tid & 63, wave = tid >> 6;
  int fr = lane & 15, fq = lane >> 4;
  int q0 = qt * 64;
  u16* Op = half ? O1 : O0;
  float* Lp = half ? L1 : L0;

  // ---- bit-pack attention mask ----
  const int* amp = amask + b * S_;
  {
    int4 a = *(const int4*)(amp + tid * 8);
    int4 c = *(const int4*)(amp + tid * 8 + 4);
    unsigned v = (unsigned)(a.x > 0) | ((unsigned)(a.y > 0) << 1) | ((unsigned)(a.z > 0) << 2) |
                 ((unsigned)(a.w > 0) << 3) | ((unsigned)(c.x > 0) << 4) | ((unsigned)(c.y > 0) << 5) |
                 ((unsigned)(c.z > 0) << 6) | ((unsigned)(c.w > 0) << 7);
    Mb[tid] = (unsigned char)v;
  }

  // ---- load Q rows wave*16+fr, apply RoPE in-register, scale 1/16 ----
  int qrow_g = b * S_ + q0 + wave * 16 + fr;
  s16x8 qr[8];
  const u16* qb = QKV + (size_t)qrow_g * 4096 + h * 256 + fq * 8;
#pragma unroll
  for (int kk = 0; kk < 8; kk++) qr[kk] = *(const s16x8*)(qb + kk * 32);
  int pos = pos_ids[qrow_g];
  const float* ctp = ct + pos * 128 + fq * 8;
  const float* stp = st + pos * 128 + fq * 8;
  s16x8 qf[8];
#pragma unroll
  for (int kk = 0; kk < 4; kk++) {
#pragma unroll
    for (int jj = 0; jj < 8; jj++) {
      float c = ctp[kk * 32 + jj], s = stp[kk * 32 + jj];
      float a = bf2f((u16)qr[kk][jj]);
      float bb = bf2f((u16)qr[kk + 4][jj]);
      qf[kk][jj]     = (short)f2bf((a * c - bb * s) * 0.0625f);
      qf[kk + 4][jj] = (short)f2bf((bb * c + a * s) * 0.0625f);
    }
  }

  f32x4 zero4 = {0.f, 0.f, 0.f, 0.f};
  f32x4 oacc[16];
#pragma unroll
  for (int i = 0; i < 16; i++) oacc[i] = zero4;
  f32x4 lacc = zero4;
  s16x8 onesv;
#pragma unroll
  for (int i = 0; i < 8; i++) onesv[i] = (short)0x3F80;

  const u16* Kbase = QKV + (size_t)b * S_ * 4096 + 2048 + g * 256;
  const u16* Vbase = VT + (size_t)(b * 4 + g) * 256 * S_;

  const u16* KsP[4];
  const u16* VsP[4];
  int dst16[4];
#pragma unroll
  for (int i = 0; i < 4; i++) {
    int c = tid + i * 256;
    int key = c >> 5, slot = c & 31;
    KsP[i] = Kbase + (size_t)key * 4096 + ((slot ^ (key & 7)) * 8);
    int hd = c >> 2, vs = c & 3;
    VsP[i] = Vbase + (size_t)hd * 2048 + ((vs ^ ((hd >> 1) & 3)) * 8);
    dst16[i] = c * 16;
  }

  __syncthreads();                                  // Mb visible; all prologue vmem drained

  // prologue: stage K(half)
#pragma unroll
  for (int i = 0; i < 4; i++)
    async16(KsP[i] + (size_t)(half * 32) * 4096, (char*)&Kl[0][0] + dst16[i]);

  int nt = 2 * qt + 2;
  int ksw = fr & 7;
  int vswl = (fr >> 1) & 3;
  int psw = (fr & 3) << 3;
  int kb = 0;
  for (int t = half; t < nt; t += 2) {
    int k0 = t * 32;
    bool more = (t + 2 < nt);
    asm volatile("s_waitcnt vmcnt(0)" ::: "memory");     // retire K(t)
    __builtin_amdgcn_sched_barrier(0);
    __builtin_amdgcn_s_barrier();                        // BAR-A
    __builtin_amdgcn_sched_barrier(0);

#pragma unroll
    for (int i = 0; i < 4; i++)
      async16(VsP[i] + k0, (char*)&Vl[0] + dst16[i]);
    if (more) {
#pragma unroll
      for (int i = 0; i < 4; i++)
        async16(KsP[i] + (size_t)(k0 + 64) * 4096, (char*)&Kl[kb ^ 1][0] + dst16[i]);
    }

    const u16* Kp = &Kl[kb][0];
    __builtin_amdgcn_s_setprio(1);
    f32x4 s0 = zero4, s1 = zero4;
#pragma unroll
    for (int kk = 0; kk < 8; kk++) {
      s16x8 b0 = *(const s16x8*)&Kp[fr * 256 + (((kk * 4 + fq) ^ ksw) * 8)];
      s16x8 b1 = *(const s16x8*)&Kp[(16 + fr) * 256 + (((kk * 4 + fq) ^ ksw) * 8)];
      s0 = mfma16(qf[kk], b0, s0);
      s1 = mfma16(qf[kk], b1, s1);
    }
    __builtin_amdgcn_s_setprio(0);

    int am0 = (Mb[(k0 + fr) >> 3] >> ((k0 + fr) & 7)) & 1;
    int am1 = (Mb[(k0 + 16 + fr) >> 3] >> ((k0 + 16 + fr) & 7)) & 1;
    bool needmask = (t >= nt - 2);                       // wave-uniform
    float pv0[4], pv1[4];
#pragma unroll
    for (int r = 0; r < 4; r++) {
      float e20 = __expf(s0[r] * 0.04f);
      float e21 = __expf(s1[r] * 0.04f);
      pv0[r] = __expf(__fdividef(-100.f, e20 + 1.f));
      pv1[r] = __expf(__fdividef(-100.f, e21 + 1.f));
    }
    if (needmask) {
#pragma unroll
      for (int r = 0; r < 4; r++) {
        int qg = q0 + wave * 16 + fq * 4 + r;
        if (!((k0 + fr) <= qg)) pv0[r] = 0.f;
        if (!((k0 + 16 + fr) <= qg)) pv1[r] = 0.f;
      }
    }
#pragma unroll
    for (int r = 0; r < 4; r++) {
      int qrow = fq * 4 + r;
      float p0 = am0 ? pv0[r] : 0.f;
      float p1 = am1 ? pv1[r] : 0.f;
      Pl[wave][qrow * 32 + (fr ^ (r << 3))] = f2bft(p0);
      Pl[wave][qrow * 32 + ((16 + fr) ^ (r << 3))] = f2bft(p1);
    }
    asm volatile("s_waitcnt lgkmcnt(0)" ::: "memory");
    __builtin_amdgcn_sched_barrier(0);
    if (more)
      asm volatile("s_waitcnt vmcnt(4)" ::: "memory");
    else
      asm volatile("s_waitcnt vmcnt(0)" ::: "memory");
    __builtin_amdgcn_sched_barrier(0);
    __builtin_amdgcn_s_barrier();                        // BAR-C
    __builtin_amdgcn_sched_barrier(0);

    s16x8 pf = *(const s16x8*)&Pl[wave][fr * 32 + ((fq * 8) ^ psw)];
    __builtin_amdgcn_s_setprio(1);
    lacc = mfma16(pf, onesv, lacc);
#pragma unroll
    for (int df = 0; df < 16; df++) {
      s16x8 vv = *(const s16x8*)&Vl[(df * 16 + fr) * 32 + ((fq ^ vswl) * 8)];
      oacc[df] = mfma16(pf, vv, oacc[df]);
    }
    __builtin_amdgcn_s_setprio(0);
    asm volatile("s_waitcnt lgkmcnt(0)" ::: "memory");
    __builtin_amdgcn_sched_barrier(0);
    kb ^= 1;
  }

  if (fr == 0) {
#pragma unroll
    for (int r = 0; r < 4; r++)
      Lp[(size_t)(b * S_ + q0 + wave * 16 + fq * 4 + r) * 8 + h] = lacc[r];
  }
#pragma unroll
  for (int df = 0; df < 16; df++) {
#pragma unroll
    for (int r = 0; r < 4; r++) {
      Op[(size_t)(b * S_ + q0 + wave * 16 + fq * 4 + r) * 2048 + h * 256 + df * 16 + fr] =
          f2bf(oacc[df][r]);
    }
  }
}

// ---------------- combine partial halves: AO = (O0+O1)/(l0+l1) ----------------
__global__ void combine_o(const u16* __restrict__ O0, const u16* __restrict__ O1,
                          const float* __restrict__ L0, const float* __restrict__ L1,
                          u16* __restrict__ AO) {
  int idx = blockIdx.x * blockDim.x + threadIdx.x;
  int row = idx >> 8;
  int cg = idx & 255;
  int h = cg >> 5;
  float rinv = 1.0f / (L0[row * 8 + h] + L1[row * 8 + h]);
  size_t base = (size_t)row * 2048 + cg * 8;
  s16x8 a = *(const s16x8*)(O0 + base);
  s16x8 b = *(const s16x8*)(O1 + base);
  s16x8 o;
#pragma unroll
  for (int j = 0; j < 8; j++)
    o[j] = (short)f2bf((bf2f((u16)a[j]) + bf2f((u16)b[j])) * rinv);
  *(s16x8*)(AO + base) = o;
}

extern "C" void kernel_launch(void* const* d_in, const int* in_sizes, int n_in,
                              void* d_out, int out_size, void* d_ws, size_t ws_size,
                              hipStream_t stream) {
  const float* X   = (const float*)d_in[0];   // [B,S,H] fp32
  const int* amask = (const int*)d_in[1];
  const int* pos   = (const int*)d_in[2];
  const float* Wq  = (const float*)d_in[3];
  const float* Wk  = (const float*)d_in[4];
  const float* Wv  = (const float*)d_in[5];
  const float* Wo  = (const float*)d_in[6];
  float* out = (float*)d_out;                 // [B,S,H] fp32

  char* ws = (char*)d_ws;
  size_t off = 0;
  auto allocB = [&](size_t bytes) {
    char* p = ws + off;
    off += ((bytes + 255) & ~(size_t)255);
    return p;
  };
  u16* Xb   = (u16*)allocB((size_t)4096 * 2304 * 2);
  u16* WqT  = (u16*)allocB((size_t)2048 * 2304 * 2);   // WqT/WkT/WvT contiguous => fused B^T
  u16* WkT  = (u16*)allocB((size_t)1024 * 2304 * 2);
  u16* WvT  = (u16*)allocB((size_t)1024 * 2304 * 2);
  u16* WoT  = (u16*)allocB((size_t)2304 * 2048 * 2);
  u16* QKV  = (u16*)allocB((size_t)4096 * 4096 * 2);
  u16* VTb  = (u16*)allocB((size_t)4096 * 1024 * 2);
  u16* AO   = (u16*)allocB((size_t)4096 * 2048 * 2);
  float* CT = (float*)allocB((size_t)2048 * 128 * 4);
  float* ST = (float*)allocB((size_t)2048 * 128 * 4);
  float* Lp0 = (float*)allocB((size_t)4096 * 8 * 4);
  float* Lp1 = (float*)allocB((size_t)4096 * 8 * 4);
  // O partials ALIAS the Xb/WqT/WkT/WvT-head region (dead after gemm256)
  u16* Op0 = (u16*)ws;
  u16* Op1 = Op0 + (size_t)4096 * 2048;
  if (off > ws_size) return;

  // fused prep: rope table + X convert + 4 weight transposes (one launch)
  prep_kernel<<<24064, 256, 0, stream>>>(X, Xb, Wq, WqT, Wk, WkT, Wv, WvT, Wo, WoT, CT, ST);

  // fused QKV projection (256² 4-phase interleave, distributed staging, 1 barrier/tile)
  gemm256<false><<<dim3(4096 / 256, 4096 / 256), 512, 0, stream>>>(Xb, WqT, QKV, 4096, 4096, 2304);

  // fused mid: rope_k + V-transpose (one launch; 1024 + 4096 blocks)
  mid_kernel<<<5120, 256, 0, stream>>>(QKV, VTb, pos, CT, ST);

  // attention: key-split grid 1024, XCD-pinned (b,g), 2-barrier pipeline
  attn_kernel<<<dim3(1024), 256, 0, stream>>>(QKV, VTb, amask, pos, CT, ST, Op0, Op1, Lp0, Lp1);

  // combine halves -> AO bf16
  combine_o<<<4096, 256, 0, stream>>>(Op0, Op1, Lp0, Lp1, AO);

  // output projection -> fp32 d_out (128² BK=32 pipelined)
  gemm128<true><<<dim3(2304 / 128, 4096 / 128), 256, 0, stream>>>(AO, WoT, out, 4096, 2304, 2048);
}

// Round 25
// 235.627 us; speedup vs baseline: 1.1481x; 1.0155x over previous
//
#include <hip/hip_runtime.h>
#include <hip/hip_bf16.h>
#include <stdint.h>

typedef unsigned short u16;
typedef __attribute__((ext_vector_type(8))) short s16x8;
typedef __attribute__((ext_vector_type(4))) float f32x4;

#define B_ 2
#define S_ 2048
#define H_ 2304
#define NH_ 8
#define NKV_ 4
#define HD_ 256

__device__ __forceinline__ float bf2f(u16 u) {
  union { uint32_t i; float f; } x; x.i = ((uint32_t)u) << 16; return x.f;
}
__device__ __forceinline__ u16 f2bf(float f) {
  union { float f; uint32_t i; } x; x.f = f;
  uint32_t u = x.i;
  return (u16)((u + 0x7fffu + ((u >> 16) & 1u)) >> 16);
}
__device__ __forceinline__ u16 f2bft(float f) {          // truncating (for P: bias cancels in O/l)
  union { float f; uint32_t i; } x; x.f = f;
  return (u16)(x.i >> 16);
}

__device__ __forceinline__ void async16(const void* g, void* l) {
  __builtin_amdgcn_global_load_lds((const __attribute__((address_space(1))) uint32_t*)g,
                                   (__attribute__((address_space(3))) uint32_t*)l, 16, 0, 0);
}

__device__ __forceinline__ f32x4 mfma16(s16x8 a, s16x8 b, f32x4 c) {
  return __builtin_amdgcn_mfma_f32_16x16x32_bf16(a, b, c, 0, 0, 0);
}

// ================= fused prep: rope table + X convert + 4 weight transposes =================
__global__ __launch_bounds__(256) void prep_kernel(
    const float* __restrict__ X, u16* __restrict__ Xb,
    const float* __restrict__ Wq, u16* __restrict__ WqT,
    const float* __restrict__ Wk, u16* __restrict__ WkT,
    const float* __restrict__ Wv, u16* __restrict__ WvT,
    const float* __restrict__ Wo, u16* __restrict__ WoT,
    float* __restrict__ ct, float* __restrict__ st) {
  __shared__ u16 tile[32][33];
  int bid = blockIdx.x, tid = threadIdx.x;

  auto tposeT = [&](const float* in, u16* out, int R, int C, int bx, int by) {
    int c0 = bx * 32, r0 = by * 32;
    int x = tid & 31, y = tid >> 5;
#pragma unroll
    for (int j = 0; j < 32; j += 8)
      tile[y + j][x] = f2bf(in[(size_t)(r0 + y + j) * C + c0 + x]);
    __syncthreads();
#pragma unroll
    for (int j = 0; j < 32; j += 8)
      out[(size_t)(c0 + y + j) * R + r0 + x] = tile[x][y + j];
  };

  if (bid < 1024) {
    int t = bid * 256 + tid;                       // t = p*128 + d
    int d = t & 127;
    int p = t >> 7;
    float invf = exp2f(-(float)d * 0.1038102530f); // log2(10000)/128
    float f = (float)p * invf;
    float s, c;
    sincosf(f, &s, &c);
    ct[t] = c;
    st[t] = s;
  } else if (bid < 10240) {
    size_t i = ((size_t)(bid - 1024) * 256 + tid) * 4;
    float4 v = *(const float4*)(X + i);
    ushort4 o;
    o.x = f2bf(v.x); o.y = f2bf(v.y); o.z = f2bf(v.z); o.w = f2bf(v.w);
    *(ushort4*)(Xb + i) = o;
  } else if (bid < 14848) {
    int b2 = bid - 10240;
    tposeT(Wq, WqT, 2304, 2048, b2 & 63, b2 >> 6);
  } else if (bid < 17152) {
    int b2 = bid - 14848;
    tposeT(Wk, WkT, 2304, 1024, b2 & 31, b2 >> 5);
  } else if (bid < 19456) {
    int b2 = bid - 17152;
    tposeT(Wv, WvT, 2304, 1024, b2 & 31, b2 >> 5);
  } else {
    int b2 = bid - 19456;
    tposeT(Wo, WoT, 2048, 2304, b2 % 72, b2 / 72);
  }
}

// ================= fused mid: rope_k + V-transpose =================
__global__ __launch_bounds__(256) void mid_kernel(u16* __restrict__ QKV, u16* __restrict__ VTb,
                                                  const int* __restrict__ pos_ids,
                                                  const float* __restrict__ ct,
                                                  const float* __restrict__ st) {
  __shared__ u16 tile[32][33];
  int bid = blockIdx.x, tid = threadIdx.x;
  if (bid < 1024) {
    int t = bid * 256 + tid;
    int dg = t & 15, h = (t >> 4) & 3, row = t >> 6;
    u16* p1 = QKV + (size_t)row * 4096 + 2048 + h * 256 + dg * 8;
    u16* p2 = p1 + 128;
    int pos = pos_ids[row];
    const float* ctp = ct + pos * 128 + dg * 8;
    const float* stp = st + pos * 128 + dg * 8;
    s16x8 v1 = *(const s16x8*)p1, v2 = *(const s16x8*)p2;
#pragma unroll
    for (int j = 0; j < 8; j++) {
      float c = ctp[j], s = stp[j];
      float a = bf2f((u16)v1[j]);
      float b = bf2f((u16)v2[j]);
      v1[j] = (short)f2bf(a * c - b * s);
      v2[j] = (short)f2bf(b * c + a * s);
    }
    *(s16x8*)p1 = v1;
    *(s16x8*)p2 = v2;
  } else {
    int b2 = bid - 1024;                       // [0,4096)
    int bx = b2 & 31;
    int by = (b2 >> 5) & 63;
    int z = b2 >> 11;
    const u16* in = QKV + 3072 + (size_t)z * 2048 * 4096;
    u16* out = VTb + (size_t)z * 1024 * 2048;
    int c0 = bx * 32, r0 = by * 32;
    int x = tid & 31, y = tid >> 5;
#pragma unroll
    for (int j = 0; j < 32; j += 8)
      tile[y + j][x] = in[(size_t)(r0 + y + j) * 4096 + c0 + x];
    __syncthreads();
#pragma unroll
    for (int j = 0; j < 32; j += 8)
      out[(size_t)(c0 + y + j) * 2048 + r0 + x] = tile[x][y + j];
  }
}

// ======== 256x256 GEMM, 4-phase interleave + distributed staging, 1 barrier/tile ========
template <bool F32OUT>
__global__ __launch_bounds__(512) void gemm256(const u16* __restrict__ A, const u16* __restrict__ BT,
                                               void* __restrict__ Cout, int M, int N, int Kd) {
  __shared__ u16 As[2][256 * 64];
  __shared__ u16 Bs[2][256 * 64];
  int tid = threadIdx.x, lane = tid & 63, wave = tid >> 6;
  int nT = gridDim.x * gridDim.y;
  int bid = blockIdx.y * gridDim.x + blockIdx.x;
  int tile = (bid & 7) * (nT >> 3) + (bid >> 3);        // XCD swizzle (nT % 8 == 0)
  int bn = (tile % gridDim.x) * 256;
  int bm = (tile / gridDim.x) * 256;
  int wm = (wave >> 2) * 128, wn = (wave & 3) * 64;
  int fr = lane & 15, fq = lane >> 4;
  f32x4 acc[8][4];
#pragma unroll
  for (int i = 0; i < 8; i++)
#pragma unroll
    for (int j = 0; j < 4; j++) acc[i][j] = (f32x4){0.f, 0.f, 0.f, 0.f};

  int srow = tid >> 3, sslot = tid & 7;
  int scol = (sslot * 8) ^ ((srow & 7) << 3);           // pre-swizzled source col (u16 units)
  const u16* Ab = A + (size_t)(bm + srow) * Kd + scol;
  const u16* Bb = BT + (size_t)(bn + srow) * Kd + scol;

  auto stage1 = [&](int buf, int k0, int i) {
    if (i < 4)
      async16(Ab + (size_t)i * 64 * Kd + k0, (char*)&As[buf][0] + wave * 1024 + i * 8192);
    else
      async16(Bb + (size_t)(i - 4) * 64 * Kd + k0, (char*)&Bs[buf][0] + wave * 1024 + (i - 4) * 8192);
  };

  int NT = Kd >> 6;
  int rsw = (fr & 7) << 3;
#pragma unroll
  for (int i = 0; i < 8; i++) stage1(0, 0, i);          // prologue: tile 0

  for (int t = 0; t < NT; ++t) {
    asm volatile("s_waitcnt vmcnt(0)" ::: "memory");    // retire tile-t loads (issued iter t-1)
    __builtin_amdgcn_sched_barrier(0);
    __builtin_amdgcn_s_barrier();                       // tile t visible; WAR for buf[(t+1)&1]
    __builtin_amdgcn_sched_barrier(0);
    const u16* Ap = &As[t & 1][0];
    const u16* Bp = &Bs[t & 1][0];
    bool more = (t + 1 < NT);
    int nb = (t + 1) & 1;
    int nk = (t + 1) << 6;
    s16x8 bfr[4][2];
#pragma unroll
    for (int q = 0; q < 4; q++) {
      if (q == 0) {
#pragma unroll
        for (int j = 0; j < 4; j++)
#pragma unroll
          for (int s = 0; s < 2; s++)
            bfr[j][s] = *(const s16x8*)&Bp[(wn + j * 16 + fr) * 64 + ((s * 32 + fq * 8) ^ rsw)];
      }
      s16x8 aq[2][2];
#pragma unroll
      for (int rf = 0; rf < 2; rf++)
#pragma unroll
        for (int s = 0; s < 2; s++)
          aq[rf][s] = *(const s16x8*)&Ap[(wm + q * 32 + rf * 16 + fr) * 64 + ((s * 32 + fq * 8) ^ rsw)];
      if (more && q < 2) {                              // front-loaded: 4 loads in ph0, 4 in ph1
#pragma unroll
        for (int i = 0; i < 4; i++) stage1(nb, nk, q * 4 + i);
      }
      asm volatile("s_waitcnt lgkmcnt(0)" ::: "memory");
      __builtin_amdgcn_sched_barrier(0);
      __builtin_amdgcn_s_setprio(1);
#pragma unroll
      for (int rf = 0; rf < 2; rf++)
#pragma unroll
        for (int j = 0; j < 4; j++) {
          acc[q * 2 + rf][j] = mfma16(aq[rf][0], bfr[j][0], acc[q * 2 + rf][j]);
          acc[q * 2 + rf][j] = mfma16(aq[rf][1], bfr[j][1], acc[q * 2 + rf][j]);
        }
      __builtin_amdgcn_s_setprio(0);
      __builtin_amdgcn_sched_barrier(0);                // pin interleave only (no s_barrier)
    }
  }

#pragma unroll
  for (int i = 0; i < 8; i++)
#pragma unroll
    for (int j = 0; j < 4; j++)
#pragma unroll
      for (int r = 0; r < 4; r++) {
        int row = bm + wm + i * 16 + fq * 4 + r;
        int col = bn + wn + j * 16 + fr;
        if (F32OUT) ((float*)Cout)[(size_t)row * N + col] = acc[i][j][r];
        else        ((u16*)Cout)[(size_t)row * N + col] = f2bf(acc[i][j][r]);
      }
}

// ======== 128x128 GEMM, 2-phase interleave + distributed staging, 1 barrier/tile ========
// Same ledger as gemm256: vmcnt(0)@top retires tile-t loads; single barrier covers RAW
// (tile-t stores visible) and WAR (buf[t+1]'s last readers passed their lgkm0 before it).
template <bool F32OUT>
__global__ __launch_bounds__(256) void gemm128(const u16* __restrict__ A, const u16* __restrict__ BT,
                                               void* __restrict__ Cout, int M, int N, int Kd) {
  __shared__ u16 As[2][128 * 32];
  __shared__ u16 Bs[2][128 * 32];
  int tid = threadIdx.x, lane = tid & 63, wave = tid >> 6;
  int nT = gridDim.x * gridDim.y;
  int bid = blockIdx.y * gridDim.x + blockIdx.x;
  int tile = (bid & 7) * (nT >> 3) + (bid >> 3);
  int bn = (tile % gridDim.x) * 128;
  int bm = (tile / gridDim.x) * 128;
  int wm = (wave >> 1) * 64, wn = (wave & 1) * 64;
  int fr = lane & 15, fq = lane >> 4;
  f32x4 acc[4][4];
#pragma unroll
  for (int i = 0; i < 4; i++)
#pragma unroll
    for (int j = 0; j < 4; j++) acc[i][j] = (f32x4){0.f, 0.f, 0.f, 0.f};

  int srow = tid >> 2, sslot = tid & 3;
  int scol = (sslot * 8) ^ ((srow & 3) << 3);
  const u16* Ab = A + (size_t)(bm + srow) * Kd + scol;
  const u16* Bb = BT + (size_t)(bn + srow) * Kd + scol;

  // staging slots: 0=A rows 0-63, 1=A rows 64-127, 2=B rows 0-63, 3=B rows 64-127
  auto stage1 = [&](int buf, int k0, int i) {
    if (i == 0)      async16(Ab + k0, (char*)&As[buf][0] + wave * 1024);
    else if (i == 1) async16(Ab + (size_t)64 * Kd + k0, (char*)&As[buf][0] + wave * 1024 + 4096);
    else if (i == 2) async16(Bb + k0, (char*)&Bs[buf][0] + wave * 1024);
    else             async16(Bb + (size_t)64 * Kd + k0, (char*)&Bs[buf][0] + wave * 1024 + 4096);
  };

  int NT = Kd >> 5;
  int rsw = (fr & 3) << 3;
#pragma unroll
  for (int i = 0; i < 4; i++) stage1(0, 0, i);          // prologue: tile 0

  for (int t = 0; t < NT; ++t) {
    asm volatile("s_waitcnt vmcnt(0)" ::: "memory");    // retire tile-t loads
    __builtin_amdgcn_sched_barrier(0);
    __builtin_amdgcn_s_barrier();                       // tile t visible; WAR for buf[(t+1)&1]
    __builtin_amdgcn_sched_barrier(0);
    const u16* Ap = &As[t & 1][0];
    const u16* Bp = &Bs[t & 1][0];
    bool more = (t + 1 < NT);
    int nb = (t + 1) & 1;
    int nk = (t + 1) << 5;
    s16x8 bv[4];
#pragma unroll
    for (int q = 0; q < 2; q++) {
      if (q == 0) {
#pragma unroll
        for (int j = 0; j < 4; j++)
          bv[j] = *(const s16x8*)&Bp[(wn + j * 16 + fr) * 32 + ((fq * 8) ^ rsw)];
      }
      s16x8 aq[2];
#pragma unroll
      for (int rf = 0; rf < 2; rf++)
        aq[rf] = *(const s16x8*)&Ap[(wm + (q * 2 + rf) * 16 + fr) * 32 + ((fq * 8) ^ rsw)];
      if (more) {                                       // 2 staging loads per phase
        stage1(nb, nk, q * 2);
        stage1(nb, nk, q * 2 + 1);
      }
      asm volatile("s_waitcnt lgkmcnt(0)" ::: "memory");
      __builtin_amdgcn_sched_barrier(0);
      __builtin_amdgcn_s_setprio(1);
#pragma unroll
      for (int rf = 0; rf < 2; rf++)
#pragma unroll
        for (int j = 0; j < 4; j++)
          acc[q * 2 + rf][j] = mfma16(aq[rf], bv[j], acc[q * 2 + rf][j]);
      __builtin_amdgcn_s_setprio(0);
      __builtin_amdgcn_sched_barrier(0);                // pin interleave only (no s_barrier)
    }
  }
#pragma unroll
  for (int i = 0; i < 4; i++)
#pragma unroll
    for (int j = 0; j < 4; j++)
#pragma unroll
      for (int r = 0; r < 4; r++) {
        int row = bm + wm + i * 16 + fq * 4 + r;
        int col = bn + wn + j * 16 + fr;
        if (F32OUT) ((float*)Cout)[(size_t)row * N + col] = acc[i][j][r];
        else        ((u16*)Cout)[(size_t)row * N + col] = f2bf(acc[i][j][r]);
      }
}

// ---------------- flash attention, KEY-SPLIT, 2-barrier race-free pipeline ----------
__global__ __launch_bounds__(256) void attn_kernel(const u16* __restrict__ QKV, const u16* __restrict__ VT,
                                                   const int* __restrict__ amask, const int* __restrict__ pos_ids,
                                                   const float* __restrict__ ct, const float* __restrict__ st,
                                                   u16* __restrict__ O0, u16* __restrict__ O1,
                                                   float* __restrict__ L0, float* __restrict__ L1) {
  __shared__ u16 Kl[2][32 * 256];        // K double buffer; granule swz: slot ^= key&7
  __shared__ u16 Vl[256 * 32];           // V single buffer; granule swz: slot ^= (hd>>1)&3
  __shared__ u16 Pl[4][16 * 32];         // per-wave P, XOR-swizzled cols
  __shared__ unsigned char Mb[256];      // bit-packed amask (2048 bits)
  int id = blockIdx.x;
  int bg = id & 7;                        // XCD-pinned (b,g)
  int r_ = id >> 3;
  int qt = 31 - (r_ >> 2);                // heavy first
  int hl = (r_ >> 1) & 1;
  int half = r_ & 1;
  int b = bg >> 2, g = bg & 3;
  int h = g * 2 + hl;
  int tid = threadIdx.x, lane = tid & 63, wave = tid >> 6;
  int fr = lane & 15, fq = lane >> 4;
  int q0 = qt * 64;
  u16* Op = half ? O1 : O0;
  float* Lp = half ? L1 : L0;

  // ---- bit-pack attention mask ----
  const int* amp = amask + b * S_;
  {
    int4 a = *(const int4*)(amp + tid * 8);
    int4 c = *(const int4*)(amp + tid * 8 + 4);
    unsigned v = (unsigned)(a.x > 0) | ((unsigned)(a.y > 0) << 1) | ((unsigned)(a.z > 0) << 2) |
                 ((unsigned)(a.w > 0) << 3) | ((unsigned)(c.x > 0) << 4) | ((unsigned)(c.y > 0) << 5) |
                 ((unsigned)(c.z > 0) << 6) | ((unsigned)(c.w > 0) << 7);
    Mb[tid] = (unsigned char)v;
  }

  // ---- load Q rows wave*16+fr, apply RoPE in-register, scale 1/16 ----
  int qrow_g = b * S_ + q0 + wave * 16 + fr;
  s16x8 qr[8];
  const u16* qb = QKV + (size_t)qrow_g * 4096 + h * 256 + fq * 8;
#pragma unroll
  for (int kk = 0; kk < 8; kk++) qr[kk] = *(const s16x8*)(qb + kk * 32);
  int pos = pos_ids[qrow_g];
  const float* ctp = ct + pos * 128 + fq * 8;
  const float* stp = st + pos * 128 + fq * 8;
  s16x8 qf[8];
#pragma unroll
  for (int kk = 0; kk < 4; kk++) {
#pragma unroll
    for (int jj = 0; jj < 8; jj++) {
      float c = ctp[kk * 32 + jj], s = stp[kk * 32 + jj];
      float a = bf2f((u16)qr[kk][jj]);
      float bb = bf2f((u16)qr[kk + 4][jj]);
      qf[kk][jj]     = (short)f2bf((a * c - bb * s) * 0.0625f);
      qf[kk + 4][jj] = (short)f2bf((bb * c + a * s) * 0.0625f);
    }
  }

  f32x4 zero4 = {0.f, 0.f, 0.f, 0.f};
  f32x4 oacc[16];
#pragma unroll
  for (int i = 0; i < 16; i++) oacc[i] = zero4;
  f32x4 lacc = zero4;
  s16x8 onesv;
#pragma unroll
  for (int i = 0; i < 8; i++) onesv[i] = (short)0x3F80;

  const u16* Kbase = QKV + (size_t)b * S_ * 4096 + 2048 + g * 256;
  const u16* Vbase = VT + (size_t)(b * 4 + g) * 256 * S_;

  const u16* KsP[4];
  const u16* VsP[4];
  int dst16[4];
#pragma unroll
  for (int i = 0; i < 4; i++) {
    int c = tid + i * 256;
    int key = c >> 5, slot = c & 31;
    KsP[i] = Kbase + (size_t)key * 4096 + ((slot ^ (key & 7)) * 8);
    int hd = c >> 2, vs = c & 3;
    VsP[i] = Vbase + (size_t)hd * 2048 + ((vs ^ ((hd >> 1) & 3)) * 8);
    dst16[i] = c * 16;
  }

  __syncthreads();                                  // Mb visible; all prologue vmem drained

  // prologue: stage K(half)
#pragma unroll
  for (int i = 0; i < 4; i++)
    async16(KsP[i] + (size_t)(half * 32) * 4096, (char*)&Kl[0][0] + dst16[i]);

  int nt = 2 * qt + 2;
  int ksw = fr & 7;
  int vswl = (fr >> 1) & 3;
  int psw = (fr & 3) << 3;
  int kb = 0;
  for (int t = half; t < nt; t += 2) {
    int k0 = t * 32;
    bool more = (t + 2 < nt);
    asm volatile("s_waitcnt vmcnt(0)" ::: "memory");     // retire K(t)
    __builtin_amdgcn_sched_barrier(0);
    __builtin_amdgcn_s_barrier();                        // BAR-A
    __builtin_amdgcn_sched_barrier(0);

#pragma unroll
    for (int i = 0; i < 4; i++)
      async16(VsP[i] + k0, (char*)&Vl[0] + dst16[i]);
    if (more) {
#pragma unroll
      for (int i = 0; i < 4; i++)
        async16(KsP[i] + (size_t)(k0 + 64) * 4096, (char*)&Kl[kb ^ 1][0] + dst16[i]);
    }

    const u16* Kp = &Kl[kb][0];
    __builtin_amdgcn_s_setprio(1);
    f32x4 s0 = zero4, s1 = zero4;
#pragma unroll
    for (int kk = 0; kk < 8; kk++) {
      s16x8 b0 = *(const s16x8*)&Kp[fr * 256 + (((kk * 4 + fq) ^ ksw) * 8)];
      s16x8 b1 = *(const s16x8*)&Kp[(16 + fr) * 256 + (((kk * 4 + fq) ^ ksw) * 8)];
      s0 = mfma16(qf[kk], b0, s0);
      s1 = mfma16(qf[kk], b1, s1);
    }
    __builtin_amdgcn_s_setprio(0);

    int am0 = (Mb[(k0 + fr) >> 3] >> ((k0 + fr) & 7)) & 1;
    int am1 = (Mb[(k0 + 16 + fr) >> 3] >> ((k0 + 16 + fr) & 7)) & 1;
    bool needmask = (t >= nt - 2);                       // wave-uniform
    float pv0[4], pv1[4];
#pragma unroll
    for (int r = 0; r < 4; r++) {
      float e20 = __expf(s0[r] * 0.04f);
      float e21 = __expf(s1[r] * 0.04f);
      pv0[r] = __expf(__fdividef(-100.f, e20 + 1.f));
      pv1[r] = __expf(__fdividef(-100.f, e21 + 1.f));
    }
    if (needmask) {
#pragma unroll
      for (int r = 0; r < 4; r++) {
        int qg = q0 + wave * 16 + fq * 4 + r;
        if (!((k0 + fr) <= qg)) pv0[r] = 0.f;
        if (!((k0 + 16 + fr) <= qg)) pv1[r] = 0.f;
      }
    }
#pragma unroll
    for (int r = 0; r < 4; r++) {
      int qrow = fq * 4 + r;
      float p0 = am0 ? pv0[r] : 0.f;
      float p1 = am1 ? pv1[r] : 0.f;
      Pl[wave][qrow * 32 + (fr ^ (r << 3))] = f2bft(p0);
      Pl[wave][qrow * 32 + ((16 + fr) ^ (r << 3))] = f2bft(p1);
    }
    asm volatile("s_waitcnt lgkmcnt(0)" ::: "memory");
    __builtin_amdgcn_sched_barrier(0);
    if (more)
      asm volatile("s_waitcnt vmcnt(4)" ::: "memory");
    else
      asm volatile("s_waitcnt vmcnt(0)" ::: "memory");
    __builtin_amdgcn_sched_barrier(0);
    __builtin_amdgcn_s_barrier();                        // BAR-C
    __builtin_amdgcn_sched_barrier(0);

    s16x8 pf = *(const s16x8*)&Pl[wave][fr * 32 + ((fq * 8) ^ psw)];
    __builtin_amdgcn_s_setprio(1);
    lacc = mfma16(pf, onesv, lacc);
#pragma unroll
    for (int df = 0; df < 16; df++) {
      s16x8 vv = *(const s16x8*)&Vl[(df * 16 + fr) * 32 + ((fq ^ vswl) * 8)];
      oacc[df] = mfma16(pf, vv, oacc[df]);
    }
    __builtin_amdgcn_s_setprio(0);
    asm volatile("s_waitcnt lgkmcnt(0)" ::: "memory");
    __builtin_amdgcn_sched_barrier(0);
    kb ^= 1;
  }

  if (fr == 0) {
#pragma unroll
    for (int r = 0; r < 4; r++)
      Lp[(size_t)(b * S_ + q0 + wave * 16 + fq * 4 + r) * 8 + h] = lacc[r];
  }
#pragma unroll
  for (int df = 0; df < 16; df++) {
#pragma unroll
    for (int r = 0; r < 4; r++) {
      Op[(size_t)(b * S_ + q0 + wave * 16 + fq * 4 + r) * 2048 + h * 256 + df * 16 + fr] =
          f2bf(oacc[df][r]);
    }
  }
}

// ---------------- combine partial halves: AO = (O0+O1)/(l0+l1) ----------------
__global__ void combine_o(const u16* __restrict__ O0, const u16* __restrict__ O1,
                          const float* __restrict__ L0, const float* __restrict__ L1,
                          u16* __restrict__ AO) {
  int idx = blockIdx.x * blockDim.x + threadIdx.x;
  int row = idx >> 8;
  int cg = idx & 255;
  int h = cg >> 5;
  float rinv = 1.0f / (L0[row * 8 + h] + L1[row * 8 + h]);
  size_t base = (size_t)row * 2048 + cg * 8;
  s16x8 a = *(const s16x8*)(O0 + base);
  s16x8 b = *(const s16x8*)(O1 + base);
  s16x8 o;
#pragma unroll
  for (int j = 0; j < 8; j++)
    o[j] = (short)f2bf((bf2f((u16)a[j]) + bf2f((u16)b[j])) * rinv);
  *(s16x8*)(AO + base) = o;
}

extern "C" void kernel_launch(void* const* d_in, const int* in_sizes, int n_in,
                              void* d_out, int out_size, void* d_ws, size_t ws_size,
                              hipStream_t stream) {
  const float* X   = (const float*)d_in[0];   // [B,S,H] fp32
  const int* amask = (const int*)d_in[1];
  const int* pos   = (const int*)d_in[2];
  const float* Wq  = (const float*)d_in[3];
  const float* Wk  = (const float*)d_in[4];
  const float* Wv  = (const float*)d_in[5];
  const float* Wo  = (const float*)d_in[6];
  float* out = (float*)d_out;                 // [B,S,H] fp32

  char* ws = (char*)d_ws;
  size_t off = 0;
  auto allocB = [&](size_t bytes) {
    char* p = ws + off;
    off += ((bytes + 255) & ~(size_t)255);
    return p;
  };
  u16* Xb   = (u16*)allocB((size_t)4096 * 2304 * 2);
  u16* WqT  = (u16*)allocB((size_t)2048 * 2304 * 2);   // WqT/WkT/WvT contiguous => fused B^T
  u16* WkT  = (u16*)allocB((size_t)1024 * 2304 * 2);
  u16* WvT  = (u16*)allocB((size_t)1024 * 2304 * 2);
  u16* WoT  = (u16*)allocB((size_t)2304 * 2048 * 2);
  u16* QKV  = (u16*)allocB((size_t)4096 * 4096 * 2);
  u16* VTb  = (u16*)allocB((size_t)4096 * 1024 * 2);
  u16* AO   = (u16*)allocB((size_t)4096 * 2048 * 2);
  float* CT = (float*)allocB((size_t)2048 * 128 * 4);
  float* ST = (float*)allocB((size_t)2048 * 128 * 4);
  float* Lp0 = (float*)allocB((size_t)4096 * 8 * 4);
  float* Lp1 = (float*)allocB((size_t)4096 * 8 * 4);
  // O partials ALIAS the Xb/WqT/WkT/WvT-head region (dead after gemm256)
  u16* Op0 = (u16*)ws;
  u16* Op1 = Op0 + (size_t)4096 * 2048;
  if (off > ws_size) return;

  // fused prep: rope table + X convert + 4 weight transposes (one launch)
  prep_kernel<<<24064, 256, 0, stream>>>(X, Xb, Wq, WqT, Wk, WkT, Wv, WvT, Wo, WoT, CT, ST);

  // fused QKV projection (256² 4-phase interleave, distributed staging, 1 barrier/tile)
  gemm256<false><<<dim3(4096 / 256, 4096 / 256), 512, 0, stream>>>(Xb, WqT, QKV, 4096, 4096, 2304);

  // fused mid: rope_k + V-transpose (one launch; 1024 + 4096 blocks)
  mid_kernel<<<5120, 256, 0, stream>>>(QKV, VTb, pos, CT, ST);

  // attention: key-split grid 1024, XCD-pinned (b,g), 2-barrier pipeline
  attn_kernel<<<dim3(1024), 256, 0, stream>>>(QKV, VTb, amask, pos, CT, ST, Op0, Op1, Lp0, Lp1);

  // combine halves -> AO bf16
  combine_o<<<4096, 256, 0, stream>>>(Op0, Op1, Lp0, Lp1, AO);

  // output projection -> fp32 d_out (128² 2-phase interleave, 1 barrier/tile)
  gemm128<true><<<dim3(2304 / 128, 4096 / 128), 256, 0, stream>>>(AO, WoT, out, 4096, 2304, 2048);
}